// Round 3
// baseline (7915.797 us; speedup 1.0000x reference)
//
#include <hip/hip_runtime.h>
#include <hip/hip_bf16.h>

using bf16 = __hip_bfloat16;

// Problem dims
constexpr int Bc = 16, Sc = 512, INc = 512, OUTc = 256;
constexpr int Dc = 1024, Hc = 16, Lc = 6, DFFc = 2048, HDc = 64, HIDc = 256;
constexpr float SCALEc = 0.125f; // HD^-0.5

__device__ inline float ldf(const float* p) { return *p; }
__device__ inline float ldf(const bf16* p) { return __bfloat162float(*p); }

// ---------------- block reductions (256 threads, wave64) ----------------
__device__ inline float blockSum256(float v) {
    __shared__ float tmp[4];
#pragma unroll
    for (int o = 32; o > 0; o >>= 1) v += __shfl_xor(v, o, 64);
    int w = threadIdx.x >> 6;
    __syncthreads();
    if ((threadIdx.x & 63) == 0) tmp[w] = v;
    __syncthreads();
    return tmp[0] + tmp[1] + tmp[2] + tmp[3];
}
__device__ inline float blockMax256(float v) {
    __shared__ float tmp[4];
#pragma unroll
    for (int o = 32; o > 0; o >>= 1) v = fmaxf(v, __shfl_xor(v, o, 64));
    int w = threadIdx.x >> 6;
    __syncthreads();
    if ((threadIdx.x & 63) == 0) tmp[w] = v;
    __syncthreads();
    return fmaxf(fmaxf(tmp[0], tmp[1]), fmaxf(tmp[2], tmp[3]));
}

// ---------------- mask flag: (sum(xm[0,:]) == 0) ----------------
__global__ __launch_bounds__(256) void mask_k(const float* __restrict__ xm, float* __restrict__ flag) {
    float s = xm[threadIdx.x] + xm[threadIdx.x + 256];
    s = blockSum256(s);
    if (threadIdx.x == 0) flag[0] = (s == 0.f) ? 1.f : 0.f;
}

// ---------------- generic GEMM: C[M,N] = act((A[M,K] @ W[K,N] + bias [+pos]) * scale) ----
// A: fp32 or bf16 (row-major). W/bias/pos: fp32. Output fp32 (Cf) or bf16 (Cb).
// 64x64 tile, BK=16, 256 threads, 4x4 micro-tile.
template <typename TA, int ACT, bool ADDPOS, bool OUT_BF16>
__global__ __launch_bounds__(256) void gemm_k(
    const TA* __restrict__ A, const float* __restrict__ W,
    const float* __restrict__ bias, const float* __restrict__ pos,
    float* __restrict__ Cf, bf16* __restrict__ Cb,
    int M, int N, int K, float scale)
{
    __shared__ float As[16][68]; // [k][m], stride 68 keeps float4-aligned rows
    __shared__ float Ws[16][68]; // [k][n]
    const int tid = threadIdx.x;
    const int m0 = blockIdx.y * 64, n0 = blockIdx.x * 64;
    const int ty = tid >> 4, tx = tid & 15;
    float c[4][4] = {};

    const int ka = tid & 15, mb = tid >> 4; // A-load coords
    const int nw = tid & 63, kb = tid >> 6; // W-load coords

    for (int k0 = 0; k0 < K; k0 += 16) {
#pragma unroll
        for (int j = 0; j < 4; ++j) {
            int m = mb + 16 * j;
            As[ka][m] = ldf(&A[(size_t)(m0 + m) * K + k0 + ka]);
        }
#pragma unroll
        for (int j = 0; j < 4; ++j) {
            int k = kb + 4 * j;
            Ws[k][nw] = W[(size_t)(k0 + k) * N + n0 + nw];
        }
        __syncthreads();
#pragma unroll
        for (int k = 0; k < 16; ++k) {
            float4 av = *(const float4*)&As[k][ty * 4];
            float4 wv = *(const float4*)&Ws[k][tx * 4];
            float a[4] = {av.x, av.y, av.z, av.w};
            float w[4] = {wv.x, wv.y, wv.z, wv.w};
#pragma unroll
            for (int i = 0; i < 4; ++i)
#pragma unroll
                for (int j = 0; j < 4; ++j) c[i][j] += a[i] * w[j];
        }
        __syncthreads();
    }

#pragma unroll
    for (int i = 0; i < 4; ++i) {
        int m = m0 + ty * 4 + i;
#pragma unroll
        for (int j = 0; j < 4; ++j) {
            int n = n0 + tx * 4 + j;
            float v = c[i][j] + bias[n];
            if (ADDPOS) v += pos[(size_t)(m & (Sc - 1)) * N + n];
            v *= scale;
            if (ACT == 1) v = fmaxf(v, 0.f);
            if (OUT_BF16) Cb[(size_t)m * N + n] = __float2bfloat16(v);
            else          Cf[(size_t)m * N + n] = v;
        }
    }
}

// ---------------- attention scores (batch 0): sc[h,t,s] = clip(q_h[t]·k_h[s]) ----------------
__global__ __launch_bounds__(256) void attn_scores_k(
    const float* __restrict__ q, const float* __restrict__ k,
    float* __restrict__ sc, const float* __restrict__ flag)
{
    const int hh = blockIdx.z;
    const int t0 = blockIdx.y * 64, s0 = blockIdx.x * 64;
    __shared__ float qs[64][68];  // [t][d]
    __shared__ float kst[64][68]; // [d][s] (transposed for float4 compute reads)
    const int tid = threadIdx.x;
    const int c4 = tid & 15, r0 = tid >> 4;
#pragma unroll
    for (int j = 0; j < 4; ++j) {
        int rr = r0 + 16 * j;
        float4 qv = *(const float4*)&q[(size_t)(t0 + rr) * Dc + hh * 64 + c4 * 4];
        *(float4*)&qs[rr][c4 * 4] = qv;
        float4 kv = *(const float4*)&k[(size_t)(s0 + rr) * Dc + hh * 64 + c4 * 4];
        kst[c4 * 4 + 0][rr] = kv.x; kst[c4 * 4 + 1][rr] = kv.y;
        kst[c4 * 4 + 2][rr] = kv.z; kst[c4 * 4 + 3][rr] = kv.w;
    }
    __syncthreads();
    const int ty = tid >> 4, tx = tid & 15;
    float c[4][4] = {};
#pragma unroll 8
    for (int d = 0; d < 64; ++d) {
        float a[4];
#pragma unroll
        for (int i = 0; i < 4; ++i) a[i] = qs[ty * 4 + i][d];
        float4 bv = *(const float4*)&kst[d][tx * 4];
        float b[4] = {bv.x, bv.y, bv.z, bv.w};
#pragma unroll
        for (int i = 0; i < 4; ++i)
#pragma unroll
            for (int j = 0; j < 4; ++j) c[i][j] += a[i] * b[j];
    }
    const bool msk = flag[0] > 0.5f;
    float* scp = sc + (size_t)hh * Sc * Sc;
#pragma unroll
    for (int i = 0; i < 4; ++i)
#pragma unroll
        for (int j = 0; j < 4; ++j) {
            float v = fminf(fmaxf(c[i][j], -10.f), 10.f);
            if (msk) v = -10.f;
            scp[(size_t)(t0 + ty * 4 + i) * Sc + s0 + tx * 4 + j] = v;
        }
}

// ---------------- row softmax (in-place safe). doclip: clamp [-10,10] first ----------------
__global__ __launch_bounds__(256) void softmax_k(
    const float* __restrict__ in, float* __restrict__ out, int ncols, int doclip)
{
    const int row = blockIdx.x;
    const float* ip = in + (size_t)row * ncols;
    float* op = out + (size_t)row * ncols;
    const int nj = ncols >> 8; // 2 (S=512) or 4 (D=1024)
    float r[4];
    float mx = -1e30f;
    for (int j = 0; j < nj; ++j) {
        float v = ip[threadIdx.x + 256 * j];
        if (doclip) v = fminf(fmaxf(v, -10.f), 10.f);
        r[j] = v;
        mx = fmaxf(mx, v);
    }
    mx = blockMax256(mx);
    float s = 0.f;
    for (int j = 0; j < nj; ++j) { r[j] = expf(r[j] - mx); s += r[j]; }
    s = blockSum256(s);
    float inv = 1.f / s;
    for (int j = 0; j < nj; ++j) op[threadIdx.x + 256 * j] = r[j] * inv;
}

// ---------------- attention AV (batch 0): ao[t, h*64+d] = sum_s aw[h,t,s] * v[s, h*64+d] ----
__global__ __launch_bounds__(256) void attn_av_k(
    const float* __restrict__ aw, const float* __restrict__ v, float* __restrict__ ao)
{
    const int hh = blockIdx.y;
    const int t0 = blockIdx.x * 64;
    __shared__ float as_[64][68]; // [t][s]
    __shared__ float vs[64][68];  // [s][d]
    const int tid = threadIdx.x;
    const int c4 = tid & 15, r0 = tid >> 4;
    const int ty = tid >> 4, tx = tid & 15;
    float c[4][4] = {};
    for (int s0 = 0; s0 < Sc; s0 += 64) {
#pragma unroll
        for (int j = 0; j < 4; ++j) {
            int rr = r0 + 16 * j;
            float4 avv = *(const float4*)&aw[(size_t)hh * Sc * Sc + (size_t)(t0 + rr) * Sc + s0 + c4 * 4];
            *(float4*)&as_[rr][c4 * 4] = avv;
            float4 vv = *(const float4*)&v[(size_t)(s0 + rr) * Dc + hh * 64 + c4 * 4];
            *(float4*)&vs[rr][c4 * 4] = vv;
        }
        __syncthreads();
#pragma unroll 8
        for (int ss = 0; ss < 64; ++ss) {
            float a[4];
#pragma unroll
            for (int i = 0; i < 4; ++i) a[i] = as_[ty * 4 + i][ss];
            float4 bv = *(const float4*)&vs[ss][tx * 4];
            float b[4] = {bv.x, bv.y, bv.z, bv.w};
#pragma unroll
            for (int i = 0; i < 4; ++i)
#pragma unroll
                for (int j = 0; j < 4; ++j) c[i][j] += a[i] * b[j];
        }
        __syncthreads();
    }
#pragma unroll
    for (int i = 0; i < 4; ++i)
#pragma unroll
        for (int j = 0; j < 4; ++j)
            ao[(size_t)(t0 + ty * 4 + i) * Dc + hh * 64 + tx * 4 + j] = c[i][j];
}

// ---------------- h = LN(h + add) ; add broadcast over batch if BCAST ----------------
template <bool BCAST>
__global__ __launch_bounds__(256) void add_ln_k(
    float* __restrict__ h, const float* __restrict__ add,
    const float* __restrict__ g, const float* __restrict__ b)
{
    const int row = blockIdx.x;
    const float* ap = BCAST ? add + (size_t)(row & (Sc - 1)) * Dc : add + (size_t)row * Dc;
    float* hp = h + (size_t)row * Dc;
    const int tid = threadIdx.x;
    float x[4];
    float s = 0.f;
#pragma unroll
    for (int j = 0; j < 4; ++j) {
        int cidx = tid + 256 * j;
        x[j] = hp[cidx] + ap[cidx];
        s += x[j];
    }
    float mean = blockSum256(s) * (1.f / (float)Dc);
    float vsum = 0.f;
#pragma unroll
    for (int j = 0; j < 4; ++j) { float d = x[j] - mean; vsum += d * d; }
    float var = blockSum256(vsum) * (1.f / (float)Dc);
    float inv = rsqrtf(var + 1e-5f);
#pragma unroll
    for (int j = 0; j < 4; ++j) {
        int cidx = tid + 256 * j;
        hp[cidx] = (x[j] - mean) * inv * g[cidx] + b[cidx];
    }
}

// ---------------- launch ----------------
extern "C" void kernel_launch(void* const* d_in, const int* in_sizes, int n_in,
                              void* d_out, int out_size, void* d_ws, size_t ws_size,
                              hipStream_t stream)
{
    const float* x      = (const float*)d_in[0];
    const float* xm     = (const float*)d_in[1];
    // d_in[2] vecSelector: assert-only, unused
    const float* proj_w = (const float*)d_in[3];
    const float* proj_b = (const float*)d_in[4];
    const float* pos    = (const float*)d_in[5];
    const float* qw     = (const float*)d_in[6];
    const float* qb     = (const float*)d_in[7];
    const float* kw     = (const float*)d_in[8];
    const float* kb     = (const float*)d_in[9];
    const float* vw     = (const float*)d_in[10];
    const float* vb     = (const float*)d_in[11];
    const float* ow     = (const float*)d_in[12];
    const float* obias  = (const float*)d_in[13];
    const float* ln1g   = (const float*)d_in[14];
    const float* ln1b   = (const float*)d_in[15];
    const float* ln2g   = (const float*)d_in[16];
    const float* ln2b   = (const float*)d_in[17];
    const float* w1     = (const float*)d_in[18];
    const float* b1     = (const float*)d_in[19];
    const float* w2     = (const float*)d_in[20];
    const float* b2     = (const float*)d_in[21];
    const float* fc1w   = (const float*)d_in[22];
    const float* fc1b   = (const float*)d_in[23];
    const float* fc2w   = (const float*)d_in[24];
    const float* fc2b   = (const float*)d_in[25];
    const float* fc3w   = (const float*)d_in[26];
    const float* fc3b   = (const float*)d_in[27];

    float* ws = (float*)d_ws;
    const size_t HSZ = (size_t)Bc * Sc * Dc; // 8,388,608 floats
    float* h    = ws;
    float* rgA  = ws + HSZ;       // attention temps | FFN mid (bf16), time-shared
    float* rgB  = ws + 2 * HSZ;   // ff | head temps, time-shared
    float* flag = ws + 3 * HSZ;   // needs ws_size >= ~96.1 MB

    float* sc  = rgA;                                  // 16*512*512
    float* qv_ = rgA + (size_t)Hc * Sc * Sc;           // 512*1024 each below
    float* kv_ = qv_ + (size_t)Sc * Dc;
    float* vv_ = kv_ + (size_t)Sc * Dc;
    float* aov = vv_ + (size_t)Sc * Dc;
    float* obv = aov + (size_t)Sc * Dc;
    bf16*  mid = (bf16*)rgA;                           // 8192*2048 bf16
    float* ff  = rgB;                                  // 8192*1024
    float* t1  = rgB;                                  // 8192*256
    float* t2  = rgB + (size_t)Bc * Sc * HIDc;

    const int MR = Bc * Sc; // 8192

    mask_k<<<1, 256, 0, stream>>>(xm, flag);

    // h = x @ proj_w + proj_b + pos
    gemm_k<float, 0, true, false><<<dim3(Dc / 64, MR / 64), 256, 0, stream>>>(
        x, proj_w, proj_b, pos, h, nullptr, MR, Dc, INc, 1.f);

    for (int l = 0; l < Lc; ++l) {
        const float* qw_l = qw + (size_t)l * Dc * Dc; const float* qb_l = qb + l * Dc;
        const float* kw_l = kw + (size_t)l * Dc * Dc; const float* kb_l = kb + l * Dc;
        const float* vw_l = vw + (size_t)l * Dc * Dc; const float* vb_l = vb + l * Dc;
        const float* ow_l = ow + (size_t)l * Dc * Dc; const float* ob_l = obias + l * Dc;
        const float* w1_l = w1 + (size_t)l * Dc * DFFc; const float* b1_l = b1 + l * DFFc;
        const float* w2_l = w2 + (size_t)l * DFFc * Dc; const float* b2_l = b2 + l * Dc;

        // attention: batch 0 only (sa = ao[0] is all that survives)
        gemm_k<float, 0, false, false><<<dim3(Dc / 64, Sc / 64), 256, 0, stream>>>(
            h, qw_l, qb_l, nullptr, qv_, nullptr, Sc, Dc, Dc, SCALEc);
        gemm_k<float, 0, false, false><<<dim3(Dc / 64, Sc / 64), 256, 0, stream>>>(
            h, kw_l, kb_l, nullptr, kv_, nullptr, Sc, Dc, Dc, 1.f);
        gemm_k<float, 0, false, false><<<dim3(Dc / 64, Sc / 64), 256, 0, stream>>>(
            h, vw_l, vb_l, nullptr, vv_, nullptr, Sc, Dc, Dc, 1.f);
        attn_scores_k<<<dim3(Sc / 64, Sc / 64, Hc), 256, 0, stream>>>(qv_, kv_, sc, flag);
        softmax_k<<<Hc * Sc, 256, 0, stream>>>(sc, sc, Sc, 0);
        attn_av_k<<<dim3(Sc / 64, Hc), 256, 0, stream>>>(sc, vv_, aov);
        gemm_k<float, 0, false, false><<<dim3(Dc / 64, Sc / 64), 256, 0, stream>>>(
            aov, ow_l, ob_l, nullptr, obv, nullptr, Sc, Dc, Dc, 1.f);
        softmax_k<<<Sc, 256, 0, stream>>>(obv, obv, Dc, 1); // forward hook: clip+softmax over D
        add_ln_k<true><<<MR, 256, 0, stream>>>(h, obv, ln1g + l * Dc, ln1b + l * Dc);

        // FFN (all batches)
        gemm_k<float, 1, false, true><<<dim3(DFFc / 64, MR / 64), 256, 0, stream>>>(
            h, w1_l, b1_l, nullptr, nullptr, mid, MR, DFFc, Dc, 1.f);
        gemm_k<bf16, 0, false, false><<<dim3(Dc / 64, MR / 64), 256, 0, stream>>>(
            mid, w2_l, b2_l, nullptr, ff, nullptr, MR, Dc, DFFc, 1.f);
        add_ln_k<false><<<MR, 256, 0, stream>>>(h, ff, ln2g + l * Dc, ln2b + l * Dc);
    }

    // head: fc1, 5x fc2, fc3 -> fp32 out
    gemm_k<float, 0, false, false><<<dim3(HIDc / 64, MR / 64), 256, 0, stream>>>(
        h, fc1w, fc1b, nullptr, t1, nullptr, MR, HIDc, Dc, 1.f);
    for (int r = 0; r < 5; ++r) {
        float* s_ = (r & 1) ? t2 : t1;
        float* d_ = (r & 1) ? t1 : t2;
        gemm_k<float, 0, false, false><<<dim3(HIDc / 64, MR / 64), 256, 0, stream>>>(
            s_, fc2w, fc2b, nullptr, d_, nullptr, MR, HIDc, HIDc, 1.f);
    }
    gemm_k<float, 0, false, false><<<dim3(OUTc / 64, MR / 64), 256, 0, stream>>>(
        t2, fc3w, fc3b, nullptr, (float*)d_out, nullptr, MR, OUTc, HIDc, 1.f);
}

// Round 4
// 2150.248 us; speedup vs baseline: 3.6813x; 3.6813x over previous
//
#include <hip/hip_runtime.h>
#include <hip/hip_bf16.h>

using bf16 = __hip_bfloat16;
typedef __attribute__((ext_vector_type(8))) short short8v;
typedef __attribute__((ext_vector_type(4))) float floatx4;

// Problem dims
constexpr int Bc = 16, Sc = 512, INc = 512, OUTc = 256;
constexpr int Dc = 1024, Hc = 16, Lc = 6, DFFc = 2048, HIDc = 256;
constexpr float SCALEc = 0.125f; // HD^-0.5

__device__ inline ushort f2b(float f) { // fp32 -> bf16 RNE
    union { float f; unsigned u; } v; v.f = f;
    unsigned r = (v.u + 0x7FFF + ((v.u >> 16) & 1)) >> 16;
    return (ushort)r;
}
__device__ inline float b2f(ushort b) {
    union { unsigned u; float f; } v; v.u = ((unsigned)b) << 16;
    return v.f;
}
__device__ inline float ldf(const float* p) { return *p; }
__device__ inline float ldf(const ushort* p) { return b2f(*p); }
__device__ inline float ldf(const bf16* p) { return __bfloat162float(*p); }

// ---------------- block reductions (256 threads, wave64) ----------------
__device__ inline float blockSum256(float v) {
    __shared__ float tmp[4];
#pragma unroll
    for (int o = 32; o > 0; o >>= 1) v += __shfl_xor(v, o, 64);
    int w = threadIdx.x >> 6;
    __syncthreads();
    if ((threadIdx.x & 63) == 0) tmp[w] = v;
    __syncthreads();
    return tmp[0] + tmp[1] + tmp[2] + tmp[3];
}
__device__ inline float blockMax256(float v) {
    __shared__ float tmp[4];
#pragma unroll
    for (int o = 32; o > 0; o >>= 1) v = fmaxf(v, __shfl_xor(v, o, 64));
    int w = threadIdx.x >> 6;
    __syncthreads();
    if ((threadIdx.x & 63) == 0) tmp[w] = v;
    __syncthreads();
    return fmaxf(fmaxf(tmp[0], tmp[1]), fmaxf(tmp[2], tmp[3]));
}

// ---------------- mask flag: (sum(xm[0,:]) == 0) ----------------
__global__ __launch_bounds__(256) void mask_k(const float* __restrict__ xm, float* __restrict__ flag) {
    float s = xm[threadIdx.x] + xm[threadIdx.x + 256];
    s = blockSum256(s);
    if (threadIdx.x == 0) flag[0] = (s == 0.f) ? 1.f : 0.f;
}

// ---------------- weight transpose + bf16 cvt: Wt[n][k] = bf16(W[k][n]) ----------------
// 64x64 tiles. W: [K][N] fp32 row-major. Wt: [N][K] bf16 row-major.
__global__ __launch_bounds__(256) void transp_k(const float* __restrict__ W, ushort* __restrict__ Wt,
                                                int K, int N) {
    __shared__ float Ls[64][65];
    const int t = threadIdx.x;
    const int n0 = blockIdx.x * 64, k0 = blockIdx.y * 64;
    const int kr = t >> 4, n4 = (t & 15) * 4;
#pragma unroll
    for (int p = 0; p < 4; ++p) {
        float4 v = *(const float4*)&W[(size_t)(k0 + kr + p * 16) * N + n0 + n4];
        Ls[kr + p * 16][n4 + 0] = v.x; Ls[kr + p * 16][n4 + 1] = v.y;
        Ls[kr + p * 16][n4 + 2] = v.z; Ls[kr + p * 16][n4 + 3] = v.w;
    }
    __syncthreads();
    const int nr = t >> 4, k4 = (t & 15) * 4;
#pragma unroll
    for (int p = 0; p < 4; ++p) {
        ushort4 o;
        o.x = f2b(Ls[k4 + 0][nr + p * 16]); o.y = f2b(Ls[k4 + 1][nr + p * 16]);
        o.z = f2b(Ls[k4 + 2][nr + p * 16]); o.w = f2b(Ls[k4 + 3][nr + p * 16]);
        *(ushort4*)&Wt[(size_t)(n0 + nr + p * 16) * K + k0 + k4] = o;
    }
}

// ---------------- 16-elt loaders for MFMA staging (fp32->bf16 cvt or raw bf16) -----------
__device__ inline void ld16(const float* s, ushort* d) {
#pragma unroll
    for (int i = 0; i < 4; ++i) {
        float4 v = *(const float4*)(s + i * 4);
        d[i * 4 + 0] = f2b(v.x); d[i * 4 + 1] = f2b(v.y);
        d[i * 4 + 2] = f2b(v.z); d[i * 4 + 3] = f2b(v.w);
    }
}
__device__ inline void ld16(const ushort* s, ushort* d) {
    *(short8v*)d = *(const short8v*)s;
    *(short8v*)(d + 8) = *(const short8v*)(s + 8);
}

// ---------------- MFMA GEMM: C[M,N] = act((A[M,K] @ W + bias [+pos]) * scale) ----------
// A: fp32 or bf16(ushort) row-major [M][K]. Bt: bf16 [N][K] (pre-transposed weight).
// 128x128 tile, BK=64, 256 thr = 4 waves (2x2), each wave 64x64 via 4x4 frags of 16x16x32.
// LDS XOR-swizzle: elem_col ^= (row&7)*8  (16B groups spread across bank-quads, G4).
template <typename TA, int ACT, bool ADDPOS, bool OUT_BF16>
__global__ __launch_bounds__(256) void mgemm_k(
    const TA* __restrict__ A, const ushort* __restrict__ Bt,
    const float* __restrict__ bias, const float* __restrict__ pos,
    float* __restrict__ Cf, ushort* __restrict__ Cb,
    int M, int N, int K, float scale)
{
    __shared__ __align__(16) ushort As[128 * 64];
    __shared__ __align__(16) ushort Bs[128 * 64];
    const int tid = threadIdx.x;
    const int m0 = blockIdx.y * 128, n0 = blockIdx.x * 128;
    const int lane = tid & 63, wv = tid >> 6;
    const int wm = (wv >> 1) * 64, wn = (wv & 1) * 64;
    floatx4 acc[4][4] = {};

    const int srow = tid >> 2, scg = tid & 3; // staging: row(+64/pass), 16-k chunk

    for (int k0 = 0; k0 < K; k0 += 64) {
#pragma unroll
        for (int p = 0; p < 2; ++p) {
            const int r = srow + p * 64;
            __align__(16) ushort ta[16], tb[16];
            ld16(&A[(size_t)(m0 + r) * K + k0 + scg * 16], ta);
            ld16(&Bt[(size_t)(n0 + r) * K + k0 + scg * 16], tb);
            const int base = r * 64, sw = (r & 7) * 8;
            *(short8v*)&As[base + ((scg * 16 + 0) ^ sw)] = *(short8v*)&ta[0];
            *(short8v*)&As[base + ((scg * 16 + 8) ^ sw)] = *(short8v*)&ta[8];
            *(short8v*)&Bs[base + ((scg * 16 + 0) ^ sw)] = *(short8v*)&tb[0];
            *(short8v*)&Bs[base + ((scg * 16 + 8) ^ sw)] = *(short8v*)&tb[8];
        }
        __syncthreads();
#pragma unroll
        for (int s = 0; s < 2; ++s) {
            short8v af[4], bf_[4];
            const int kg = s * 32 + (lane >> 4) * 8;
#pragma unroll
            for (int f = 0; f < 4; ++f) {
                const int ra = wm + f * 16 + (lane & 15);
                af[f] = *(const short8v*)&As[ra * 64 + (kg ^ ((ra & 7) * 8))];
                const int rb = wn + f * 16 + (lane & 15);
                bf_[f] = *(const short8v*)&Bs[rb * 64 + (kg ^ ((rb & 7) * 8))];
            }
#pragma unroll
            for (int i = 0; i < 4; ++i)
#pragma unroll
                for (int j = 0; j < 4; ++j)
                    acc[i][j] = __builtin_amdgcn_mfma_f32_16x16x32_bf16(af[i], bf_[j], acc[i][j], 0, 0, 0);
        }
        __syncthreads();
    }

    // epilogue: C/D layout col=lane&15, row=(lane>>4)*4+reg (m89)
    const int cc = lane & 15, rr4 = (lane >> 4) * 4;
#pragma unroll
    for (int i = 0; i < 4; ++i) {
#pragma unroll
        for (int j = 0; j < 4; ++j) {
            const int col = n0 + wn + j * 16 + cc;
            const float bsv = bias[col];
#pragma unroll
            for (int q = 0; q < 4; ++q) {
                const int row = m0 + wm + i * 16 + rr4 + q;
                float v = acc[i][j][q] + bsv;
                if (ADDPOS) v += pos[(size_t)(row & (Sc - 1)) * N + col];
                v *= scale;
                if (ACT == 1) v = fmaxf(v, 0.f);
                if (OUT_BF16) Cb[(size_t)row * N + col] = f2b(v);
                else          Cf[(size_t)row * N + col] = v;
            }
        }
    }
}

// ---------------- fp32 VALU GEMM (head only): C = A@W + bias ----------------
template <typename TA, int ACT, bool ADDPOS, bool OUT_BF16>
__global__ __launch_bounds__(256) void gemm_k(
    const TA* __restrict__ A, const float* __restrict__ W,
    const float* __restrict__ bias, const float* __restrict__ pos,
    float* __restrict__ Cf, bf16* __restrict__ Cb,
    int M, int N, int K, float scale)
{
    __shared__ float As[16][68];
    __shared__ float Ws[16][68];
    const int tid = threadIdx.x;
    const int m0 = blockIdx.y * 64, n0 = blockIdx.x * 64;
    const int ty = tid >> 4, tx = tid & 15;
    float c[4][4] = {};

    const int ka = tid & 15, mb = tid >> 4;
    const int nw = tid & 63, kb = tid >> 6;

    for (int k0 = 0; k0 < K; k0 += 16) {
#pragma unroll
        for (int j = 0; j < 4; ++j) {
            int m = mb + 16 * j;
            As[ka][m] = ldf(&A[(size_t)(m0 + m) * K + k0 + ka]);
        }
#pragma unroll
        for (int j = 0; j < 4; ++j) {
            int k = kb + 4 * j;
            Ws[k][nw] = W[(size_t)(k0 + k) * N + n0 + nw];
        }
        __syncthreads();
#pragma unroll
        for (int k = 0; k < 16; ++k) {
            float4 av = *(const float4*)&As[k][ty * 4];
            float4 wv = *(const float4*)&Ws[k][tx * 4];
            float a[4] = {av.x, av.y, av.z, av.w};
            float w[4] = {wv.x, wv.y, wv.z, wv.w};
#pragma unroll
            for (int i = 0; i < 4; ++i)
#pragma unroll
                for (int j = 0; j < 4; ++j) c[i][j] += a[i] * w[j];
        }
        __syncthreads();
    }

#pragma unroll
    for (int i = 0; i < 4; ++i) {
        int m = m0 + ty * 4 + i;
#pragma unroll
        for (int j = 0; j < 4; ++j) {
            int n = n0 + tx * 4 + j;
            float v = c[i][j] + bias[n];
            if (ADDPOS) v += pos[(size_t)(m & (Sc - 1)) * N + n];
            v *= scale;
            if (ACT == 1) v = fmaxf(v, 0.f);
            if (OUT_BF16) Cb[(size_t)m * N + n] = __float2bfloat16(v);
            else          Cf[(size_t)m * N + n] = v;
        }
    }
}

// ---------------- attention scores (batch 0): sc[h,t,s] = clip(q_h[t]·k_h[s]) ----------------
__global__ __launch_bounds__(256) void attn_scores_k(
    const float* __restrict__ q, const float* __restrict__ k,
    float* __restrict__ sc, const float* __restrict__ flag)
{
    const int hh = blockIdx.z;
    const int t0 = blockIdx.y * 64, s0 = blockIdx.x * 64;
    __shared__ float qs[64][68];
    __shared__ float kst[64][68];
    const int tid = threadIdx.x;
    const int c4 = tid & 15, r0 = tid >> 4;
#pragma unroll
    for (int j = 0; j < 4; ++j) {
        int rr = r0 + 16 * j;
        float4 qv = *(const float4*)&q[(size_t)(t0 + rr) * Dc + hh * 64 + c4 * 4];
        *(float4*)&qs[rr][c4 * 4] = qv;
        float4 kv = *(const float4*)&k[(size_t)(s0 + rr) * Dc + hh * 64 + c4 * 4];
        kst[c4 * 4 + 0][rr] = kv.x; kst[c4 * 4 + 1][rr] = kv.y;
        kst[c4 * 4 + 2][rr] = kv.z; kst[c4 * 4 + 3][rr] = kv.w;
    }
    __syncthreads();
    const int ty = tid >> 4, tx = tid & 15;
    float c[4][4] = {};
#pragma unroll 8
    for (int d = 0; d < 64; ++d) {
        float a[4];
#pragma unroll
        for (int i = 0; i < 4; ++i) a[i] = qs[ty * 4 + i][d];
        float4 bv = *(const float4*)&kst[d][tx * 4];
        float b[4] = {bv.x, bv.y, bv.z, bv.w};
#pragma unroll
        for (int i = 0; i < 4; ++i)
#pragma unroll
            for (int j = 0; j < 4; ++j) c[i][j] += a[i] * b[j];
    }
    const bool msk = flag[0] > 0.5f;
    float* scp = sc + (size_t)hh * Sc * Sc;
#pragma unroll
    for (int i = 0; i < 4; ++i)
#pragma unroll
        for (int j = 0; j < 4; ++j) {
            float v = fminf(fmaxf(c[i][j], -10.f), 10.f);
            if (msk) v = -10.f;
            scp[(size_t)(t0 + ty * 4 + i) * Sc + s0 + tx * 4 + j] = v;
        }
}

// ---------------- row softmax (in-place safe). doclip: clamp [-10,10] first ----------------
__global__ __launch_bounds__(256) void softmax_k(
    const float* __restrict__ in, float* __restrict__ out, int ncols, int doclip)
{
    const int row = blockIdx.x;
    const float* ip = in + (size_t)row * ncols;
    float* op = out + (size_t)row * ncols;
    const int nj = ncols >> 8;
    float r[4];
    float mx = -1e30f;
    for (int j = 0; j < nj; ++j) {
        float v = ip[threadIdx.x + 256 * j];
        if (doclip) v = fminf(fmaxf(v, -10.f), 10.f);
        r[j] = v;
        mx = fmaxf(mx, v);
    }
    mx = blockMax256(mx);
    float s = 0.f;
    for (int j = 0; j < nj; ++j) { r[j] = expf(r[j] - mx); s += r[j]; }
    s = blockSum256(s);
    float inv = 1.f / s;
    for (int j = 0; j < nj; ++j) op[threadIdx.x + 256 * j] = r[j] * inv;
}

// ---------------- attention AV (batch 0) ----------------
__global__ __launch_bounds__(256) void attn_av_k(
    const float* __restrict__ aw, const float* __restrict__ v, float* __restrict__ ao)
{
    const int hh = blockIdx.y;
    const int t0 = blockIdx.x * 64;
    __shared__ float as_[64][68];
    __shared__ float vs[64][68];
    const int tid = threadIdx.x;
    const int c4 = tid & 15, r0 = tid >> 4;
    const int ty = tid >> 4, tx = tid & 15;
    float c[4][4] = {};
    for (int s0 = 0; s0 < Sc; s0 += 64) {
#pragma unroll
        for (int j = 0; j < 4; ++j) {
            int rr = r0 + 16 * j;
            float4 avv = *(const float4*)&aw[(size_t)hh * Sc * Sc + (size_t)(t0 + rr) * Sc + s0 + c4 * 4];
            *(float4*)&as_[rr][c4 * 4] = avv;
            float4 vv = *(const float4*)&v[(size_t)(s0 + rr) * Dc + hh * 64 + c4 * 4];
            *(float4*)&vs[rr][c4 * 4] = vv;
        }
        __syncthreads();
#pragma unroll 8
        for (int ss = 0; ss < 64; ++ss) {
            float a[4];
#pragma unroll
            for (int i = 0; i < 4; ++i) a[i] = as_[ty * 4 + i][ss];
            float4 bv = *(const float4*)&vs[ss][tx * 4];
            float b[4] = {bv.x, bv.y, bv.z, bv.w};
#pragma unroll
            for (int i = 0; i < 4; ++i)
#pragma unroll
                for (int j = 0; j < 4; ++j) c[i][j] += a[i] * b[j];
        }
        __syncthreads();
    }
#pragma unroll
    for (int i = 0; i < 4; ++i)
#pragma unroll
        for (int j = 0; j < 4; ++j)
            ao[(size_t)(t0 + ty * 4 + i) * Dc + hh * 64 + tx * 4 + j] = c[i][j];
}

// ---------------- h = LN(h + add) ; add broadcast over batch if BCAST ----------------
template <bool BCAST, typename TADD>
__global__ __launch_bounds__(256) void add_ln_k(
    float* __restrict__ h, const TADD* __restrict__ add,
    const float* __restrict__ g, const float* __restrict__ b)
{
    const int row = blockIdx.x;
    const TADD* ap = BCAST ? add + (size_t)(row & (Sc - 1)) * Dc : add + (size_t)row * Dc;
    float* hp = h + (size_t)row * Dc;
    const int tid = threadIdx.x;
    float x[4];
    float s = 0.f;
#pragma unroll
    for (int j = 0; j < 4; ++j) {
        int cidx = tid + 256 * j;
        x[j] = hp[cidx] + ldf(&ap[cidx]);
        s += x[j];
    }
    float mean = blockSum256(s) * (1.f / (float)Dc);
    float vsum = 0.f;
#pragma unroll
    for (int j = 0; j < 4; ++j) { float d = x[j] - mean; vsum += d * d; }
    float var = blockSum256(vsum) * (1.f / (float)Dc);
    float inv = rsqrtf(var + 1e-5f);
#pragma unroll
    for (int j = 0; j < 4; ++j) {
        int cidx = tid + 256 * j;
        hp[cidx] = (x[j] - mean) * inv * g[cidx] + b[cidx];
    }
}

// ---------------- launch ----------------
extern "C" void kernel_launch(void* const* d_in, const int* in_sizes, int n_in,
                              void* d_out, int out_size, void* d_ws, size_t ws_size,
                              hipStream_t stream)
{
    const float* x      = (const float*)d_in[0];
    const float* xm     = (const float*)d_in[1];
    // d_in[2] vecSelector: assert-only, unused
    const float* proj_w = (const float*)d_in[3];
    const float* proj_b = (const float*)d_in[4];
    const float* pos    = (const float*)d_in[5];
    const float* qw     = (const float*)d_in[6];
    const float* qb     = (const float*)d_in[7];
    const float* kw     = (const float*)d_in[8];
    const float* kb     = (const float*)d_in[9];
    const float* vw     = (const float*)d_in[10];
    const float* vb     = (const float*)d_in[11];
    const float* ow     = (const float*)d_in[12];
    const float* obias  = (const float*)d_in[13];
    const float* ln1g   = (const float*)d_in[14];
    const float* ln1b   = (const float*)d_in[15];
    const float* ln2g   = (const float*)d_in[16];
    const float* ln2b   = (const float*)d_in[17];
    const float* w1     = (const float*)d_in[18];
    const float* b1     = (const float*)d_in[19];
    const float* w2     = (const float*)d_in[20];
    const float* b2     = (const float*)d_in[21];
    const float* fc1w   = (const float*)d_in[22];
    const float* fc1b   = (const float*)d_in[23];
    const float* fc2w   = (const float*)d_in[24];
    const float* fc2b   = (const float*)d_in[25];
    const float* fc3w   = (const float*)d_in[26];
    const float* fc3b   = (const float*)d_in[27];

    float* ws = (float*)d_ws;
    const size_t HSZ = (size_t)Bc * Sc * Dc; // 8,388,608 floats
    float* h    = ws;                 // fp32 residual stream, 32 MB
    float* rgA  = ws + HSZ;           // attn temps | FFN mid (bf16), 32 MB
    float* rgB  = ws + 2 * HSZ;       // ff(bf16) + Wt | head temps + Wt, 32 MB
    float* flag = ws + 3 * HSZ;       // total footprint ~96.5 MB (validated round 3)

    float* sc  = rgA;                                  // 16*512*512
    float* qv_ = rgA + (size_t)Hc * Sc * Sc;
    float* kv_ = qv_ + (size_t)Sc * Dc;
    float* vv_ = kv_ + (size_t)Sc * Dc;
    float* aov = vv_ + (size_t)Sc * Dc;
    float* obv = aov + (size_t)Sc * Dc;
    ushort* midu = (ushort*)rgA;                       // 8192*2048 bf16 (FFN phase)
    ushort* ffu  = (ushort*)rgB;                       // 8192*1024 bf16
    ushort* Wt   = (ushort*)(rgB + (size_t)4 * 1024 * 1024); // rolling bf16 W^T, <=4MB
    float* t1  = rgB;                                  // head: 8192*256 fp32
    float* t2  = rgB + (size_t)Bc * Sc * HIDc;

    const int MR = Bc * Sc; // 8192

    mask_k<<<1, 256, 0, stream>>>(xm, flag);

    // h = x @ proj_w + proj_b + pos   (MFMA)
    transp_k<<<dim3(Dc / 64, INc / 64), 256, 0, stream>>>(proj_w, Wt, INc, Dc);
    mgemm_k<float, 0, true, false><<<dim3(Dc / 128, MR / 128), 256, 0, stream>>>(
        x, Wt, proj_b, pos, h, nullptr, MR, Dc, INc, 1.f);

    for (int l = 0; l < Lc; ++l) {
        const float* qw_l = qw + (size_t)l * Dc * Dc; const float* qb_l = qb + l * Dc;
        const float* kw_l = kw + (size_t)l * Dc * Dc; const float* kb_l = kb + l * Dc;
        const float* vw_l = vw + (size_t)l * Dc * Dc; const float* vb_l = vb + l * Dc;
        const float* ow_l = ow + (size_t)l * Dc * Dc; const float* ob_l = obias + l * Dc;
        const float* w1_l = w1 + (size_t)l * Dc * DFFc; const float* b1_l = b1 + l * DFFc;
        const float* w2_l = w2 + (size_t)l * DFFc * Dc; const float* b2_l = b2 + l * Dc;

        // attention: batch 0 only (sa = ao[0] is all that survives)
        transp_k<<<dim3(Dc / 64, Dc / 64), 256, 0, stream>>>(qw_l, Wt, Dc, Dc);
        mgemm_k<float, 0, false, false><<<dim3(Dc / 128, Sc / 128), 256, 0, stream>>>(
            h, Wt, qb_l, nullptr, qv_, nullptr, Sc, Dc, Dc, SCALEc);
        transp_k<<<dim3(Dc / 64, Dc / 64), 256, 0, stream>>>(kw_l, Wt, Dc, Dc);
        mgemm_k<float, 0, false, false><<<dim3(Dc / 128, Sc / 128), 256, 0, stream>>>(
            h, Wt, kb_l, nullptr, kv_, nullptr, Sc, Dc, Dc, 1.f);
        transp_k<<<dim3(Dc / 64, Dc / 64), 256, 0, stream>>>(vw_l, Wt, Dc, Dc);
        mgemm_k<float, 0, false, false><<<dim3(Dc / 128, Sc / 128), 256, 0, stream>>>(
            h, Wt, vb_l, nullptr, vv_, nullptr, Sc, Dc, Dc, 1.f);
        attn_scores_k<<<dim3(Sc / 64, Sc / 64, Hc), 256, 0, stream>>>(qv_, kv_, sc, flag);
        softmax_k<<<Hc * Sc, 256, 0, stream>>>(sc, sc, Sc, 0);
        attn_av_k<<<dim3(Sc / 64, Hc), 256, 0, stream>>>(sc, vv_, aov);
        transp_k<<<dim3(Dc / 64, Dc / 64), 256, 0, stream>>>(ow_l, Wt, Dc, Dc);
        mgemm_k<float, 0, false, false><<<dim3(Dc / 128, Sc / 128), 256, 0, stream>>>(
            aov, Wt, ob_l, nullptr, obv, nullptr, Sc, Dc, Dc, 1.f);
        softmax_k<<<Sc, 256, 0, stream>>>(obv, obv, Dc, 1); // forward hook: clip+softmax over D
        add_ln_k<true, float><<<MR, 256, 0, stream>>>(h, obv, ln1g + l * Dc, ln1b + l * Dc);

        // FFN (all batches, MFMA)
        transp_k<<<dim3(DFFc / 64, Dc / 64), 256, 0, stream>>>(w1_l, Wt, Dc, DFFc);
        mgemm_k<float, 1, false, true><<<dim3(DFFc / 128, MR / 128), 256, 0, stream>>>(
            h, Wt, b1_l, nullptr, nullptr, midu, MR, DFFc, Dc, 1.f);
        transp_k<<<dim3(Dc / 64, DFFc / 64), 256, 0, stream>>>(w2_l, Wt, DFFc, Dc);
        mgemm_k<ushort, 0, false, true><<<dim3(Dc / 128, MR / 128), 256, 0, stream>>>(
            midu, Wt, b2_l, nullptr, nullptr, ffu, MR, Dc, DFFc, 1.f);
        add_ln_k<false, ushort><<<MR, 256, 0, stream>>>(h, ffu, ln2g + l * Dc, ln2b + l * Dc);
    }

    // head: fc1, 5x fc2, fc3 -> fp32 out (VALU fp32, preserves precision margin)
    gemm_k<float, 0, false, false><<<dim3(HIDc / 64, MR / 64), 256, 0, stream>>>(
        h, fc1w, fc1b, nullptr, t1, nullptr, MR, HIDc, Dc, 1.f);
    for (int r = 0; r < 5; ++r) {
        float* s_ = (r & 1) ? t2 : t1;
        float* d_ = (r & 1) ? t1 : t2;
        gemm_k<float, 0, false, false><<<dim3(HIDc / 64, MR / 64), 256, 0, stream>>>(
            s_, fc2w, fc2b, nullptr, d_, nullptr, MR, HIDc, HIDc, 1.f);
    }
    gemm_k<float, 0, false, false><<<dim3(OUTc / 64, MR / 64), 256, 0, stream>>>(
        t2, fc3w, fc3b, nullptr, (float*)d_out, nullptr, MR, OUTc, HIDc, 1.f);
}

// Round 5
// 2113.473 us; speedup vs baseline: 3.7454x; 1.0174x over previous
//
#include <hip/hip_runtime.h>
#include <hip/hip_bf16.h>

using bf16 = __hip_bfloat16;
typedef __attribute__((ext_vector_type(8))) short short8v;
typedef __attribute__((ext_vector_type(4))) float floatx4;

// Problem dims
constexpr int Bc = 16, Sc = 512, INc = 512, OUTc = 256;
constexpr int Dc = 1024, Hc = 16, Lc = 6, DFFc = 2048, HIDc = 256;
constexpr float SCALEc = 0.125f; // HD^-0.5

__device__ inline ushort f2b(float f) { // fp32 -> bf16 RNE
    union { float f; unsigned u; } v; v.f = f;
    unsigned r = (v.u + 0x7FFF + ((v.u >> 16) & 1)) >> 16;
    return (ushort)r;
}
__device__ inline float b2f(ushort b) {
    union { unsigned u; float f; } v; v.u = ((unsigned)b) << 16;
    return v.f;
}
__device__ inline float ldf(const float* p) { return *p; }
__device__ inline float ldf(const ushort* p) { return b2f(*p); }
__device__ inline float ldf(const bf16* p) { return __bfloat162float(*p); }

// ---------------- block reductions (256 threads, wave64) ----------------
__device__ inline float blockSum256(float v) {
    __shared__ float tmp[4];
#pragma unroll
    for (int o = 32; o > 0; o >>= 1) v += __shfl_xor(v, o, 64);
    int w = threadIdx.x >> 6;
    __syncthreads();
    if ((threadIdx.x & 63) == 0) tmp[w] = v;
    __syncthreads();
    return tmp[0] + tmp[1] + tmp[2] + tmp[3];
}
__device__ inline float blockMax256(float v) {
    __shared__ float tmp[4];
#pragma unroll
    for (int o = 32; o > 0; o >>= 1) v = fmaxf(v, __shfl_xor(v, o, 64));
    int w = threadIdx.x >> 6;
    __syncthreads();
    if ((threadIdx.x & 63) == 0) tmp[w] = v;
    __syncthreads();
    return fmaxf(fmaxf(tmp[0], tmp[1]), fmaxf(tmp[2], tmp[3]));
}

// ---------------- mask flag: (sum(xm[0,:]) == 0) ----------------
__global__ __launch_bounds__(256) void mask_k(const float* __restrict__ xm, float* __restrict__ flag) {
    float s = xm[threadIdx.x] + xm[threadIdx.x + 256];
    s = blockSum256(s);
    if (threadIdx.x == 0) flag[0] = (s == 0.f) ? 1.f : 0.f;
}

// ---------------- weight transpose + bf16 cvt: Wt[n][k] = bf16(W[k][n]) ----------------
__global__ __launch_bounds__(256) void transp_k(const float* __restrict__ W, ushort* __restrict__ Wt,
                                                int K, int N) {
    __shared__ float Ls[64][65];
    const int t = threadIdx.x;
    const int n0 = blockIdx.x * 64, k0 = blockIdx.y * 64;
    const int kr = t >> 4, n4 = (t & 15) * 4;
#pragma unroll
    for (int p = 0; p < 4; ++p) {
        float4 v = *(const float4*)&W[(size_t)(k0 + kr + p * 16) * N + n0 + n4];
        Ls[kr + p * 16][n4 + 0] = v.x; Ls[kr + p * 16][n4 + 1] = v.y;
        Ls[kr + p * 16][n4 + 2] = v.z; Ls[kr + p * 16][n4 + 3] = v.w;
    }
    __syncthreads();
    const int nr = t >> 4, k4 = (t & 15) * 4;
#pragma unroll
    for (int p = 0; p < 4; ++p) {
        ushort4 o;
        o.x = f2b(Ls[k4 + 0][nr + p * 16]); o.y = f2b(Ls[k4 + 1][nr + p * 16]);
        o.z = f2b(Ls[k4 + 2][nr + p * 16]); o.w = f2b(Ls[k4 + 3][nr + p * 16]);
        *(ushort4*)&Wt[(size_t)(n0 + nr + p * 16) * K + k0 + k4] = o;
    }
}

// ---------------- 16-elt loaders for MFMA staging ----------------
__device__ inline void ld16(const float* s, ushort* d) {
#pragma unroll
    for (int i = 0; i < 4; ++i) {
        float4 v = *(const float4*)(s + i * 4);
        d[i * 4 + 0] = f2b(v.x); d[i * 4 + 1] = f2b(v.y);
        d[i * 4 + 2] = f2b(v.z); d[i * 4 + 3] = f2b(v.w);
    }
}
__device__ inline void ld16(const ushort* s, ushort* d) {
    *(short8v*)d = *(const short8v*)s;
    *(short8v*)(d + 8) = *(const short8v*)(s + 8);
}

// ---------------- MFMA GEMM (128x128 tile, BK=64, 4 waves, XOR-swizzled LDS) ----------
template <typename TA, int ACT, bool ADDPOS, bool OUT_BF16>
__global__ __launch_bounds__(256) void mgemm_k(
    const TA* __restrict__ A, const ushort* __restrict__ Bt,
    const float* __restrict__ bias, const float* __restrict__ pos,
    float* __restrict__ Cf, ushort* __restrict__ Cb,
    int M, int N, int K, float scale)
{
    __shared__ __align__(16) ushort As[128 * 64];
    __shared__ __align__(16) ushort Bs[128 * 64];
    const int tid = threadIdx.x;
    const int m0 = blockIdx.y * 128, n0 = blockIdx.x * 128;
    const int lane = tid & 63, wv = tid >> 6;
    const int wm = (wv >> 1) * 64, wn = (wv & 1) * 64;
    floatx4 acc[4][4] = {};

    const int srow = tid >> 2, scg = tid & 3;

    for (int k0 = 0; k0 < K; k0 += 64) {
#pragma unroll
        for (int p = 0; p < 2; ++p) {
            const int r = srow + p * 64;
            __align__(16) ushort ta[16], tb[16];
            ld16(&A[(size_t)(m0 + r) * K + k0 + scg * 16], ta);
            ld16(&Bt[(size_t)(n0 + r) * K + k0 + scg * 16], tb);
            const int base = r * 64, sw = (r & 7) * 8;
            *(short8v*)&As[base + ((scg * 16 + 0) ^ sw)] = *(short8v*)&ta[0];
            *(short8v*)&As[base + ((scg * 16 + 8) ^ sw)] = *(short8v*)&ta[8];
            *(short8v*)&Bs[base + ((scg * 16 + 0) ^ sw)] = *(short8v*)&tb[0];
            *(short8v*)&Bs[base + ((scg * 16 + 8) ^ sw)] = *(short8v*)&tb[8];
        }
        __syncthreads();
#pragma unroll
        for (int s = 0; s < 2; ++s) {
            short8v af[4], bf_[4];
            const int kg = s * 32 + (lane >> 4) * 8;
#pragma unroll
            for (int f = 0; f < 4; ++f) {
                const int ra = wm + f * 16 + (lane & 15);
                af[f] = *(const short8v*)&As[ra * 64 + (kg ^ ((ra & 7) * 8))];
                const int rb = wn + f * 16 + (lane & 15);
                bf_[f] = *(const short8v*)&Bs[rb * 64 + (kg ^ ((rb & 7) * 8))];
            }
#pragma unroll
            for (int i = 0; i < 4; ++i)
#pragma unroll
                for (int j = 0; j < 4; ++j)
                    acc[i][j] = __builtin_amdgcn_mfma_f32_16x16x32_bf16(af[i], bf_[j], acc[i][j], 0, 0, 0);
        }
        __syncthreads();
    }

    const int cc = lane & 15, rr4 = (lane >> 4) * 4;
#pragma unroll
    for (int i = 0; i < 4; ++i) {
#pragma unroll
        for (int j = 0; j < 4; ++j) {
            const int col = n0 + wn + j * 16 + cc;
            const float bsv = bias[col];
#pragma unroll
            for (int q = 0; q < 4; ++q) {
                const int row = m0 + wm + i * 16 + rr4 + q;
                float v = acc[i][j][q] + bsv;
                if (ADDPOS) v += pos[(size_t)(row & (Sc - 1)) * N + col];
                v *= scale;
                if (ACT == 1) v = fmaxf(v, 0.f);
                if (OUT_BF16) Cb[(size_t)row * N + col] = f2b(v);
                else          Cf[(size_t)row * N + col] = v;
            }
        }
    }
}

// ---------------- fp32 VALU GEMM (head composition): C = A@W [+ bias] ----------------
template <typename TA, int ACT, bool ADDPOS, bool OUT_BF16, bool HASB>
__global__ __launch_bounds__(256) void gemm_k(
    const TA* __restrict__ A, const float* __restrict__ W,
    const float* __restrict__ bias, const float* __restrict__ pos,
    float* __restrict__ Cf, bf16* __restrict__ Cb,
    int M, int N, int K, float scale)
{
    __shared__ float As[16][68];
    __shared__ float Ws[16][68];
    const int tid = threadIdx.x;
    const int m0 = blockIdx.y * 64, n0 = blockIdx.x * 64;
    const int ty = tid >> 4, tx = tid & 15;
    float c[4][4] = {};

    const int ka = tid & 15, mb = tid >> 4;
    const int nw = tid & 63, kb = tid >> 6;

    for (int k0 = 0; k0 < K; k0 += 16) {
#pragma unroll
        for (int j = 0; j < 4; ++j) {
            int m = mb + 16 * j;
            As[ka][m] = ldf(&A[(size_t)(m0 + m) * K + k0 + ka]);
        }
#pragma unroll
        for (int j = 0; j < 4; ++j) {
            int k = kb + 4 * j;
            Ws[k][nw] = W[(size_t)(k0 + k) * N + n0 + nw];
        }
        __syncthreads();
#pragma unroll
        for (int k = 0; k < 16; ++k) {
            float4 av = *(const float4*)&As[k][ty * 4];
            float4 wv = *(const float4*)&Ws[k][tx * 4];
            float a[4] = {av.x, av.y, av.z, av.w};
            float w[4] = {wv.x, wv.y, wv.z, wv.w};
#pragma unroll
            for (int i = 0; i < 4; ++i)
#pragma unroll
                for (int j = 0; j < 4; ++j) c[i][j] += a[i] * w[j];
        }
        __syncthreads();
    }

#pragma unroll
    for (int i = 0; i < 4; ++i) {
        int m = m0 + ty * 4 + i;
#pragma unroll
        for (int j = 0; j < 4; ++j) {
            int n = n0 + tx * 4 + j;
            float v = c[i][j] + (HASB ? bias[n] : 0.f);
            if (ADDPOS) v += pos[(size_t)(m & (Sc - 1)) * N + n];
            v *= scale;
            if (ACT == 1) v = fmaxf(v, 0.f);
            if (OUT_BF16) Cb[(size_t)m * N + n] = __float2bfloat16(v);
            else          Cf[(size_t)m * N + n] = v;
        }
    }
}

// ---------------- vec-mat: out[n] = sum_k v[k]*W[k][n] + b[n] (256x256) ----------------
__global__ __launch_bounds__(256) void vecmat_k(const float* __restrict__ v, const float* __restrict__ W,
                                                const float* __restrict__ b, float* __restrict__ out) {
    __shared__ float vs[256];
    vs[threadIdx.x] = v[threadIdx.x];
    __syncthreads();
    float s = b[threadIdx.x];
#pragma unroll 8
    for (int k = 0; k < 256; ++k) s += vs[k] * W[k * 256 + threadIdx.x];
    out[threadIdx.x] = s;
}

// ---------------- attention scores (batch 0) ----------------
__global__ __launch_bounds__(256) void attn_scores_k(
    const float* __restrict__ q, const float* __restrict__ k,
    float* __restrict__ sc, const float* __restrict__ flag)
{
    const int hh = blockIdx.z;
    const int t0 = blockIdx.y * 64, s0 = blockIdx.x * 64;
    __shared__ float qs[64][68];
    __shared__ float kst[64][68];
    const int tid = threadIdx.x;
    const int c4 = tid & 15, r0 = tid >> 4;
#pragma unroll
    for (int j = 0; j < 4; ++j) {
        int rr = r0 + 16 * j;
        float4 qv = *(const float4*)&q[(size_t)(t0 + rr) * Dc + hh * 64 + c4 * 4];
        *(float4*)&qs[rr][c4 * 4] = qv;
        float4 kv = *(const float4*)&k[(size_t)(s0 + rr) * Dc + hh * 64 + c4 * 4];
        kst[c4 * 4 + 0][rr] = kv.x; kst[c4 * 4 + 1][rr] = kv.y;
        kst[c4 * 4 + 2][rr] = kv.z; kst[c4 * 4 + 3][rr] = kv.w;
    }
    __syncthreads();
    const int ty = tid >> 4, tx = tid & 15;
    float c[4][4] = {};
#pragma unroll 8
    for (int d = 0; d < 64; ++d) {
        float a[4];
#pragma unroll
        for (int i = 0; i < 4; ++i) a[i] = qs[ty * 4 + i][d];
        float4 bv = *(const float4*)&kst[d][tx * 4];
        float b[4] = {bv.x, bv.y, bv.z, bv.w};
#pragma unroll
        for (int i = 0; i < 4; ++i)
#pragma unroll
            for (int j = 0; j < 4; ++j) c[i][j] += a[i] * b[j];
    }
    const bool msk = flag[0] > 0.5f;
    float* scp = sc + (size_t)hh * Sc * Sc;
#pragma unroll
    for (int i = 0; i < 4; ++i)
#pragma unroll
        for (int j = 0; j < 4; ++j) {
            float v = fminf(fmaxf(c[i][j], -10.f), 10.f);
            if (msk) v = -10.f;
            scp[(size_t)(t0 + ty * 4 + i) * Sc + s0 + tx * 4 + j] = v;
        }
}

// ---------------- row softmax ----------------
__global__ __launch_bounds__(256) void softmax_k(
    const float* __restrict__ in, float* __restrict__ out, int ncols, int doclip)
{
    const int row = blockIdx.x;
    const float* ip = in + (size_t)row * ncols;
    float* op = out + (size_t)row * ncols;
    const int nj = ncols >> 8;
    float r[4];
    float mx = -1e30f;
    for (int j = 0; j < nj; ++j) {
        float v = ip[threadIdx.x + 256 * j];
        if (doclip) v = fminf(fmaxf(v, -10.f), 10.f);
        r[j] = v;
        mx = fmaxf(mx, v);
    }
    mx = blockMax256(mx);
    float s = 0.f;
    for (int j = 0; j < nj; ++j) { r[j] = expf(r[j] - mx); s += r[j]; }
    s = blockSum256(s);
    float inv = 1.f / s;
    for (int j = 0; j < nj; ++j) op[threadIdx.x + 256 * j] = r[j] * inv;
}

// ---------------- attention AV (batch 0) ----------------
__global__ __launch_bounds__(256) void attn_av_k(
    const float* __restrict__ aw, const float* __restrict__ v, float* __restrict__ ao)
{
    const int hh = blockIdx.y;
    const int t0 = blockIdx.x * 64;
    __shared__ float as_[64][68];
    __shared__ float vs[64][68];
    const int tid = threadIdx.x;
    const int c4 = tid & 15, r0 = tid >> 4;
    const int ty = tid >> 4, tx = tid & 15;
    float c[4][4] = {};
    for (int s0 = 0; s0 < Sc; s0 += 64) {
#pragma unroll
        for (int j = 0; j < 4; ++j) {
            int rr = r0 + 16 * j;
            float4 avv = *(const float4*)&aw[(size_t)hh * Sc * Sc + (size_t)(t0 + rr) * Sc + s0 + c4 * 4];
            *(float4*)&as_[rr][c4 * 4] = avv;
            float4 vv = *(const float4*)&v[(size_t)(s0 + rr) * Dc + hh * 64 + c4 * 4];
            *(float4*)&vs[rr][c4 * 4] = vv;
        }
        __syncthreads();
#pragma unroll 8
        for (int ss = 0; ss < 64; ++ss) {
            float a[4];
#pragma unroll
            for (int i = 0; i < 4; ++i) a[i] = as_[ty * 4 + i][ss];
            float4 bv = *(const float4*)&vs[ss][tx * 4];
            float b[4] = {bv.x, bv.y, bv.z, bv.w};
#pragma unroll
            for (int i = 0; i < 4; ++i)
#pragma unroll
                for (int j = 0; j < 4; ++j) c[i][j] += a[i] * b[j];
        }
        __syncthreads();
    }
#pragma unroll
    for (int i = 0; i < 4; ++i)
#pragma unroll
        for (int j = 0; j < 4; ++j)
            ao[(size_t)(t0 + ty * 4 + i) * Dc + hh * 64 + tx * 4 + j] = c[i][j];
}

// ---------------- h = LN(h + add) ----------------
template <bool BCAST, typename TADD>
__global__ __launch_bounds__(256) void add_ln_k(
    float* __restrict__ h, const TADD* __restrict__ add,
    const float* __restrict__ g, const float* __restrict__ b)
{
    const int row = blockIdx.x;
    const TADD* ap = BCAST ? add + (size_t)(row & (Sc - 1)) * Dc : add + (size_t)row * Dc;
    float* hp = h + (size_t)row * Dc;
    const int tid = threadIdx.x;
    float x[4];
    float s = 0.f;
#pragma unroll
    for (int j = 0; j < 4; ++j) {
        int cidx = tid + 256 * j;
        x[j] = hp[cidx] + ldf(&ap[cidx]);
        s += x[j];
    }
    float mean = blockSum256(s) * (1.f / (float)Dc);
    float vsum = 0.f;
#pragma unroll
    for (int j = 0; j < 4; ++j) { float d = x[j] - mean; vsum += d * d; }
    float var = blockSum256(vsum) * (1.f / (float)Dc);
    float inv = rsqrtf(var + 1e-5f);
#pragma unroll
    for (int j = 0; j < 4; ++j) {
        int cidx = tid + 256 * j;
        hp[cidx] = (x[j] - mean) * inv * g[cidx] + b[cidx];
    }
}

// ---------------- launch ----------------
extern "C" void kernel_launch(void* const* d_in, const int* in_sizes, int n_in,
                              void* d_out, int out_size, void* d_ws, size_t ws_size,
                              hipStream_t stream)
{
    const float* x      = (const float*)d_in[0];
    const float* xm     = (const float*)d_in[1];
    // d_in[2] vecSelector: assert-only, unused
    const float* proj_w = (const float*)d_in[3];
    const float* proj_b = (const float*)d_in[4];
    const float* pos    = (const float*)d_in[5];
    const float* qw     = (const float*)d_in[6];
    const float* qb     = (const float*)d_in[7];
    const float* kw     = (const float*)d_in[8];
    const float* kb     = (const float*)d_in[9];
    const float* vw     = (const float*)d_in[10];
    const float* vb     = (const float*)d_in[11];
    const float* ow     = (const float*)d_in[12];
    const float* obias  = (const float*)d_in[13];
    const float* ln1g   = (const float*)d_in[14];
    const float* ln1b   = (const float*)d_in[15];
    const float* ln2g   = (const float*)d_in[16];
    const float* ln2b   = (const float*)d_in[17];
    const float* w1     = (const float*)d_in[18];
    const float* b1     = (const float*)d_in[19];
    const float* w2     = (const float*)d_in[20];
    const float* b2     = (const float*)d_in[21];
    const float* fc1w   = (const float*)d_in[22];
    const float* fc1b   = (const float*)d_in[23];
    const float* fc2w   = (const float*)d_in[24];
    const float* fc2b   = (const float*)d_in[25];
    const float* fc3w   = (const float*)d_in[26];
    const float* fc3b   = (const float*)d_in[27];

    float* ws = (float*)d_ws;
    const size_t HSZ = (size_t)Bc * Sc * Dc; // 8,388,608 floats
    float* h    = ws;                 // fp32 residual stream, 32 MB
    float* rgA  = ws + HSZ;           // attn temps | FFN mid (bf16) | head comp temps
    float* rgB  = ws + 2 * HSZ;       // ff(bf16) + Wt
    float* flag = ws + 3 * HSZ;       // footprint ~96.5 MB (validated)

    float* sc  = rgA;                                  // 16*512*512
    float* qv_ = rgA + (size_t)Hc * Sc * Sc;
    float* kv_ = qv_ + (size_t)Sc * Dc;
    float* vv_ = kv_ + (size_t)Sc * Dc;
    float* aov = vv_ + (size_t)Sc * Dc;
    float* obv = aov + (size_t)Sc * Dc;
    ushort* midu = (ushort*)rgA;                       // 8192*2048 bf16 (FFN phase)
    ushort* ffu  = (ushort*)rgB;                       // 8192*1024 bf16
    ushort* Wt   = (ushort*)(rgB + (size_t)4 * 1024 * 1024); // rolling bf16 W^T

    // head-composition temps (rgA is free after last FFN's mid usage)
    float* W2  = rgA;                   // 256*256
    float* W4  = rgA + 65536;
    float* W5  = rgA + 131072;
    float* C1  = rgA + 196608;          // 1024*256
    float* Wc  = rgA + 458752;          // 1024*256
    float* bv0 = rgA + 720896;          // 256
    float* bv1 = rgA + 721152;          // 256
    float* bcv = rgA + 721408;          // 256

    const int MR = Bc * Sc; // 8192

    mask_k<<<1, 256, 0, stream>>>(xm, flag);

    // h = x @ proj_w + proj_b + pos   (MFMA)
    transp_k<<<dim3(Dc / 64, INc / 64), 256, 0, stream>>>(proj_w, Wt, INc, Dc);
    mgemm_k<float, 0, true, false><<<dim3(Dc / 128, MR / 128), 256, 0, stream>>>(
        x, Wt, proj_b, pos, h, nullptr, MR, Dc, INc, 1.f);

    for (int l = 0; l < Lc; ++l) {
        const float* qw_l = qw + (size_t)l * Dc * Dc; const float* qb_l = qb + l * Dc;
        const float* kw_l = kw + (size_t)l * Dc * Dc; const float* kb_l = kb + l * Dc;
        const float* vw_l = vw + (size_t)l * Dc * Dc; const float* vb_l = vb + l * Dc;
        const float* ow_l = ow + (size_t)l * Dc * Dc; const float* ob_l = obias + l * Dc;
        const float* w1_l = w1 + (size_t)l * Dc * DFFc; const float* b1_l = b1 + l * DFFc;
        const float* w2_l = w2 + (size_t)l * DFFc * Dc; const float* b2_l = b2 + l * Dc;

        // attention: batch 0 only (sa = ao[0] is all that survives)
        transp_k<<<dim3(Dc / 64, Dc / 64), 256, 0, stream>>>(qw_l, Wt, Dc, Dc);
        mgemm_k<float, 0, false, false><<<dim3(Dc / 128, Sc / 128), 256, 0, stream>>>(
            h, Wt, qb_l, nullptr, qv_, nullptr, Sc, Dc, Dc, SCALEc);
        transp_k<<<dim3(Dc / 64, Dc / 64), 256, 0, stream>>>(kw_l, Wt, Dc, Dc);
        mgemm_k<float, 0, false, false><<<dim3(Dc / 128, Sc / 128), 256, 0, stream>>>(
            h, Wt, kb_l, nullptr, kv_, nullptr, Sc, Dc, Dc, 1.f);
        transp_k<<<dim3(Dc / 64, Dc / 64), 256, 0, stream>>>(vw_l, Wt, Dc, Dc);
        mgemm_k<float, 0, false, false><<<dim3(Dc / 128, Sc / 128), 256, 0, stream>>>(
            h, Wt, vb_l, nullptr, vv_, nullptr, Sc, Dc, Dc, 1.f);
        attn_scores_k<<<dim3(Sc / 64, Sc / 64, Hc), 256, 0, stream>>>(qv_, kv_, sc, flag);
        softmax_k<<<Hc * Sc, 256, 0, stream>>>(sc, sc, Sc, 0);
        attn_av_k<<<dim3(Sc / 64, Hc), 256, 0, stream>>>(sc, vv_, aov);
        transp_k<<<dim3(Dc / 64, Dc / 64), 256, 0, stream>>>(ow_l, Wt, Dc, Dc);
        mgemm_k<float, 0, false, false><<<dim3(Dc / 128, Sc / 128), 256, 0, stream>>>(
            aov, Wt, ob_l, nullptr, obv, nullptr, Sc, Dc, Dc, 1.f);
        softmax_k<<<Sc, 256, 0, stream>>>(obv, obv, Dc, 1); // forward hook: clip+softmax over D
        add_ln_k<true, float><<<MR, 256, 0, stream>>>(h, obv, ln1g + l * Dc, ln1b + l * Dc);

        // FFN (all batches, MFMA)
        transp_k<<<dim3(DFFc / 64, Dc / 64), 256, 0, stream>>>(w1_l, Wt, Dc, DFFc);
        mgemm_k<float, 1, false, true><<<dim3(DFFc / 128, MR / 128), 256, 0, stream>>>(
            h, Wt, b1_l, nullptr, nullptr, midu, MR, DFFc, Dc, 1.f);
        transp_k<<<dim3(Dc / 64, DFFc / 64), 256, 0, stream>>>(w2_l, Wt, DFFc, Dc);
        mgemm_k<ushort, 0, false, true><<<dim3(Dc / 128, MR / 128), 256, 0, stream>>>(
            midu, Wt, b2_l, nullptr, nullptr, ffu, MR, Dc, DFFc, 1.f);
        add_ln_k<false, ushort><<<MR, 256, 0, stream>>>(h, ffu, ln2g + l * Dc, ln2b + l * Dc);
    }

    // ---- head: out = h @ Wc + bc, where Wc = fc1_w·fc2_w^5·fc3_w (fc2 is affine 5x) ----
    // W^2, W^4, W^5 (fp32, 256^3 each)
    gemm_k<float, 0, false, false, false><<<dim3(4, 4), 256, 0, stream>>>(
        fc2w, fc2w, nullptr, nullptr, W2, nullptr, HIDc, HIDc, HIDc, 1.f);
    gemm_k<float, 0, false, false, false><<<dim3(4, 4), 256, 0, stream>>>(
        W2, W2, nullptr, nullptr, W4, nullptr, HIDc, HIDc, HIDc, 1.f);
    gemm_k<float, 0, false, false, false><<<dim3(4, 4), 256, 0, stream>>>(
        W4, fc2w, nullptr, nullptr, W5, nullptr, HIDc, HIDc, HIDc, 1.f);
    // C1 = fc1_w @ W5 ; Wc = C1 @ fc3_w   (1024x256x256, fp32)
    gemm_k<float, 0, false, false, false><<<dim3(4, 16), 256, 0, stream>>>(
        fc1w, W5, nullptr, nullptr, C1, nullptr, Dc, HIDc, HIDc, 1.f);
    gemm_k<float, 0, false, false, false><<<dim3(4, 16), 256, 0, stream>>>(
        C1, fc3w, nullptr, nullptr, Wc, nullptr, Dc, HIDc, HIDc, 1.f);
    // bias push-forward: v = fc1_b; 5x (v = v@fc2_w + fc2_b); bc = v@fc3_w + fc3_b
    vecmat_k<<<1, 256, 0, stream>>>(fc1b, fc2w, fc2b, bv0);
    vecmat_k<<<1, 256, 0, stream>>>(bv0, fc2w, fc2b, bv1);
    vecmat_k<<<1, 256, 0, stream>>>(bv1, fc2w, fc2b, bv0);
    vecmat_k<<<1, 256, 0, stream>>>(bv0, fc2w, fc2b, bv1);
    vecmat_k<<<1, 256, 0, stream>>>(bv1, fc2w, fc2b, bv0);
    vecmat_k<<<1, 256, 0, stream>>>(bv0, fc3w, fc3b, bcv);
    // out = h @ Wc + bc  (MFMA, 8192x256x1024)
    transp_k<<<dim3(HIDc / 64, Dc / 64), 256, 0, stream>>>(Wc, Wt, Dc, HIDc);
    mgemm_k<float, 0, false, false><<<dim3(HIDc / 128, MR / 128), 256, 0, stream>>>(
        h, Wt, bcv, nullptr, (float*)d_out, nullptr, MR, HIDc, Dc, 1.f);
}

// Round 6
// 1668.738 us; speedup vs baseline: 4.7436x; 1.2665x over previous
//
#include <hip/hip_runtime.h>
#include <hip/hip_bf16.h>

using bf16 = __hip_bfloat16;
typedef __attribute__((ext_vector_type(8))) short short8v;
typedef __attribute__((ext_vector_type(4))) float floatx4;

// Problem dims
constexpr int Bc = 16, Sc = 512, INc = 512, OUTc = 256;
constexpr int Dc = 1024, Hc = 16, Lc = 6, DFFc = 2048, HIDc = 256;
constexpr float SCALEc = 0.125f; // HD^-0.5
constexpr int QKVS = 3072;       // fused qkv row stride

__device__ inline ushort f2b(float f) { // fp32 -> bf16 RNE
    union { float f; unsigned u; } v; v.f = f;
    unsigned r = (v.u + 0x7FFF + ((v.u >> 16) & 1)) >> 16;
    return (ushort)r;
}
__device__ inline float b2f(ushort b) {
    union { unsigned u; float f; } v; v.u = ((unsigned)b) << 16;
    return v.f;
}
__device__ inline float ldf(const float* p) { return *p; }
__device__ inline float ldf(const ushort* p) { return b2f(*p); }

// ---------------- block reductions (256 threads, wave64) ----------------
__device__ inline float blockSum256(float v) {
    __shared__ float tmp[4];
#pragma unroll
    for (int o = 32; o > 0; o >>= 1) v += __shfl_xor(v, o, 64);
    int w = threadIdx.x >> 6;
    __syncthreads();
    if ((threadIdx.x & 63) == 0) tmp[w] = v;
    __syncthreads();
    return tmp[0] + tmp[1] + tmp[2] + tmp[3];
}
__device__ inline float blockMax256(float v) {
    __shared__ float tmp[4];
#pragma unroll
    for (int o = 32; o > 0; o >>= 1) v = fmaxf(v, __shfl_xor(v, o, 64));
    int w = threadIdx.x >> 6;
    __syncthreads();
    if ((threadIdx.x & 63) == 0) tmp[w] = v;
    __syncthreads();
    return fmaxf(fmaxf(tmp[0], tmp[1]), fmaxf(tmp[2], tmp[3]));
}

// ---------------- mask flag: (sum(xm[0,:]) == 0) ----------------
__global__ __launch_bounds__(256) void mask_k(const float* __restrict__ xm, float* __restrict__ flag) {
    float s = xm[threadIdx.x] + xm[threadIdx.x + 256];
    s = blockSum256(s);
    if (threadIdx.x == 0) flag[0] = (s == 0.f) ? 1.f : 0.f;
}

// ---------------- weight transpose + bf16 cvt (+scale fold): Wt[n][k] = bf16(W[k][n]*s) ----
__global__ __launch_bounds__(256) void transp_k(const float* __restrict__ W, ushort* __restrict__ Wt,
                                                int K, int N, float wscale) {
    __shared__ float Ls[64][65];
    const int t = threadIdx.x;
    const int n0 = blockIdx.x * 64, k0 = blockIdx.y * 64;
    const int kr = t >> 4, n4 = (t & 15) * 4;
#pragma unroll
    for (int p = 0; p < 4; ++p) {
        float4 v = *(const float4*)&W[(size_t)(k0 + kr + p * 16) * N + n0 + n4];
        Ls[kr + p * 16][n4 + 0] = v.x; Ls[kr + p * 16][n4 + 1] = v.y;
        Ls[kr + p * 16][n4 + 2] = v.z; Ls[kr + p * 16][n4 + 3] = v.w;
    }
    __syncthreads();
    const int nr = t >> 4, k4 = (t & 15) * 4;
#pragma unroll
    for (int p = 0; p < 4; ++p) {
        ushort4 o;
        o.x = f2b(Ls[k4 + 0][nr + p * 16] * wscale); o.y = f2b(Ls[k4 + 1][nr + p * 16] * wscale);
        o.z = f2b(Ls[k4 + 2][nr + p * 16] * wscale); o.w = f2b(Ls[k4 + 3][nr + p * 16] * wscale);
        *(ushort4*)&Wt[(size_t)(n0 + nr + p * 16) * K + k0 + k4] = o;
    }
}

// ---------------- 16-elt loaders for MFMA staging ----------------
__device__ inline void ld16(const float* s, ushort* d) {
#pragma unroll
    for (int i = 0; i < 4; ++i) {
        float4 v = *(const float4*)(s + i * 4);
        d[i * 4 + 0] = f2b(v.x); d[i * 4 + 1] = f2b(v.y);
        d[i * 4 + 2] = f2b(v.z); d[i * 4 + 3] = f2b(v.w);
    }
}
__device__ inline void ld16(const ushort* s, ushort* d) {
    *(short8v*)d = *(const short8v*)s;
    *(short8v*)(d + 8) = *(const short8v*)(s + 8);
}

// ---------------- MFMA GEMM (128x128 tile, BK=64, 4 waves, XOR-swizzled LDS) ----------
// XCD-contiguous block swizzle: each XCD gets a contiguous chunk of logical tiles
// (n-fastest), so an A-panel is fetched by one XCD's L2 instead of all eight.
// OMODE: 0=fp32 out, 1=bf16 out, 2=both.
template <typename TA, int ACT, bool ADDPOS, int OMODE>
__global__ __launch_bounds__(256) void mgemm_k(
    const TA* __restrict__ A, const ushort* __restrict__ Bt,
    const float* __restrict__ bias, const float* __restrict__ pos,
    float* __restrict__ Cf, ushort* __restrict__ Cb,
    int M, int N, int K, float scale)
{
    __shared__ __align__(16) ushort As[128 * 64];
    __shared__ __align__(16) ushort Bs[128 * 64];
    const int tid = threadIdx.x;
    const int nx = gridDim.x;
    const int nwg = nx * gridDim.y;
    int d = blockIdx.x + blockIdx.y * nx;
    if ((nwg & 7) == 0) d = (d & 7) * (nwg >> 3) + (d >> 3); // bijective: nwg%8==0
    const int m0 = (d / nx) * 128, n0 = (d % nx) * 128;
    const int lane = tid & 63, wv = tid >> 6;
    const int wm = (wv >> 1) * 64, wn = (wv & 1) * 64;
    floatx4 acc[4][4] = {};

    const int srow = tid >> 2, scg = tid & 3;

    for (int k0 = 0; k0 < K; k0 += 64) {
#pragma unroll
        for (int p = 0; p < 2; ++p) {
            const int r = srow + p * 64;
            __align__(16) ushort ta[16], tb[16];
            ld16(&A[(size_t)(m0 + r) * K + k0 + scg * 16], ta);
            ld16(&Bt[(size_t)(n0 + r) * K + k0 + scg * 16], tb);
            const int base = r * 64, sw = (r & 7) * 8;
            *(short8v*)&As[base + ((scg * 16 + 0) ^ sw)] = *(short8v*)&ta[0];
            *(short8v*)&As[base + ((scg * 16 + 8) ^ sw)] = *(short8v*)&ta[8];
            *(short8v*)&Bs[base + ((scg * 16 + 0) ^ sw)] = *(short8v*)&tb[0];
            *(short8v*)&Bs[base + ((scg * 16 + 8) ^ sw)] = *(short8v*)&tb[8];
        }
        __syncthreads();
#pragma unroll
        for (int s = 0; s < 2; ++s) {
            short8v af[4], bf_[4];
            const int kg = s * 32 + (lane >> 4) * 8;
#pragma unroll
            for (int f = 0; f < 4; ++f) {
                const int ra = wm + f * 16 + (lane & 15);
                af[f] = *(const short8v*)&As[ra * 64 + (kg ^ ((ra & 7) * 8))];
                const int rb = wn + f * 16 + (lane & 15);
                bf_[f] = *(const short8v*)&Bs[rb * 64 + (kg ^ ((rb & 7) * 8))];
            }
#pragma unroll
            for (int i = 0; i < 4; ++i)
#pragma unroll
                for (int j = 0; j < 4; ++j)
                    acc[i][j] = __builtin_amdgcn_mfma_f32_16x16x32_bf16(af[i], bf_[j], acc[i][j], 0, 0, 0);
        }
        __syncthreads();
    }

    const int cc = lane & 15, rr4 = (lane >> 4) * 4;
#pragma unroll
    for (int i = 0; i < 4; ++i) {
#pragma unroll
        for (int j = 0; j < 4; ++j) {
            const int col = n0 + wn + j * 16 + cc;
            const float bsv = bias[col];
#pragma unroll
            for (int q = 0; q < 4; ++q) {
                const int row = m0 + wm + i * 16 + rr4 + q;
                float v = acc[i][j][q] + bsv;
                if (ADDPOS) v += pos[(size_t)(row & (Sc - 1)) * N + col];
                v *= scale;
                if (ACT == 1) v = fmaxf(v, 0.f);
                if (OMODE == 0) Cf[(size_t)row * N + col] = v;
                else if (OMODE == 1) Cb[(size_t)row * N + col] = f2b(v);
                else { Cf[(size_t)row * N + col] = v; Cb[(size_t)row * N + col] = f2b(v); }
            }
        }
    }
}

// ---------------- fp32 VALU GEMM (head composition): C = A@W [+ bias] ----------------
template <typename TA, int ACT, bool ADDPOS, bool OUT_BF16, bool HASB>
__global__ __launch_bounds__(256) void gemm_k(
    const TA* __restrict__ A, const float* __restrict__ W,
    const float* __restrict__ bias, const float* __restrict__ pos,
    float* __restrict__ Cf, bf16* __restrict__ Cb,
    int M, int N, int K, float scale)
{
    __shared__ float As[16][68];
    __shared__ float Ws[16][68];
    const int tid = threadIdx.x;
    const int m0 = blockIdx.y * 64, n0 = blockIdx.x * 64;
    const int ty = tid >> 4, tx = tid & 15;
    float c[4][4] = {};

    const int ka = tid & 15, mb = tid >> 4;
    const int nw = tid & 63, kb = tid >> 6;

    for (int k0 = 0; k0 < K; k0 += 16) {
#pragma unroll
        for (int j = 0; j < 4; ++j) {
            int m = mb + 16 * j;
            As[ka][m] = ldf(&A[(size_t)(m0 + m) * K + k0 + ka]);
        }
#pragma unroll
        for (int j = 0; j < 4; ++j) {
            int k = kb + 4 * j;
            Ws[k][nw] = W[(size_t)(k0 + k) * N + n0 + nw];
        }
        __syncthreads();
#pragma unroll
        for (int k = 0; k < 16; ++k) {
            float4 av = *(const float4*)&As[k][ty * 4];
            float4 wv = *(const float4*)&Ws[k][tx * 4];
            float a[4] = {av.x, av.y, av.z, av.w};
            float w[4] = {wv.x, wv.y, wv.z, wv.w};
#pragma unroll
            for (int i = 0; i < 4; ++i)
#pragma unroll
                for (int j = 0; j < 4; ++j) c[i][j] += a[i] * w[j];
        }
        __syncthreads();
    }

#pragma unroll
    for (int i = 0; i < 4; ++i) {
        int m = m0 + ty * 4 + i;
#pragma unroll
        for (int j = 0; j < 4; ++j) {
            int n = n0 + tx * 4 + j;
            float v = c[i][j] + (HASB ? bias[n] : 0.f);
            if (ADDPOS) v += pos[(size_t)(m & (Sc - 1)) * N + n];
            v *= scale;
            if (ACT == 1) v = fmaxf(v, 0.f);
            if (OUT_BF16) Cb[(size_t)m * N + n] = __float2bfloat16(v);
            else          Cf[(size_t)m * N + n] = v;
        }
    }
}

// ---------------- fused head bias chain: bc = ((fc1b @ fc2w + fc2b) x5) @ fc3w + fc3b ----
__global__ __launch_bounds__(256) void biaschain_k(
    const float* __restrict__ fc1b, const float* __restrict__ fc2w, const float* __restrict__ fc2b,
    const float* __restrict__ fc3w, const float* __restrict__ fc3b, float* __restrict__ bc)
{
    __shared__ float vs[256];
    const int t = threadIdx.x;
    float v = fc1b[t];
    for (int r = 0; r < 5; ++r) {
        vs[t] = v; __syncthreads();
        float s = fc2b[t];
#pragma unroll 8
        for (int k = 0; k < 256; ++k) s += vs[k] * fc2w[k * 256 + t];
        v = s; __syncthreads();
    }
    vs[t] = v; __syncthreads();
    float s = fc3b[t];
#pragma unroll 8
    for (int k = 0; k < 256; ++k) s += vs[k] * fc3w[k * 256 + t];
    bc[t] = s;
}

// ---------------- qkv bias concat (q-part pre-scaled) ----------------
__global__ __launch_bounds__(256) void qkvbias_k(
    const float* __restrict__ qb, const float* __restrict__ kb, const float* __restrict__ vb,
    float* __restrict__ o)
{
    int i = blockIdx.x * 256 + threadIdx.x; // grid 12
    float v = (i < 1024) ? qb[i] * SCALEc : ((i < 2048) ? kb[i - 1024] : vb[i - 2048]);
    o[i] = v;
}

// ---------------- attention scores (batch 0, fused-qkv input) ----------------
__global__ __launch_bounds__(256) void attn_scores_k(
    const float* __restrict__ qkv, float* __restrict__ sc, const float* __restrict__ flag)
{
    const int hh = blockIdx.z;
    const int t0 = blockIdx.y * 64, s0 = blockIdx.x * 64;
    __shared__ float qs[64][68];
    __shared__ float kst[64][68];
    const int tid = threadIdx.x;
    const int c4 = tid & 15, r0 = tid >> 4;
#pragma unroll
    for (int j = 0; j < 4; ++j) {
        int rr = r0 + 16 * j;
        float4 qv = *(const float4*)&qkv[(size_t)(t0 + rr) * QKVS + hh * 64 + c4 * 4];
        *(float4*)&qs[rr][c4 * 4] = qv;
        float4 kv = *(const float4*)&qkv[(size_t)(s0 + rr) * QKVS + 1024 + hh * 64 + c4 * 4];
        kst[c4 * 4 + 0][rr] = kv.x; kst[c4 * 4 + 1][rr] = kv.y;
        kst[c4 * 4 + 2][rr] = kv.z; kst[c4 * 4 + 3][rr] = kv.w;
    }
    __syncthreads();
    const int ty = tid >> 4, tx = tid & 15;
    float c[4][4] = {};
#pragma unroll 8
    for (int dd = 0; dd < 64; ++dd) {
        float a[4];
#pragma unroll
        for (int i = 0; i < 4; ++i) a[i] = qs[ty * 4 + i][dd];
        float4 bv = *(const float4*)&kst[dd][tx * 4];
        float b[4] = {bv.x, bv.y, bv.z, bv.w};
#pragma unroll
        for (int i = 0; i < 4; ++i)
#pragma unroll
            for (int j = 0; j < 4; ++j) c[i][j] += a[i] * b[j];
    }
    const bool msk = flag[0] > 0.5f;
    float* scp = sc + (size_t)hh * Sc * Sc;
#pragma unroll
    for (int i = 0; i < 4; ++i)
#pragma unroll
        for (int j = 0; j < 4; ++j) {
            float v = fminf(fmaxf(c[i][j], -10.f), 10.f);
            if (msk) v = -10.f;
            scp[(size_t)(t0 + ty * 4 + i) * Sc + s0 + tx * 4 + j] = v;
        }
}

// ---------------- row softmax ----------------
__global__ __launch_bounds__(256) void softmax_k(
    const float* __restrict__ in, float* __restrict__ out, int ncols, int doclip)
{
    const int row = blockIdx.x;
    const float* ip = in + (size_t)row * ncols;
    float* op = out + (size_t)row * ncols;
    const int nj = ncols >> 8;
    float r[4];
    float mx = -1e30f;
    for (int j = 0; j < nj; ++j) {
        float v = ip[threadIdx.x + 256 * j];
        if (doclip) v = fminf(fmaxf(v, -10.f), 10.f);
        r[j] = v;
        mx = fmaxf(mx, v);
    }
    mx = blockMax256(mx);
    float s = 0.f;
    for (int j = 0; j < nj; ++j) { r[j] = expf(r[j] - mx); s += r[j]; }
    s = blockSum256(s);
    float inv = 1.f / s;
    for (int j = 0; j < nj; ++j) op[threadIdx.x + 256 * j] = r[j] * inv;
}

// ---------------- attention AV (batch 0, fused-qkv input) ----------------
__global__ __launch_bounds__(256) void attn_av_k(
    const float* __restrict__ aw, const float* __restrict__ qkv, float* __restrict__ ao)
{
    const int hh = blockIdx.y;
    const int t0 = blockIdx.x * 64;
    __shared__ float as_[64][68];
    __shared__ float vs[64][68];
    const int tid = threadIdx.x;
    const int c4 = tid & 15, r0 = tid >> 4;
    const int ty = tid >> 4, tx = tid & 15;
    float c[4][4] = {};
    for (int s0 = 0; s0 < Sc; s0 += 64) {
#pragma unroll
        for (int j = 0; j < 4; ++j) {
            int rr = r0 + 16 * j;
            float4 avv = *(const float4*)&aw[(size_t)hh * Sc * Sc + (size_t)(t0 + rr) * Sc + s0 + c4 * 4];
            *(float4*)&as_[rr][c4 * 4] = avv;
            float4 vv = *(const float4*)&qkv[(size_t)(s0 + rr) * QKVS + 2048 + hh * 64 + c4 * 4];
            *(float4*)&vs[rr][c4 * 4] = vv;
        }
        __syncthreads();
#pragma unroll 8
        for (int ss = 0; ss < 64; ++ss) {
            float a[4];
#pragma unroll
            for (int i = 0; i < 4; ++i) a[i] = as_[ty * 4 + i][ss];
            float4 bv = *(const float4*)&vs[ss][tx * 4];
            float b[4] = {bv.x, bv.y, bv.z, bv.w};
#pragma unroll
            for (int i = 0; i < 4; ++i)
#pragma unroll
                for (int j = 0; j < 4; ++j) c[i][j] += a[i] * b[j];
        }
        __syncthreads();
    }
#pragma unroll
    for (int i = 0; i < 4; ++i)
#pragma unroll
        for (int j = 0; j < 4; ++j)
            ao[(size_t)(t0 + ty * 4 + i) * Dc + hh * 64 + tx * 4 + j] = c[i][j];
}

// ---------------- h = LN(h + add); also writes bf16 shadow hb ----------------
// hb may alias `add` (row-wise: all reads complete before writes via blockSum barrier)
template <bool BCAST, typename TADD>
__global__ __launch_bounds__(256) void add_ln_k(
    float* __restrict__ h, const TADD* __restrict__ add,
    const float* __restrict__ g, const float* __restrict__ b, ushort* __restrict__ hb)
{
    const int row = blockIdx.x;
    const TADD* ap = BCAST ? add + (size_t)(row & (Sc - 1)) * Dc : add + (size_t)row * Dc;
    float* hp = h + (size_t)row * Dc;
    ushort* hbp = hb + (size_t)row * Dc;
    const int tid = threadIdx.x;
    float x[4];
    float s = 0.f;
#pragma unroll
    for (int j = 0; j < 4; ++j) {
        int cidx = tid + 256 * j;
        x[j] = hp[cidx] + ldf(&ap[cidx]);
        s += x[j];
    }
    float mean = blockSum256(s) * (1.f / (float)Dc);
    float vsum = 0.f;
#pragma unroll
    for (int j = 0; j < 4; ++j) { float d = x[j] - mean; vsum += d * d; }
    float var = blockSum256(vsum) * (1.f / (float)Dc);
    float inv = rsqrtf(var + 1e-5f);
#pragma unroll
    for (int j = 0; j < 4; ++j) {
        int cidx = tid + 256 * j;
        float o = (x[j] - mean) * inv * g[cidx] + b[cidx];
        hp[cidx] = o;
        hbp[cidx] = f2b(o);
    }
}

// ---------------- launch ----------------
extern "C" void kernel_launch(void* const* d_in, const int* in_sizes, int n_in,
                              void* d_out, int out_size, void* d_ws, size_t ws_size,
                              hipStream_t stream)
{
    const float* x      = (const float*)d_in[0];
    const float* xm     = (const float*)d_in[1];
    // d_in[2] vecSelector: assert-only, unused
    const float* proj_w = (const float*)d_in[3];
    const float* proj_b = (const float*)d_in[4];
    const float* pos    = (const float*)d_in[5];
    const float* qw     = (const float*)d_in[6];
    const float* qb     = (const float*)d_in[7];
    const float* kw     = (const float*)d_in[8];
    const float* kb     = (const float*)d_in[9];
    const float* vw     = (const float*)d_in[10];
    const float* vb     = (const float*)d_in[11];
    const float* ow     = (const float*)d_in[12];
    const float* obias  = (const float*)d_in[13];
    const float* ln1g   = (const float*)d_in[14];
    const float* ln1b   = (const float*)d_in[15];
    const float* ln2g   = (const float*)d_in[16];
    const float* ln2b   = (const float*)d_in[17];
    const float* w1     = (const float*)d_in[18];
    const float* b1     = (const float*)d_in[19];
    const float* w2     = (const float*)d_in[20];
    const float* b2     = (const float*)d_in[21];
    const float* fc1w   = (const float*)d_in[22];
    const float* fc1b   = (const float*)d_in[23];
    const float* fc2w   = (const float*)d_in[24];
    const float* fc2b   = (const float*)d_in[25];
    const float* fc3w   = (const float*)d_in[26];
    const float* fc3b   = (const float*)d_in[27];

    float* ws = (float*)d_ws;
    const size_t HSZ = (size_t)Bc * Sc * Dc; // 8,388,608 floats
    float* h    = ws;                 // fp32 residual stream, 32 MiB
    float* rgA  = ws + HSZ;           // attn temps | FFN mid (bf16) | head comp temps
    float* rgB  = ws + 2 * HSZ;       // [0,16): hb / ffu (aliased)  [16,22): Wt
    float* flag = ws + 3 * HSZ;       // footprint ~96 MiB (validated)

    // rgA offsets (floats)
    float* sc   = rgA;                                   // [0, 4194304): 16*512*512
    float* qkvf = rgA + 4194304;                         // 512*3072 fp32
    float* aov  = rgA + 5767168;                         // 512*1024
    float* obv  = rgA + 6291456;                         // 512*1024
    float* qkvb = rgA + 6815744;                         // 3072
    ushort* midu = (ushort*)rgA;                         // 8192*2048 bf16 (FFN phase)

    ushort* hb  = (ushort*)rgB;                          // bf16 shadow of h; aliases ffu
    ushort* ffu = (ushort*)rgB;                          // w2 output (bf16)
    ushort* Wt  = (ushort*)(rgB + (size_t)4 * 1024 * 1024); // rolling bf16 W^T, <=6 MiB

    // head-composition temps (rgA free after last FFN)
    float* W2  = rgA;                   // 256*256
    float* W4  = rgA + 65536;
    float* W5  = rgA + 131072;
    float* C1  = rgA + 196608;          // 1024*256
    float* Wc  = rgA + 458752;          // 1024*256
    float* bcv = rgA + 720896;          // 256

    const int MR = Bc * Sc; // 8192

    mask_k<<<1, 256, 0, stream>>>(xm, flag);

    // h = x @ proj_w + proj_b + pos   (MFMA, writes fp32 h + bf16 hb)
    transp_k<<<dim3(Dc / 64, INc / 64), 256, 0, stream>>>(proj_w, Wt, INc, Dc, 1.f);
    mgemm_k<float, 0, true, 2><<<dim3(Dc / 128, MR / 128), 256, 0, stream>>>(
        x, Wt, proj_b, pos, h, hb, MR, Dc, INc, 1.f);

    for (int l = 0; l < Lc; ++l) {
        const float* qw_l = qw + (size_t)l * Dc * Dc; const float* qb_l = qb + l * Dc;
        const float* kw_l = kw + (size_t)l * Dc * Dc; const float* kb_l = kb + l * Dc;
        const float* vw_l = vw + (size_t)l * Dc * Dc; const float* vb_l = vb + l * Dc;
        const float* ow_l = ow + (size_t)l * Dc * Dc; const float* ob_l = obias + l * Dc;
        const float* w1_l = w1 + (size_t)l * Dc * DFFc; const float* b1_l = b1 + l * DFFc;
        const float* w2_l = w2 + (size_t)l * DFFc * Dc; const float* b2_l = b2 + l * Dc;

        // attention: batch 0 only (sa = ao[0] is all that survives). Fused QKV GEMM,
        // SCALE folded into transposed qw and qkv bias.
        transp_k<<<dim3(Dc / 64, Dc / 64), 256, 0, stream>>>(qw_l, Wt, Dc, Dc, SCALEc);
        transp_k<<<dim3(Dc / 64, Dc / 64), 256, 0, stream>>>(kw_l, Wt + (size_t)1024 * 1024, Dc, Dc, 1.f);
        transp_k<<<dim3(Dc / 64, Dc / 64), 256, 0, stream>>>(vw_l, Wt + (size_t)2048 * 1024, Dc, Dc, 1.f);
        qkvbias_k<<<12, 256, 0, stream>>>(qb_l, kb_l, vb_l, qkvb);
        mgemm_k<ushort, 0, false, 0><<<dim3(QKVS / 128, Sc / 128), 256, 0, stream>>>(
            hb, Wt, qkvb, nullptr, qkvf, nullptr, Sc, QKVS, Dc, 1.f);
        attn_scores_k<<<dim3(Sc / 64, Sc / 64, Hc), 256, 0, stream>>>(qkvf, sc, flag);
        softmax_k<<<Hc * Sc, 256, 0, stream>>>(sc, sc, Sc, 0);
        attn_av_k<<<dim3(Sc / 64, Hc), 256, 0, stream>>>(sc, qkvf, aov);
        transp_k<<<dim3(Dc / 64, Dc / 64), 256, 0, stream>>>(ow_l, Wt, Dc, Dc, 1.f);
        mgemm_k<float, 0, false, 0><<<dim3(Dc / 128, Sc / 128), 256, 0, stream>>>(
            aov, Wt, ob_l, nullptr, obv, nullptr, Sc, Dc, Dc, 1.f);
        softmax_k<<<Sc, 256, 0, stream>>>(obv, obv, Dc, 1); // forward hook: clip+softmax over D
        add_ln_k<true, float><<<MR, 256, 0, stream>>>(h, obv, ln1g + l * Dc, ln1b + l * Dc, hb);

        // FFN (all batches, MFMA, bf16 A-operands)
        transp_k<<<dim3(DFFc / 64, Dc / 64), 256, 0, stream>>>(w1_l, Wt, Dc, DFFc, 1.f);
        mgemm_k<ushort, 1, false, 1><<<dim3(DFFc / 128, MR / 128), 256, 0, stream>>>(
            hb, Wt, b1_l, nullptr, nullptr, midu, MR, DFFc, Dc, 1.f);
        transp_k<<<dim3(Dc / 64, DFFc / 64), 256, 0, stream>>>(w2_l, Wt, DFFc, Dc, 1.f);
        mgemm_k<ushort, 0, false, 1><<<dim3(Dc / 128, MR / 128), 256, 0, stream>>>(
            midu, Wt, b2_l, nullptr, nullptr, ffu, MR, Dc, DFFc, 1.f);
        add_ln_k<false, ushort><<<MR, 256, 0, stream>>>(h, ffu, ln2g + l * Dc, ln2b + l * Dc, hb);
    }

    // ---- head: out = h @ Wc + bc, Wc = fc1_w·fc2_w^5·fc3_w (fc2 affine, applied 5x) ----
    gemm_k<float, 0, false, false, false><<<dim3(4, 4), 256, 0, stream>>>(
        fc2w, fc2w, nullptr, nullptr, W2, nullptr, HIDc, HIDc, HIDc, 1.f);
    gemm_k<float, 0, false, false, false><<<dim3(4, 4), 256, 0, stream>>>(
        W2, W2, nullptr, nullptr, W4, nullptr, HIDc, HIDc, HIDc, 1.f);
    gemm_k<float, 0, false, false, false><<<dim3(4, 4), 256, 0, stream>>>(
        W4, fc2w, nullptr, nullptr, W5, nullptr, HIDc, HIDc, HIDc, 1.f);
    gemm_k<float, 0, false, false, false><<<dim3(4, 16), 256, 0, stream>>>(
        fc1w, W5, nullptr, nullptr, C1, nullptr, Dc, HIDc, HIDc, 1.f);
    gemm_k<float, 0, false, false, false><<<dim3(4, 16), 256, 0, stream>>>(
        C1, fc3w, nullptr, nullptr, Wc, nullptr, Dc, HIDc, HIDc, 1.f);
    biaschain_k<<<1, 256, 0, stream>>>(fc1b, fc2w, fc2b, fc3w, fc3b, bcv);
    // out = h @ Wc + bc  (MFMA, bf16 A)
    transp_k<<<dim3(HIDc / 64, Dc / 64), 256, 0, stream>>>(Wc, Wt, Dc, HIDc, 1.f);
    mgemm_k<ushort, 0, false, 0><<<dim3(HIDc / 128, MR / 128), 256, 0, stream>>>(
        hb, Wt, bcv, nullptr, (float*)d_out, nullptr, MR, HIDc, Dc, 1.f);
}

// Round 7
// 1580.334 us; speedup vs baseline: 5.0089x; 1.0559x over previous
//
#include <hip/hip_runtime.h>
#include <hip/hip_bf16.h>

using bf16 = __hip_bfloat16;
typedef __attribute__((ext_vector_type(8))) short short8v;
typedef __attribute__((ext_vector_type(4))) float floatx4;

// Problem dims
constexpr int Bc = 16, Sc = 512, INc = 512, OUTc = 256;
constexpr int Dc = 1024, Hc = 16, Lc = 6, DFFc = 2048, HIDc = 256;
constexpr float SCALEc = 0.125f; // HD^-0.5
constexpr int QKVS = 3072;       // fused qkv row stride

__device__ inline ushort f2b(float f) { // fp32 -> bf16 RNE
    union { float f; unsigned u; } v; v.f = f;
    unsigned r = (v.u + 0x7FFF + ((v.u >> 16) & 1)) >> 16;
    return (ushort)r;
}
__device__ inline float b2f(ushort b) {
    union { unsigned u; float f; } v; v.u = ((unsigned)b) << 16;
    return v.f;
}
__device__ inline float ldf(const float* p) { return *p; }
__device__ inline float ldf(const ushort* p) { return b2f(*p); }

// async global->LDS, 16 B per lane. LDS dest is wave-uniform base + lane*16 (m104).
__device__ inline void gll16(const ushort* g, ushort* l) {
    __builtin_amdgcn_global_load_lds(
        (const __attribute__((address_space(1))) unsigned int*)g,
        (__attribute__((address_space(3))) unsigned int*)l, 16, 0, 0);
}

// ---------------- block reductions (256 threads, wave64) ----------------
__device__ inline float blockSum256(float v) {
    __shared__ float tmp[4];
#pragma unroll
    for (int o = 32; o > 0; o >>= 1) v += __shfl_xor(v, o, 64);
    int w = threadIdx.x >> 6;
    __syncthreads();
    if ((threadIdx.x & 63) == 0) tmp[w] = v;
    __syncthreads();
    return tmp[0] + tmp[1] + tmp[2] + tmp[3];
}
__device__ inline float blockMax256(float v) {
    __shared__ float tmp[4];
#pragma unroll
    for (int o = 32; o > 0; o >>= 1) v = fmaxf(v, __shfl_xor(v, o, 64));
    int w = threadIdx.x >> 6;
    __syncthreads();
    if ((threadIdx.x & 63) == 0) tmp[w] = v;
    __syncthreads();
    return fmaxf(fmaxf(tmp[0], tmp[1]), fmaxf(tmp[2], tmp[3]));
}

// ---------------- mask flag: (sum(xm[0,:]) == 0) ----------------
__global__ __launch_bounds__(256) void mask_k(const float* __restrict__ xm, float* __restrict__ flag) {
    float s = xm[threadIdx.x] + xm[threadIdx.x + 256];
    s = blockSum256(s);
    if (threadIdx.x == 0) flag[0] = (s == 0.f) ? 1.f : 0.f;
}

// ---------------- weight transpose + bf16 cvt (+scale fold): Wt[n][k] = bf16(W[k][n]*s) ----
__global__ __launch_bounds__(256) void transp_k(const float* __restrict__ W, ushort* __restrict__ Wt,
                                                int K, int N, float wscale) {
    __shared__ float Ls[64][65];
    const int t = threadIdx.x;
    const int n0 = blockIdx.x * 64, k0 = blockIdx.y * 64;
    const int kr = t >> 4, n4 = (t & 15) * 4;
#pragma unroll
    for (int p = 0; p < 4; ++p) {
        float4 v = *(const float4*)&W[(size_t)(k0 + kr + p * 16) * N + n0 + n4];
        Ls[kr + p * 16][n4 + 0] = v.x; Ls[kr + p * 16][n4 + 1] = v.y;
        Ls[kr + p * 16][n4 + 2] = v.z; Ls[kr + p * 16][n4 + 3] = v.w;
    }
    __syncthreads();
    const int nr = t >> 4, k4 = (t & 15) * 4;
#pragma unroll
    for (int p = 0; p < 4; ++p) {
        ushort4 o;
        o.x = f2b(Ls[k4 + 0][nr + p * 16] * wscale); o.y = f2b(Ls[k4 + 1][nr + p * 16] * wscale);
        o.z = f2b(Ls[k4 + 2][nr + p * 16] * wscale); o.w = f2b(Ls[k4 + 3][nr + p * 16] * wscale);
        *(ushort4*)&Wt[(size_t)(n0 + nr + p * 16) * K + k0 + k4] = o;
    }
}

// ---------------- fused qkv weight transpose (z selects q/k/v; q pre-scaled) ----------
__global__ __launch_bounds__(256) void transp3_k(const float* __restrict__ qw, const float* __restrict__ kw,
                                                 const float* __restrict__ vw, ushort* __restrict__ Wt) {
    const float* W = (blockIdx.z == 0) ? qw : (blockIdx.z == 1) ? kw : vw;
    const float wscale = (blockIdx.z == 0) ? SCALEc : 1.f;
    ushort* dst = Wt + (size_t)blockIdx.z * Dc * Dc;
    __shared__ float Ls[64][65];
    const int t = threadIdx.x;
    const int n0 = blockIdx.x * 64, k0 = blockIdx.y * 64;
    const int kr = t >> 4, n4 = (t & 15) * 4;
#pragma unroll
    for (int p = 0; p < 4; ++p) {
        float4 v = *(const float4*)&W[(size_t)(k0 + kr + p * 16) * Dc + n0 + n4];
        Ls[kr + p * 16][n4 + 0] = v.x; Ls[kr + p * 16][n4 + 1] = v.y;
        Ls[kr + p * 16][n4 + 2] = v.z; Ls[kr + p * 16][n4 + 3] = v.w;
    }
    __syncthreads();
    const int nr = t >> 4, k4 = (t & 15) * 4;
#pragma unroll
    for (int p = 0; p < 4; ++p) {
        ushort4 o;
        o.x = f2b(Ls[k4 + 0][nr + p * 16] * wscale); o.y = f2b(Ls[k4 + 1][nr + p * 16] * wscale);
        o.z = f2b(Ls[k4 + 2][nr + p * 16] * wscale); o.w = f2b(Ls[k4 + 3][nr + p * 16] * wscale);
        *(ushort4*)&dst[(size_t)(n0 + nr + p * 16) * Dc + k0 + k4] = o;
    }
}

// ---------------- 16-elt loader for fp32 A staging ----------------
__device__ inline void ld16(const float* s, ushort* d) {
#pragma unroll
    for (int i = 0; i < 4; ++i) {
        float4 v = *(const float4*)(s + i * 4);
        d[i * 4 + 0] = f2b(v.x); d[i * 4 + 1] = f2b(v.y);
        d[i * 4 + 2] = f2b(v.z); d[i * 4 + 3] = f2b(v.w);
    }
}

// ---------------- MFMA GEMM (128x128 tile, BK=64, 4 waves, XOR-swizzled LDS) ----------
// Staging: global_load_lds width=16 (m97). LDS dest linear; the XOR swizzle is realized
// by inverse-permuting the per-lane GLOBAL source chunk (rule #21): lane covers row
// r = w*32+p*8+(l>>3), chunk c = l&7; it fetches global chunk c^(r&7), so LDS position
// q holds global elt q^((r&7)*8) -- matching the swizzled ds_read below.
// A: bf16 -> gll; fp32 -> reg-stage+cvt. B (Wt): always gll.
// OMODE: 0=fp32 out, 1=bf16 out, 2=both.
template <typename TA, int ACT, bool ADDPOS, int OMODE>
__global__ __launch_bounds__(256) void mgemm_k(
    const TA* __restrict__ A, const ushort* __restrict__ Bt,
    const float* __restrict__ bias, const float* __restrict__ pos,
    float* __restrict__ Cf, ushort* __restrict__ Cb,
    int M, int N, int K, float scale)
{
    __shared__ __align__(16) ushort As[128 * 64];
    __shared__ __align__(16) ushort Bs[128 * 64];
    const int tid = threadIdx.x;
    const int nx = gridDim.x;
    const int nwg = nx * gridDim.y;
    int d = blockIdx.x + blockIdx.y * nx;
    if ((nwg & 7) == 0) d = (d & 7) * (nwg >> 3) + (d >> 3); // XCD swizzle, bijective
    const int m0 = (d / nx) * 128, n0 = (d % nx) * 128;
    const int lane = tid & 63, wv = tid >> 6;
    const int wm = (wv >> 1) * 64, wn = (wv & 1) * 64;
    floatx4 acc[4][4] = {};

    const int rA8 = lane >> 3, cch = lane & 7; // gll coords within 8-row issue
    const int srow = tid >> 2, scg = tid & 3;  // reg-stage coords (fp32 A)

    for (int k0 = 0; k0 < K; k0 += 64) {
        // B: async gll staging (4 issues/wave of 8 rows each)
#pragma unroll
        for (int p = 0; p < 4; ++p) {
            const int r = wv * 32 + p * 8 + rA8;
            const int cs = (cch ^ (r & 7)) * 8;
            gll16(&Bt[(size_t)(n0 + r) * K + k0 + cs], &Bs[(wv * 32 + p * 8) * 64]);
        }
        if constexpr (sizeof(TA) == 2) {
#pragma unroll
            for (int p = 0; p < 4; ++p) {
                const int r = wv * 32 + p * 8 + rA8;
                const int cs = (cch ^ (r & 7)) * 8;
                gll16((const ushort*)&A[(size_t)(m0 + r) * K + k0 + cs], &As[(wv * 32 + p * 8) * 64]);
            }
        } else {
#pragma unroll
            for (int p = 0; p < 2; ++p) {
                const int r = srow + p * 64;
                __align__(16) ushort ta[16];
                ld16(&A[(size_t)(m0 + r) * K + k0 + scg * 16], ta);
                const int base = r * 64, sw = (r & 7) * 8;
                *(short8v*)&As[base + ((scg * 16 + 0) ^ sw)] = *(short8v*)&ta[0];
                *(short8v*)&As[base + ((scg * 16 + 8) ^ sw)] = *(short8v*)&ta[8];
            }
        }
        __syncthreads();
#pragma unroll
        for (int s = 0; s < 2; ++s) {
            short8v af[4], bf_[4];
            const int kg = s * 32 + (lane >> 4) * 8;
#pragma unroll
            for (int f = 0; f < 4; ++f) {
                const int ra = wm + f * 16 + (lane & 15);
                af[f] = *(const short8v*)&As[ra * 64 + (kg ^ ((ra & 7) * 8))];
                const int rb = wn + f * 16 + (lane & 15);
                bf_[f] = *(const short8v*)&Bs[rb * 64 + (kg ^ ((rb & 7) * 8))];
            }
#pragma unroll
            for (int i = 0; i < 4; ++i)
#pragma unroll
                for (int j = 0; j < 4; ++j)
                    acc[i][j] = __builtin_amdgcn_mfma_f32_16x16x32_bf16(af[i], bf_[j], acc[i][j], 0, 0, 0);
        }
        __syncthreads();
    }

    const int cc = lane & 15, rr4 = (lane >> 4) * 4;
#pragma unroll
    for (int i = 0; i < 4; ++i) {
#pragma unroll
        for (int j = 0; j < 4; ++j) {
            const int col = n0 + wn + j * 16 + cc;
            const float bsv = bias[col];
#pragma unroll
            for (int q = 0; q < 4; ++q) {
                const int row = m0 + wm + i * 16 + rr4 + q;
                float v = acc[i][j][q] + bsv;
                if (ADDPOS) v += pos[(size_t)(row & (Sc - 1)) * N + col];
                v *= scale;
                if (ACT == 1) v = fmaxf(v, 0.f);
                if (OMODE == 0) Cf[(size_t)row * N + col] = v;
                else if (OMODE == 1) Cb[(size_t)row * N + col] = f2b(v);
                else { Cf[(size_t)row * N + col] = v; Cb[(size_t)row * N + col] = f2b(v); }
            }
        }
    }
}

// ---------------- fp32 VALU GEMM (head composition): C = A@W [+ bias] ----------------
template <typename TA, int ACT, bool ADDPOS, bool OUT_BF16, bool HASB>
__global__ __launch_bounds__(256) void gemm_k(
    const TA* __restrict__ A, const float* __restrict__ W,
    const float* __restrict__ bias, const float* __restrict__ pos,
    float* __restrict__ Cf, bf16* __restrict__ Cb,
    int M, int N, int K, float scale)
{
    __shared__ float As[16][68];
    __shared__ float Ws[16][68];
    const int tid = threadIdx.x;
    const int m0 = blockIdx.y * 64, n0 = blockIdx.x * 64;
    const int ty = tid >> 4, tx = tid & 15;
    float c[4][4] = {};

    const int ka = tid & 15, mb = tid >> 4;
    const int nw = tid & 63, kb = tid >> 6;

    for (int k0 = 0; k0 < K; k0 += 16) {
#pragma unroll
        for (int j = 0; j < 4; ++j) {
            int m = mb + 16 * j;
            As[ka][m] = ldf(&A[(size_t)(m0 + m) * K + k0 + ka]);
        }
#pragma unroll
        for (int j = 0; j < 4; ++j) {
            int k = kb + 4 * j;
            Ws[k][nw] = W[(size_t)(k0 + k) * N + n0 + nw];
        }
        __syncthreads();
#pragma unroll
        for (int k = 0; k < 16; ++k) {
            float4 av = *(const float4*)&As[k][ty * 4];
            float4 wv = *(const float4*)&Ws[k][tx * 4];
            float a[4] = {av.x, av.y, av.z, av.w};
            float w[4] = {wv.x, wv.y, wv.z, wv.w};
#pragma unroll
            for (int i = 0; i < 4; ++i)
#pragma unroll
                for (int j = 0; j < 4; ++j) c[i][j] += a[i] * w[j];
        }
        __syncthreads();
    }

#pragma unroll
    for (int i = 0; i < 4; ++i) {
        int m = m0 + ty * 4 + i;
#pragma unroll
        for (int j = 0; j < 4; ++j) {
            int n = n0 + tx * 4 + j;
            float v = c[i][j] + (HASB ? bias[n] : 0.f);
            if (ADDPOS) v += pos[(size_t)(m & (Sc - 1)) * N + n];
            v *= scale;
            if (ACT == 1) v = fmaxf(v, 0.f);
            if (OUT_BF16) Cb[(size_t)m * N + n] = __float2bfloat16(v);
            else          Cf[(size_t)m * N + n] = v;
        }
    }
}

// ---------------- fused head bias chain: bc = ((fc1b @ fc2w + fc2b) x5) @ fc3w + fc3b ----
__global__ __launch_bounds__(256) void biaschain_k(
    const float* __restrict__ fc1b, const float* __restrict__ fc2w, const float* __restrict__ fc2b,
    const float* __restrict__ fc3w, const float* __restrict__ fc3b, float* __restrict__ bc)
{
    __shared__ float vs[256];
    const int t = threadIdx.x;
    float v = fc1b[t];
    for (int r = 0; r < 5; ++r) {
        vs[t] = v; __syncthreads();
        float s = fc2b[t];
#pragma unroll 8
        for (int k = 0; k < 256; ++k) s += vs[k] * fc2w[k * 256 + t];
        v = s; __syncthreads();
    }
    vs[t] = v; __syncthreads();
    float s = fc3b[t];
#pragma unroll 8
    for (int k = 0; k < 256; ++k) s += vs[k] * fc3w[k * 256 + t];
    bc[t] = s;
}

// ---------------- qkv bias concat (q-part pre-scaled) ----------------
__global__ __launch_bounds__(256) void qkvbias_k(
    const float* __restrict__ qb, const float* __restrict__ kb, const float* __restrict__ vb,
    float* __restrict__ o)
{
    int i = blockIdx.x * 256 + threadIdx.x; // grid 12
    float v = (i < 1024) ? qb[i] * SCALEc : ((i < 2048) ? kb[i - 1024] : vb[i - 2048]);
    o[i] = v;
}

// ---------------- attention scores (batch 0, fused-qkv input) ----------------
__global__ __launch_bounds__(256) void attn_scores_k(
    const float* __restrict__ qkv, float* __restrict__ sc, const float* __restrict__ flag)
{
    const int hh = blockIdx.z;
    const int t0 = blockIdx.y * 64, s0 = blockIdx.x * 64;
    __shared__ float qs[64][68];
    __shared__ float kst[64][68];
    const int tid = threadIdx.x;
    const int c4 = tid & 15, r0 = tid >> 4;
#pragma unroll
    for (int j = 0; j < 4; ++j) {
        int rr = r0 + 16 * j;
        float4 qv = *(const float4*)&qkv[(size_t)(t0 + rr) * QKVS + hh * 64 + c4 * 4];
        *(float4*)&qs[rr][c4 * 4] = qv;
        float4 kv = *(const float4*)&qkv[(size_t)(s0 + rr) * QKVS + 1024 + hh * 64 + c4 * 4];
        kst[c4 * 4 + 0][rr] = kv.x; kst[c4 * 4 + 1][rr] = kv.y;
        kst[c4 * 4 + 2][rr] = kv.z; kst[c4 * 4 + 3][rr] = kv.w;
    }
    __syncthreads();
    const int ty = tid >> 4, tx = tid & 15;
    float c[4][4] = {};
#pragma unroll 8
    for (int dd = 0; dd < 64; ++dd) {
        float a[4];
#pragma unroll
        for (int i = 0; i < 4; ++i) a[i] = qs[ty * 4 + i][dd];
        float4 bv = *(const float4*)&kst[dd][tx * 4];
        float b[4] = {bv.x, bv.y, bv.z, bv.w};
#pragma unroll
        for (int i = 0; i < 4; ++i)
#pragma unroll
            for (int j = 0; j < 4; ++j) c[i][j] += a[i] * b[j];
    }
    const bool msk = flag[0] > 0.5f;
    float* scp = sc + (size_t)hh * Sc * Sc;
#pragma unroll
    for (int i = 0; i < 4; ++i)
#pragma unroll
        for (int j = 0; j < 4; ++j) {
            float v = fminf(fmaxf(c[i][j], -10.f), 10.f);
            if (msk) v = -10.f;
            scp[(size_t)(t0 + ty * 4 + i) * Sc + s0 + tx * 4 + j] = v;
        }
}

// ---------------- row softmax ----------------
__global__ __launch_bounds__(256) void softmax_k(
    const float* __restrict__ in, float* __restrict__ out, int ncols, int doclip)
{
    const int row = blockIdx.x;
    const float* ip = in + (size_t)row * ncols;
    float* op = out + (size_t)row * ncols;
    const int nj = ncols >> 8;
    float r[4];
    float mx = -1e30f;
    for (int j = 0; j < nj; ++j) {
        float v = ip[threadIdx.x + 256 * j];
        if (doclip) v = fminf(fmaxf(v, -10.f), 10.f);
        r[j] = v;
        mx = fmaxf(mx, v);
    }
    mx = blockMax256(mx);
    float s = 0.f;
    for (int j = 0; j < nj; ++j) { r[j] = expf(r[j] - mx); s += r[j]; }
    s = blockSum256(s);
    float inv = 1.f / s;
    for (int j = 0; j < nj; ++j) op[threadIdx.x + 256 * j] = r[j] * inv;
}

// ---------------- attention AV (batch 0, fused-qkv input, bf16 out) ----------------
__global__ __launch_bounds__(256) void attn_av_k(
    const float* __restrict__ aw, const float* __restrict__ qkv, ushort* __restrict__ ao)
{
    const int hh = blockIdx.y;
    const int t0 = blockIdx.x * 64;
    __shared__ float as_[64][68];
    __shared__ float vs[64][68];
    const int tid = threadIdx.x;
    const int c4 = tid & 15, r0 = tid >> 4;
    const int ty = tid >> 4, tx = tid & 15;
    float c[4][4] = {};
    for (int s0 = 0; s0 < Sc; s0 += 64) {
#pragma unroll
        for (int j = 0; j < 4; ++j) {
            int rr = r0 + 16 * j;
            float4 avv = *(const float4*)&aw[(size_t)hh * Sc * Sc + (size_t)(t0 + rr) * Sc + s0 + c4 * 4];
            *(float4*)&as_[rr][c4 * 4] = avv;
            float4 vv = *(const float4*)&qkv[(size_t)(s0 + rr) * QKVS + 2048 + hh * 64 + c4 * 4];
            *(float4*)&vs[rr][c4 * 4] = vv;
        }
        __syncthreads();
#pragma unroll 8
        for (int ss = 0; ss < 64; ++ss) {
            float a[4];
#pragma unroll
            for (int i = 0; i < 4; ++i) a[i] = as_[ty * 4 + i][ss];
            float4 bv = *(const float4*)&vs[ss][tx * 4];
            float b[4] = {bv.x, bv.y, bv.z, bv.w};
#pragma unroll
            for (int i = 0; i < 4; ++i)
#pragma unroll
                for (int j = 0; j < 4; ++j) c[i][j] += a[i] * b[j];
        }
        __syncthreads();
    }
#pragma unroll
    for (int i = 0; i < 4; ++i)
#pragma unroll
        for (int j = 0; j < 4; ++j)
            ao[(size_t)(t0 + ty * 4 + i) * Dc + hh * 64 + tx * 4 + j] = f2b(c[i][j]);
}

// ---------------- h = LN(h + add); also writes bf16 shadow hb ----------------
template <bool BCAST, typename TADD>
__global__ __launch_bounds__(256) void add_ln_k(
    float* __restrict__ h, const TADD* __restrict__ add,
    const float* __restrict__ g, const float* __restrict__ b, ushort* __restrict__ hb)
{
    const int row = blockIdx.x;
    const TADD* ap = BCAST ? add + (size_t)(row & (Sc - 1)) * Dc : add + (size_t)row * Dc;
    float* hp = h + (size_t)row * Dc;
    ushort* hbp = hb + (size_t)row * Dc;
    const int tid = threadIdx.x;
    float x[4];
    float s = 0.f;
#pragma unroll
    for (int j = 0; j < 4; ++j) {
        int cidx = tid + 256 * j;
        x[j] = hp[cidx] + ldf(&ap[cidx]);
        s += x[j];
    }
    float mean = blockSum256(s) * (1.f / (float)Dc);
    float vsum = 0.f;
#pragma unroll
    for (int j = 0; j < 4; ++j) { float d = x[j] - mean; vsum += d * d; }
    float var = blockSum256(vsum) * (1.f / (float)Dc);
    float inv = rsqrtf(var + 1e-5f);
#pragma unroll
    for (int j = 0; j < 4; ++j) {
        int cidx = tid + 256 * j;
        float o = (x[j] - mean) * inv * g[cidx] + b[cidx];
        hp[cidx] = o;
        hbp[cidx] = f2b(o);
    }
}

// ---------------- launch ----------------
extern "C" void kernel_launch(void* const* d_in, const int* in_sizes, int n_in,
                              void* d_out, int out_size, void* d_ws, size_t ws_size,
                              hipStream_t stream)
{
    const float* x      = (const float*)d_in[0];
    const float* xm     = (const float*)d_in[1];
    // d_in[2] vecSelector: assert-only, unused
    const float* proj_w = (const float*)d_in[3];
    const float* proj_b = (const float*)d_in[4];
    const float* pos    = (const float*)d_in[5];
    const float* qw     = (const float*)d_in[6];
    const float* qb     = (const float*)d_in[7];
    const float* kw     = (const float*)d_in[8];
    const float* kb     = (const float*)d_in[9];
    const float* vw     = (const float*)d_in[10];
    const float* vb     = (const float*)d_in[11];
    const float* ow     = (const float*)d_in[12];
    const float* obias  = (const float*)d_in[13];
    const float* ln1g   = (const float*)d_in[14];
    const float* ln1b   = (const float*)d_in[15];
    const float* ln2g   = (const float*)d_in[16];
    const float* ln2b   = (const float*)d_in[17];
    const float* w1     = (const float*)d_in[18];
    const float* b1     = (const float*)d_in[19];
    const float* w2     = (const float*)d_in[20];
    const float* b2     = (const float*)d_in[21];
    const float* fc1w   = (const float*)d_in[22];
    const float* fc1b   = (const float*)d_in[23];
    const float* fc2w   = (const float*)d_in[24];
    const float* fc2b   = (const float*)d_in[25];
    const float* fc3w   = (const float*)d_in[26];
    const float* fc3b   = (const float*)d_in[27];

    float* ws = (float*)d_ws;
    const size_t HSZ = (size_t)Bc * Sc * Dc; // 8,388,608 floats
    float* h    = ws;                 // fp32 residual stream, 32 MiB
    float* rgA  = ws + HSZ;           // attn temps | FFN mid (bf16) | head comp temps
    float* rgB  = ws + 2 * HSZ;       // [0,16): hb / ffu (aliased)  [16,22): Wt
    float* flag = ws + 3 * HSZ;       // footprint ~96 MiB (validated)

    // rgA offsets (floats)
    float* sc   = rgA;                                   // [0, 4194304): 16*512*512
    float* qkvf = rgA + 4194304;                         // 512*3072 fp32
    ushort* aovu = (ushort*)(rgA + 5767168);             // 512*1024 bf16
    float* obv  = rgA + 6291456;                         // 512*1024
    float* qkvb = rgA + 6815744;                         // 3072
    ushort* midu = (ushort*)rgA;                         // 8192*2048 bf16 (FFN phase)

    ushort* hb  = (ushort*)rgB;                          // bf16 shadow of h; aliases ffu
    ushort* ffu = (ushort*)rgB;                          // w2 output (bf16)
    ushort* Wt  = (ushort*)(rgB + (size_t)4 * 1024 * 1024); // rolling bf16 W^T, <=6 MiB

    // head-composition temps (rgA free after last FFN)
    float* W2  = rgA;                   // 256*256
    float* W4  = rgA + 65536;
    float* W5  = rgA + 131072;
    float* C1  = rgA + 196608;          // 1024*256
    float* Wc  = rgA + 458752;          // 1024*256
    float* bcv = rgA + 720896;          // 256

    const int MR = Bc * Sc; // 8192

    mask_k<<<1, 256, 0, stream>>>(xm, flag);

    // h = x @ proj_w + proj_b + pos   (MFMA, writes fp32 h + bf16 hb)
    transp_k<<<dim3(Dc / 64, INc / 64), 256, 0, stream>>>(proj_w, Wt, INc, Dc, 1.f);
    mgemm_k<float, 0, true, 2><<<dim3(Dc / 128, MR / 128), 256, 0, stream>>>(
        x, Wt, proj_b, pos, h, hb, MR, Dc, INc, 1.f);

    for (int l = 0; l < Lc; ++l) {
        const float* qw_l = qw + (size_t)l * Dc * Dc; const float* qb_l = qb + l * Dc;
        const float* kw_l = kw + (size_t)l * Dc * Dc; const float* kb_l = kb + l * Dc;
        const float* vw_l = vw + (size_t)l * Dc * Dc; const float* vb_l = vb + l * Dc;
        const float* ow_l = ow + (size_t)l * Dc * Dc; const float* ob_l = obias + l * Dc;
        const float* w1_l = w1 + (size_t)l * Dc * DFFc; const float* b1_l = b1 + l * DFFc;
        const float* w2_l = w2 + (size_t)l * DFFc * Dc; const float* b2_l = b2 + l * Dc;

        // attention: batch 0 only (sa = ao[0] is all that survives). Fused QKV GEMM.
        transp3_k<<<dim3(Dc / 64, Dc / 64, 3), 256, 0, stream>>>(qw_l, kw_l, vw_l, Wt);
        qkvbias_k<<<12, 256, 0, stream>>>(qb_l, kb_l, vb_l, qkvb);
        mgemm_k<ushort, 0, false, 0><<<dim3(QKVS / 128, Sc / 128), 256, 0, stream>>>(
            hb, Wt, qkvb, nullptr, qkvf, nullptr, Sc, QKVS, Dc, 1.f);
        attn_scores_k<<<dim3(Sc / 64, Sc / 64, Hc), 256, 0, stream>>>(qkvf, sc, flag);
        softmax_k<<<Hc * Sc, 256, 0, stream>>>(sc, sc, Sc, 0);
        attn_av_k<<<dim3(Sc / 64, Hc), 256, 0, stream>>>(sc, qkvf, aovu);
        transp_k<<<dim3(Dc / 64, Dc / 64), 256, 0, stream>>>(ow_l, Wt, Dc, Dc, 1.f);
        mgemm_k<ushort, 0, false, 0><<<dim3(Dc / 128, Sc / 128), 256, 0, stream>>>(
            aovu, Wt, ob_l, nullptr, obv, nullptr, Sc, Dc, Dc, 1.f);
        softmax_k<<<Sc, 256, 0, stream>>>(obv, obv, Dc, 1); // forward hook: clip+softmax over D
        add_ln_k<true, float><<<MR, 256, 0, stream>>>(h, obv, ln1g + l * Dc, ln1b + l * Dc, hb);

        // FFN (all batches, MFMA, bf16 A-operands via global_load_lds)
        transp_k<<<dim3(DFFc / 64, Dc / 64), 256, 0, stream>>>(w1_l, Wt, Dc, DFFc, 1.f);
        mgemm_k<ushort, 1, false, 1><<<dim3(DFFc / 128, MR / 128), 256, 0, stream>>>(
            hb, Wt, b1_l, nullptr, nullptr, midu, MR, DFFc, Dc, 1.f);
        transp_k<<<dim3(Dc / 64, DFFc / 64), 256, 0, stream>>>(w2_l, Wt, DFFc, Dc, 1.f);
        mgemm_k<ushort, 0, false, 1><<<dim3(Dc / 128, MR / 128), 256, 0, stream>>>(
            midu, Wt, b2_l, nullptr, nullptr, ffu, MR, Dc, DFFc, 1.f);
        add_ln_k<false, ushort><<<MR, 256, 0, stream>>>(h, ffu, ln2g + l * Dc, ln2b + l * Dc, hb);
    }

    // ---- head: out = h @ Wc + bc, Wc = fc1_w·fc2_w^5·fc3_w (fc2 affine, applied 5x) ----
    gemm_k<float, 0, false, false, false><<<dim3(4, 4), 256, 0, stream>>>(
        fc2w, fc2w, nullptr, nullptr, W2, nullptr, HIDc, HIDc, HIDc, 1.f);
    gemm_k<float, 0, false, false, false><<<dim3(4, 4), 256, 0, stream>>>(
        W2, W2, nullptr, nullptr, W4, nullptr, HIDc, HIDc, HIDc, 1.f);
    gemm_k<float, 0, false, false, false><<<dim3(4, 4), 256, 0, stream>>>(
        W4, fc2w, nullptr, nullptr, W5, nullptr, HIDc, HIDc, HIDc, 1.f);
    gemm_k<float, 0, false, false, false><<<dim3(4, 16), 256, 0, stream>>>(
        fc1w, W5, nullptr, nullptr, C1, nullptr, Dc, HIDc, HIDc, 1.f);
    gemm_k<float, 0, false, false, false><<<dim3(4, 16), 256, 0, stream>>>(
        C1, fc3w, nullptr, nullptr, Wc, nullptr, Dc, HIDc, HIDc, 1.f);
    biaschain_k<<<1, 256, 0, stream>>>(fc1b, fc2w, fc2b, fc3w, fc3b, bcv);
    // out = h @ Wc + bc  (MFMA, bf16 A via gll)
    transp_k<<<dim3(HIDc / 64, Dc / 64), 256, 0, stream>>>(Wc, Wt, Dc, HIDc, 1.f);
    mgemm_k<ushort, 0, false, 0><<<dim3(HIDc / 128, MR / 128), 256, 0, stream>>>(
        hb, Wt, bcv, nullptr, (float*)d_out, nullptr, MR, HIDc, Dc, 1.f);
}

// Round 8
// 1403.240 us; speedup vs baseline: 5.6411x; 1.1262x over previous
//
#include <hip/hip_runtime.h>
#include <hip/hip_bf16.h>

using bf16 = __hip_bfloat16;
typedef __attribute__((ext_vector_type(8))) short short8v;
typedef __attribute__((ext_vector_type(4))) float floatx4;

// Problem dims
constexpr int Bc = 16, Sc = 512, INc = 512, OUTc = 256;
constexpr int Dc = 1024, Hc = 16, Lc = 6, DFFc = 2048, HIDc = 256;
constexpr float SCALEc = 0.125f; // HD^-0.5
constexpr int QKVS = 3072;       // fused qkv row stride

__device__ inline ushort f2b(float f) { // fp32 -> bf16 RNE
    union { float f; unsigned u; } v; v.f = f;
    unsigned r = (v.u + 0x7FFF + ((v.u >> 16) & 1)) >> 16;
    return (ushort)r;
}
__device__ inline float b2f(ushort b) {
    union { unsigned u; float f; } v; v.u = ((unsigned)b) << 16;
    return v.f;
}
__device__ inline float ldf(const float* p) { return *p; }
__device__ inline float ldf(const ushort* p) { return b2f(*p); }

// async global->LDS, 16 B per lane. LDS dest is wave-uniform base + lane*16 (m104).
__device__ inline void gll16(const ushort* g, ushort* l) {
    __builtin_amdgcn_global_load_lds(
        (const __attribute__((address_space(1))) unsigned int*)g,
        (__attribute__((address_space(3))) unsigned int*)l, 16, 0, 0);
}

// ---------------- block reductions (256 threads, wave64) ----------------
__device__ inline float blockSum256(float v) {
    __shared__ float tmp[4];
#pragma unroll
    for (int o = 32; o > 0; o >>= 1) v += __shfl_xor(v, o, 64);
    int w = threadIdx.x >> 6;
    __syncthreads();
    if ((threadIdx.x & 63) == 0) tmp[w] = v;
    __syncthreads();
    return tmp[0] + tmp[1] + tmp[2] + tmp[3];
}
__device__ inline float blockMax256(float v) {
    __shared__ float tmp[4];
#pragma unroll
    for (int o = 32; o > 0; o >>= 1) v = fmaxf(v, __shfl_xor(v, o, 64));
    int w = threadIdx.x >> 6;
    __syncthreads();
    if ((threadIdx.x & 63) == 0) tmp[w] = v;
    __syncthreads();
    return fmaxf(fmaxf(tmp[0], tmp[1]), fmaxf(tmp[2], tmp[3]));
}

// ---------------- mask flag: (sum(xm[0,:]) == 0) ----------------
__global__ __launch_bounds__(256) void mask_k(const float* __restrict__ xm, float* __restrict__ flag) {
    float s = xm[threadIdx.x] + xm[threadIdx.x + 256];
    s = blockSum256(s);
    if (threadIdx.x == 0) flag[0] = (s == 0.f) ? 1.f : 0.f;
}

// ---------------- weight transpose + bf16 cvt (+scale fold): Wt[n][k] = bf16(W[k][n]*s) ----
__global__ __launch_bounds__(256) void transp_k(const float* __restrict__ W, ushort* __restrict__ Wt,
                                                int K, int N, float wscale) {
    __shared__ float Ls[64][65];
    const int t = threadIdx.x;
    const int n0 = blockIdx.x * 64, k0 = blockIdx.y * 64;
    const int kr = t >> 4, n4 = (t & 15) * 4;
#pragma unroll
    for (int p = 0; p < 4; ++p) {
        float4 v = *(const float4*)&W[(size_t)(k0 + kr + p * 16) * N + n0 + n4];
        Ls[kr + p * 16][n4 + 0] = v.x; Ls[kr + p * 16][n4 + 1] = v.y;
        Ls[kr + p * 16][n4 + 2] = v.z; Ls[kr + p * 16][n4 + 3] = v.w;
    }
    __syncthreads();
    const int nr = t >> 4, k4 = (t & 15) * 4;
#pragma unroll
    for (int p = 0; p < 4; ++p) {
        ushort4 o;
        o.x = f2b(Ls[k4 + 0][nr + p * 16] * wscale); o.y = f2b(Ls[k4 + 1][nr + p * 16] * wscale);
        o.z = f2b(Ls[k4 + 2][nr + p * 16] * wscale); o.w = f2b(Ls[k4 + 3][nr + p * 16] * wscale);
        *(ushort4*)&Wt[(size_t)(n0 + nr + p * 16) * K + k0 + k4] = o;
    }
}

// ---------------- fused q/k/v/ow weight transpose (z selects; q pre-scaled) ----------
__global__ __launch_bounds__(256) void transp4_k(const float* __restrict__ qw, const float* __restrict__ kw,
                                                 const float* __restrict__ vw, const float* __restrict__ ow,
                                                 ushort* __restrict__ Wt) {
    const int z = blockIdx.z;
    const float* W = (z == 0) ? qw : (z == 1) ? kw : (z == 2) ? vw : ow;
    const float wscale = (z == 0) ? SCALEc : 1.f;
    ushort* dst = Wt + (size_t)z * Dc * Dc;
    __shared__ float Ls[64][65];
    const int t = threadIdx.x;
    const int n0 = blockIdx.x * 64, k0 = blockIdx.y * 64;
    const int kr = t >> 4, n4 = (t & 15) * 4;
#pragma unroll
    for (int p = 0; p < 4; ++p) {
        float4 v = *(const float4*)&W[(size_t)(k0 + kr + p * 16) * Dc + n0 + n4];
        Ls[kr + p * 16][n4 + 0] = v.x; Ls[kr + p * 16][n4 + 1] = v.y;
        Ls[kr + p * 16][n4 + 2] = v.z; Ls[kr + p * 16][n4 + 3] = v.w;
    }
    __syncthreads();
    const int nr = t >> 4, k4 = (t & 15) * 4;
#pragma unroll
    for (int p = 0; p < 4; ++p) {
        ushort4 o;
        o.x = f2b(Ls[k4 + 0][nr + p * 16] * wscale); o.y = f2b(Ls[k4 + 1][nr + p * 16] * wscale);
        o.z = f2b(Ls[k4 + 2][nr + p * 16] * wscale); o.w = f2b(Ls[k4 + 3][nr + p * 16] * wscale);
        *(ushort4*)&dst[(size_t)(n0 + nr + p * 16) * Dc + k0 + k4] = o;
    }
}

// ---------------- 16-elt loader for fp32 A staging ----------------
__device__ inline void ld16(const float* s, ushort* d) {
#pragma unroll
    for (int i = 0; i < 4; ++i) {
        float4 v = *(const float4*)(s + i * 4);
        d[i * 4 + 0] = f2b(v.x); d[i * 4 + 1] = f2b(v.y);
        d[i * 4 + 2] = f2b(v.z); d[i * 4 + 3] = f2b(v.w);
    }
}

// ---------------- MFMA GEMM (128x128 tile, BK=64, 4 waves, XOR-swizzled LDS) ----------
// Staging: global_load_lds width=16; linear LDS dest + inverse-swizzled global source
// chunk (rule #21) matching the swizzled ds_read. OMODE: 0=fp32, 1=bf16, 2=both.
template <typename TA, int ACT, bool ADDPOS, int OMODE>
__global__ __launch_bounds__(256) void mgemm_k(
    const TA* __restrict__ A, const ushort* __restrict__ Bt,
    const float* __restrict__ bias, const float* __restrict__ pos,
    float* __restrict__ Cf, ushort* __restrict__ Cb,
    int M, int N, int K, float scale)
{
    __shared__ __align__(16) ushort As[128 * 64];
    __shared__ __align__(16) ushort Bs[128 * 64];
    const int tid = threadIdx.x;
    const int nx = gridDim.x;
    const int nwg = nx * gridDim.y;
    int d = blockIdx.x + blockIdx.y * nx;
    if ((nwg & 7) == 0) d = (d & 7) * (nwg >> 3) + (d >> 3); // XCD swizzle, bijective
    const int m0 = (d / nx) * 128, n0 = (d % nx) * 128;
    const int lane = tid & 63, wv = tid >> 6;
    const int wm = (wv >> 1) * 64, wn = (wv & 1) * 64;
    floatx4 acc[4][4] = {};

    const int rA8 = lane >> 3, cch = lane & 7; // gll coords within 8-row issue
    const int srow = tid >> 2, scg = tid & 3;  // reg-stage coords (fp32 A)

    for (int k0 = 0; k0 < K; k0 += 64) {
#pragma unroll
        for (int p = 0; p < 4; ++p) {
            const int r = wv * 32 + p * 8 + rA8;
            const int cs = (cch ^ (r & 7)) * 8;
            gll16(&Bt[(size_t)(n0 + r) * K + k0 + cs], &Bs[(wv * 32 + p * 8) * 64]);
        }
        if constexpr (sizeof(TA) == 2) {
#pragma unroll
            for (int p = 0; p < 4; ++p) {
                const int r = wv * 32 + p * 8 + rA8;
                const int cs = (cch ^ (r & 7)) * 8;
                gll16((const ushort*)&A[(size_t)(m0 + r) * K + k0 + cs], &As[(wv * 32 + p * 8) * 64]);
            }
        } else {
#pragma unroll
            for (int p = 0; p < 2; ++p) {
                const int r = srow + p * 64;
                __align__(16) ushort ta[16];
                ld16(&A[(size_t)(m0 + r) * K + k0 + scg * 16], ta);
                const int base = r * 64, sw = (r & 7) * 8;
                *(short8v*)&As[base + ((scg * 16 + 0) ^ sw)] = *(short8v*)&ta[0];
                *(short8v*)&As[base + ((scg * 16 + 8) ^ sw)] = *(short8v*)&ta[8];
            }
        }
        __syncthreads();
#pragma unroll
        for (int s = 0; s < 2; ++s) {
            short8v af[4], bf_[4];
            const int kg = s * 32 + (lane >> 4) * 8;
#pragma unroll
            for (int f = 0; f < 4; ++f) {
                const int ra = wm + f * 16 + (lane & 15);
                af[f] = *(const short8v*)&As[ra * 64 + (kg ^ ((ra & 7) * 8))];
                const int rb = wn + f * 16 + (lane & 15);
                bf_[f] = *(const short8v*)&Bs[rb * 64 + (kg ^ ((rb & 7) * 8))];
            }
#pragma unroll
            for (int i = 0; i < 4; ++i)
#pragma unroll
                for (int j = 0; j < 4; ++j)
                    acc[i][j] = __builtin_amdgcn_mfma_f32_16x16x32_bf16(af[i], bf_[j], acc[i][j], 0, 0, 0);
        }
        __syncthreads();
    }

    const int cc = lane & 15, rr4 = (lane >> 4) * 4;
#pragma unroll
    for (int i = 0; i < 4; ++i) {
#pragma unroll
        for (int j = 0; j < 4; ++j) {
            const int col = n0 + wn + j * 16 + cc;
            const float bsv = bias[col];
#pragma unroll
            for (int q = 0; q < 4; ++q) {
                const int row = m0 + wm + i * 16 + rr4 + q;
                float v = acc[i][j][q] + bsv;
                if (ADDPOS) v += pos[(size_t)(row & (Sc - 1)) * N + col];
                v *= scale;
                if (ACT == 1) v = fmaxf(v, 0.f);
                if (OMODE == 0) Cf[(size_t)row * N + col] = v;
                else if (OMODE == 1) Cb[(size_t)row * N + col] = f2b(v);
                else { Cf[(size_t)row * N + col] = v; Cb[(size_t)row * N + col] = f2b(v); }
            }
        }
    }
}

// ---------------- fused attention (batch 0): softmax(clip(QK^T))·V -> ao bf16 --------
// Grid (Sc/32, Hc), 256 thr = 4 waves. QK^T on MFMA (swizzled bf16 LDS); clip bounds the
// max at 10, so exp(v-10) needs no online max; row-sums in-register; PV on VALU from LDS.
__global__ __launch_bounds__(256) void fattn_k(
    const float* __restrict__ qkv, ushort* __restrict__ ao, const float* __restrict__ flag)
{
    const int hh = blockIdx.y;
    const int t0 = blockIdx.x * 32;
    __shared__ __align__(16) ushort Qs[32 * 64];
    __shared__ __align__(16) ushort Ks[64 * 64];
    __shared__ float Vs[64][68];
    __shared__ float Ps[32][68];
    __shared__ float rs[4][32];
    const int tid = threadIdx.x;
    const int lane = tid & 63, wv = tid >> 6;
    const bool msk = flag[0] > 0.5f;

    { // stage Q tile (32x64 -> bf16, swizzled)
        const int r = tid >> 3, c = tid & 7;
        const float* src = &qkv[(size_t)(t0 + r) * QKVS + hh * 64 + c * 8];
        float4 v0 = *(const float4*)src, v1 = *(const float4*)(src + 4);
        __align__(16) ushort tmp[8] = {f2b(v0.x), f2b(v0.y), f2b(v0.z), f2b(v0.w),
                                       f2b(v1.x), f2b(v1.y), f2b(v1.z), f2b(v1.w)};
        *(short8v*)&Qs[r * 64 + ((c * 8) ^ ((r & 7) * 8))] = *(short8v*)tmp;
    }
    if (tid < 128) ((float*)rs)[tid] = 0.f;

    float o[8] = {};
    const int pq = tid >> 3, pd = (tid & 7) * 8; // PV ownership: row pq, cols pd..pd+7

    for (int s0 = 0; s0 < Sc; s0 += 64) {
        __syncthreads(); // previous PV readers done before restage
        { // stage V (fp32) and K (bf16 swizzled)
            const int vr = tid >> 2, vc = (tid & 3) * 16;
            const float* vsrc = &qkv[(size_t)(s0 + vr) * QKVS + 2048 + hh * 64 + vc];
#pragma unroll
            for (int u = 0; u < 4; ++u)
                *(float4*)&Vs[vr][vc + u * 4] = *(const float4*)(vsrc + u * 4);
#pragma unroll
            for (int u = 0; u < 2; ++u) {
                const int task = tid + u * 256;
                const int kr = task >> 3, kc = task & 7;
                const float* ksrc = &qkv[(size_t)(s0 + kr) * QKVS + 1024 + hh * 64 + kc * 8];
                float4 a = *(const float4*)ksrc, b = *(const float4*)(ksrc + 4);
                __align__(16) ushort tmp[8] = {f2b(a.x), f2b(a.y), f2b(a.z), f2b(a.w),
                                               f2b(b.x), f2b(b.y), f2b(b.z), f2b(b.w)};
                *(short8v*)&Ks[kr * 64 + ((kc * 8) ^ ((kr & 7) * 8))] = *(short8v*)tmp;
            }
        }
        __syncthreads();
        // QK^T: wave wv owns s-cols [wv*16, wv*16+16), both 16-row q-strips
        floatx4 pacc[2] = {};
#pragma unroll
        for (int i = 0; i < 2; ++i)
#pragma unroll
            for (int s = 0; s < 2; ++s) {
                const int kg = s * 32 + (lane >> 4) * 8;
                const int ra = 16 * i + (lane & 15);
                short8v aq = *(const short8v*)&Qs[ra * 64 + (kg ^ ((ra & 7) * 8))];
                const int rb = 16 * wv + (lane & 15);
                short8v bk = *(const short8v*)&Ks[rb * 64 + (kg ^ ((rb & 7) * 8))];
                pacc[i] = __builtin_amdgcn_mfma_f32_16x16x32_bf16(aq, bk, pacc[i], 0, 0, 0);
            }
        // clip + exp(v-10) + rowsum + write P
        const int cc = lane & 15, rr4 = (lane >> 4) * 4;
#pragma unroll
        for (int i = 0; i < 2; ++i)
#pragma unroll
            for (int q = 0; q < 4; ++q) {
                float v = fminf(fmaxf(pacc[i][q], -10.f), 10.f);
                if (msk) v = -10.f;
                float e = __expf(v - 10.f);
                Ps[16 * i + rr4 + q][wv * 16 + cc] = e;
                float rsum = e;
                rsum += __shfl_xor(rsum, 1, 64);
                rsum += __shfl_xor(rsum, 2, 64);
                rsum += __shfl_xor(rsum, 4, 64);
                rsum += __shfl_xor(rsum, 8, 64);
                if (cc == 0) rs[wv][16 * i + rr4 + q] += rsum;
            }
        __syncthreads();
        // PV (VALU): o[pq][pd..pd+7] += P[pq][ss] * V[ss][pd..pd+7]
#pragma unroll 8
        for (int ss = 0; ss < 64; ++ss) {
            float p = Ps[pq][ss];
#pragma unroll
            for (int u = 0; u < 8; ++u) o[u] += p * Vs[ss][pd + u];
        }
    }
    __syncthreads();
    float inv = 1.f / (rs[0][pq] + rs[1][pq] + rs[2][pq] + rs[3][pq]);
#pragma unroll
    for (int u = 0; u < 8; ++u)
        ao[(size_t)(t0 + pq) * Dc + hh * 64 + pd + u] = f2b(o[u] * inv);
}

// ---------------- fp32 VALU GEMM (head composition): C = A@W ----------------
template <typename TA, int ACT, bool ADDPOS, bool OUT_BF16, bool HASB>
__global__ __launch_bounds__(256) void gemm_k(
    const TA* __restrict__ A, const float* __restrict__ W,
    const float* __restrict__ bias, const float* __restrict__ pos,
    float* __restrict__ Cf, bf16* __restrict__ Cb,
    int M, int N, int K, float scale)
{
    __shared__ float As[16][68];
    __shared__ float Ws[16][68];
    const int tid = threadIdx.x;
    const int m0 = blockIdx.y * 64, n0 = blockIdx.x * 64;
    const int ty = tid >> 4, tx = tid & 15;
    float c[4][4] = {};

    const int ka = tid & 15, mb = tid >> 4;
    const int nw = tid & 63, kb = tid >> 6;

    for (int k0 = 0; k0 < K; k0 += 16) {
#pragma unroll
        for (int j = 0; j < 4; ++j) {
            int m = mb + 16 * j;
            As[ka][m] = ldf(&A[(size_t)(m0 + m) * K + k0 + ka]);
        }
#pragma unroll
        for (int j = 0; j < 4; ++j) {
            int k = kb + 4 * j;
            Ws[k][nw] = W[(size_t)(k0 + k) * N + n0 + nw];
        }
        __syncthreads();
#pragma unroll
        for (int k = 0; k < 16; ++k) {
            float4 av = *(const float4*)&As[k][ty * 4];
            float4 wv = *(const float4*)&Ws[k][tx * 4];
            float a[4] = {av.x, av.y, av.z, av.w};
            float w[4] = {wv.x, wv.y, wv.z, wv.w};
#pragma unroll
            for (int i = 0; i < 4; ++i)
#pragma unroll
                for (int j = 0; j < 4; ++j) c[i][j] += a[i] * w[j];
        }
        __syncthreads();
    }

#pragma unroll
    for (int i = 0; i < 4; ++i) {
        int m = m0 + ty * 4 + i;
#pragma unroll
        for (int j = 0; j < 4; ++j) {
            int n = n0 + tx * 4 + j;
            float v = c[i][j] + (HASB ? bias[n] : 0.f);
            if (ADDPOS) v += pos[(size_t)(m & (Sc - 1)) * N + n];
            v *= scale;
            if (ACT == 1) v = fmaxf(v, 0.f);
            if (OUT_BF16) Cb[(size_t)m * N + n] = __float2bfloat16(v);
            else          Cf[(size_t)m * N + n] = v;
        }
    }
}

// ---------------- fused head bias chain ----------------
__global__ __launch_bounds__(256) void biaschain_k(
    const float* __restrict__ fc1b, const float* __restrict__ fc2w, const float* __restrict__ fc2b,
    const float* __restrict__ fc3w, const float* __restrict__ fc3b, float* __restrict__ bc)
{
    __shared__ float vs[256];
    const int t = threadIdx.x;
    float v = fc1b[t];
    for (int r = 0; r < 5; ++r) {
        vs[t] = v; __syncthreads();
        float s = fc2b[t];
#pragma unroll 8
        for (int k = 0; k < 256; ++k) s += vs[k] * fc2w[k * 256 + t];
        v = s; __syncthreads();
    }
    vs[t] = v; __syncthreads();
    float s = fc3b[t];
#pragma unroll 8
    for (int k = 0; k < 256; ++k) s += vs[k] * fc3w[k * 256 + t];
    bc[t] = s;
}

// ---------------- qkv bias concat (q-part pre-scaled) ----------------
__global__ __launch_bounds__(256) void qkvbias_k(
    const float* __restrict__ qb, const float* __restrict__ kb, const float* __restrict__ vb,
    float* __restrict__ o)
{
    int i = blockIdx.x * 256 + threadIdx.x; // grid 12
    float v = (i < 1024) ? qb[i] * SCALEc : ((i < 2048) ? kb[i - 1024] : vb[i - 2048]);
    o[i] = v;
}

// ---------------- row softmax (obv: clip + softmax over D) ----------------
__global__ __launch_bounds__(256) void softmax_k(
    const float* __restrict__ in, float* __restrict__ out, int ncols, int doclip)
{
    const int row = blockIdx.x;
    const float* ip = in + (size_t)row * ncols;
    float* op = out + (size_t)row * ncols;
    const int nj = ncols >> 8;
    float r[4];
    float mx = -1e30f;
    for (int j = 0; j < nj; ++j) {
        float v = ip[threadIdx.x + 256 * j];
        if (doclip) v = fminf(fmaxf(v, -10.f), 10.f);
        r[j] = v;
        mx = fmaxf(mx, v);
    }
    mx = blockMax256(mx);
    float s = 0.f;
    for (int j = 0; j < nj; ++j) { r[j] = expf(r[j] - mx); s += r[j]; }
    s = blockSum256(s);
    float inv = 1.f / s;
    for (int j = 0; j < nj; ++j) op[threadIdx.x + 256 * j] = r[j] * inv;
}

// ---------------- hb = bf16(LN(hb + add)) ; residual state is bf16-only ----------------
template <bool BCAST, typename TADD>
__global__ __launch_bounds__(256) void add_ln_k(
    ushort* __restrict__ hb, const TADD* __restrict__ add,
    const float* __restrict__ g, const float* __restrict__ b)
{
    const int row = blockIdx.x;
    const TADD* ap = BCAST ? add + (size_t)(row & (Sc - 1)) * Dc : add + (size_t)row * Dc;
    ushort* hp = hb + (size_t)row * Dc;
    const int tid = threadIdx.x;
    const int c0 = tid * 4;
    ushort4 hv = *(const ushort4*)&hp[c0];
    float x[4] = {b2f(hv.x), b2f(hv.y), b2f(hv.z), b2f(hv.w)};
#pragma unroll
    for (int j = 0; j < 4; ++j) x[j] += ldf(&ap[c0 + j]);
    float s = x[0] + x[1] + x[2] + x[3];
    float mean = blockSum256(s) * (1.f / (float)Dc);
    float vsum = 0.f;
#pragma unroll
    for (int j = 0; j < 4; ++j) { float d = x[j] - mean; vsum += d * d; }
    float var = blockSum256(vsum) * (1.f / (float)Dc);
    float inv = rsqrtf(var + 1e-5f);
    float4 gv = *(const float4*)&g[c0];
    float4 bv = *(const float4*)&b[c0];
    ushort4 ov;
    ov.x = f2b((x[0] - mean) * inv * gv.x + bv.x);
    ov.y = f2b((x[1] - mean) * inv * gv.y + bv.y);
    ov.z = f2b((x[2] - mean) * inv * gv.z + bv.z);
    ov.w = f2b((x[3] - mean) * inv * gv.w + bv.w);
    *(ushort4*)&hp[c0] = ov;
}

// ---------------- launch ----------------
extern "C" void kernel_launch(void* const* d_in, const int* in_sizes, int n_in,
                              void* d_out, int out_size, void* d_ws, size_t ws_size,
                              hipStream_t stream)
{
    const float* x      = (const float*)d_in[0];
    const float* xm     = (const float*)d_in[1];
    // d_in[2] vecSelector: assert-only, unused
    const float* proj_w = (const float*)d_in[3];
    const float* proj_b = (const float*)d_in[4];
    const float* pos    = (const float*)d_in[5];
    const float* qw     = (const float*)d_in[6];
    const float* qb     = (const float*)d_in[7];
    const float* kw     = (const float*)d_in[8];
    const float* kb     = (const float*)d_in[9];
    const float* vw     = (const float*)d_in[10];
    const float* vb     = (const float*)d_in[11];
    const float* ow     = (const float*)d_in[12];
    const float* obias  = (const float*)d_in[13];
    const float* ln1g   = (const float*)d_in[14];
    const float* ln1b   = (const float*)d_in[15];
    const float* ln2g   = (const float*)d_in[16];
    const float* ln2b   = (const float*)d_in[17];
    const float* w1     = (const float*)d_in[18];
    const float* b1     = (const float*)d_in[19];
    const float* w2     = (const float*)d_in[20];
    const float* b2     = (const float*)d_in[21];
    const float* fc1w   = (const float*)d_in[22];
    const float* fc1b   = (const float*)d_in[23];
    const float* fc2w   = (const float*)d_in[24];
    const float* fc2b   = (const float*)d_in[25];
    const float* fc3w   = (const float*)d_in[26];
    const float* fc3b   = (const float*)d_in[27];

    float* ws = (float*)d_ws;
    const size_t HSZ = (size_t)Bc * Sc * Dc; // 8,388,608 floats
    // region0: hb (bf16 residual, 16 MiB) + ffu (bf16 w2 out, 16 MiB)
    ushort* hb  = (ushort*)ws;
    ushort* ffu = (ushort*)(ws + HSZ / 2);
    float* rgA  = ws + HSZ;           // attn temps | FFN mid (bf16) | head comp temps
    float* rgB  = ws + 2 * HSZ;       // Wt
    float* flag = ws + 3 * HSZ;

    // rgA offsets (floats)
    float* qkvf  = rgA;                                  // 512*3072 fp32
    ushort* aovu = (ushort*)(rgA + 1572864);             // 512*1024 bf16
    float* obv   = rgA + 1835008;                        // 512*1024 fp32
    float* qkvb  = rgA + 2359296;                        // 3072
    ushort* midu = (ushort*)rgA;                         // 8192*2048 bf16 (FFN phase)

    ushort* Wt = (ushort*)rgB;                           // rolling bf16 W^T, <=8 MiB

    // head-composition temps (rgA free after last FFN)
    float* W2  = rgA;                   // 256*256
    float* W4  = rgA + 65536;
    float* W5  = rgA + 131072;
    float* C1  = rgA + 196608;          // 1024*256
    float* Wc  = rgA + 458752;          // 1024*256
    float* bcv = rgA + 720896;          // 256

    const int MR = Bc * Sc; // 8192

    mask_k<<<1, 256, 0, stream>>>(xm, flag);

    // hb = bf16(x @ proj_w + proj_b + pos)   (MFMA)
    transp_k<<<dim3(Dc / 64, INc / 64), 256, 0, stream>>>(proj_w, Wt, INc, Dc, 1.f);
    mgemm_k<float, 0, true, 1><<<dim3(Dc / 128, MR / 128), 256, 0, stream>>>(
        x, Wt, proj_b, pos, nullptr, hb, MR, Dc, INc, 1.f);

    for (int l = 0; l < Lc; ++l) {
        const float* qw_l = qw + (size_t)l * Dc * Dc; const float* qb_l = qb + l * Dc;
        const float* kw_l = kw + (size_t)l * Dc * Dc; const float* kb_l = kb + l * Dc;
        const float* vw_l = vw + (size_t)l * Dc * Dc; const float* vb_l = vb + l * Dc;
        const float* ow_l = ow + (size_t)l * Dc * Dc; const float* ob_l = obias + l * Dc;
        const float* w1_l = w1 + (size_t)l * Dc * DFFc; const float* b1_l = b1 + l * DFFc;
        const float* w2_l = w2 + (size_t)l * DFFc * Dc; const float* b2_l = b2 + l * Dc;

        // attention: batch 0 only (sa = ao[0] is all that survives)
        transp4_k<<<dim3(Dc / 64, Dc / 64, 4), 256, 0, stream>>>(qw_l, kw_l, vw_l, ow_l, Wt);
        qkvbias_k<<<12, 256, 0, stream>>>(qb_l, kb_l, vb_l, qkvb);
        mgemm_k<ushort, 0, false, 0><<<dim3(QKVS / 128, Sc / 128), 256, 0, stream>>>(
            hb, Wt, qkvb, nullptr, qkvf, nullptr, Sc, QKVS, Dc, 1.f);
        fattn_k<<<dim3(Sc / 32, Hc), 256, 0, stream>>>(qkvf, aovu, flag);
        mgemm_k<ushort, 0, false, 0><<<dim3(Dc / 128, Sc / 128), 256, 0, stream>>>(
            aovu, Wt + (size_t)3 * Dc * Dc, ob_l, nullptr, obv, nullptr, Sc, Dc, Dc, 1.f);
        softmax_k<<<Sc, 256, 0, stream>>>(obv, obv, Dc, 1); // forward hook: clip+softmax over D
        add_ln_k<true, float><<<MR, 256, 0, stream>>>(hb, obv, ln1g + l * Dc, ln1b + l * Dc);

        // FFN (all batches, MFMA, bf16 operands via global_load_lds)
        transp_k<<<dim3(DFFc / 64, Dc / 64), 256, 0, stream>>>(w1_l, Wt, Dc, DFFc, 1.f);
        mgemm_k<ushort, 1, false, 1><<<dim3(DFFc / 128, MR / 128), 256, 0, stream>>>(
            hb, Wt, b1_l, nullptr, nullptr, midu, MR, DFFc, Dc, 1.f);
        transp_k<<<dim3(Dc / 64, DFFc / 64), 256, 0, stream>>>(w2_l, Wt, DFFc, Dc, 1.f);
        mgemm_k<ushort, 0, false, 1><<<dim3(Dc / 128, MR / 128), 256, 0, stream>>>(
            midu, Wt, b2_l, nullptr, nullptr, ffu, MR, Dc, DFFc, 1.f);
        add_ln_k<false, ushort><<<MR, 256, 0, stream>>>(hb, ffu, ln2g + l * Dc, ln2b + l * Dc);
    }

    // ---- head: out = h @ Wc + bc, Wc = fc1_w·fc2_w^5·fc3_w (fc2 affine, applied 5x) ----
    gemm_k<float, 0, false, false, false><<<dim3(4, 4), 256, 0, stream>>>(
        fc2w, fc2w, nullptr, nullptr, W2, nullptr, HIDc, HIDc, HIDc, 1.f);
    gemm_k<float, 0, false, false, false><<<dim3(4, 4), 256, 0, stream>>>(
        W2, W2, nullptr, nullptr, W4, nullptr, HIDc, HIDc, HIDc, 1.f);
    gemm_k<float, 0, false, false, false><<<dim3(4, 4), 256, 0, stream>>>(
        W4, fc2w, nullptr, nullptr, W5, nullptr, HIDc, HIDc, HIDc, 1.f);
    gemm_k<float, 0, false, false, false><<<dim3(4, 16), 256, 0, stream>>>(
        fc1w, W5, nullptr, nullptr, C1, nullptr, Dc, HIDc, HIDc, 1.f);
    gemm_k<float, 0, false, false, false><<<dim3(4, 16), 256, 0, stream>>>(
        C1, fc3w, nullptr, nullptr, Wc, nullptr, Dc, HIDc, HIDc, 1.f);
    biaschain_k<<<1, 256, 0, stream>>>(fc1b, fc2w, fc2b, fc3w, fc3b, bcv);
    transp_k<<<dim3(HIDc / 64, Dc / 64), 256, 0, stream>>>(Wc, Wt, Dc, HIDc, 1.f);
    mgemm_k<ushort, 0, false, 0><<<dim3(HIDc / 128, MR / 128), 256, 0, stream>>>(
        hb, Wt, bcv, nullptr, (float*)d_out, nullptr, MR, HIDc, Dc, 1.f);
}

// Round 9
// 1398.498 us; speedup vs baseline: 5.6602x; 1.0034x over previous
//
#include <hip/hip_runtime.h>
#include <hip/hip_bf16.h>

using bf16 = __hip_bfloat16;
typedef __attribute__((ext_vector_type(8))) short short8v;
typedef __attribute__((ext_vector_type(4))) float floatx4;

// Problem dims
constexpr int Bc = 16, Sc = 512, INc = 512, OUTc = 256;
constexpr int Dc = 1024, Hc = 16, Lc = 6, DFFc = 2048, HIDc = 256;
constexpr float SCALEc = 0.125f; // HD^-0.5
constexpr int QKVS = 3072;       // fused qkv row stride
constexpr size_t LSLOT = 8388608; // ushorts per layer weight slot (16 MiB): qkvo|w1|w2

__device__ inline ushort f2b(float f) { // fp32 -> bf16 RNE
    union { float f; unsigned u; } v; v.f = f;
    unsigned r = (v.u + 0x7FFF + ((v.u >> 16) & 1)) >> 16;
    return (ushort)r;
}
__device__ inline float b2f(ushort b) {
    union { unsigned u; float f; } v; v.u = ((unsigned)b) << 16;
    return v.f;
}
__device__ inline float ldf(const float* p) { return *p; }
__device__ inline float ldf(const ushort* p) { return b2f(*p); }

// async global->LDS, 16 B per lane. LDS dest is wave-uniform base + lane*16 (m104).
__device__ inline void gll16(const ushort* g, ushort* l) {
    __builtin_amdgcn_global_load_lds(
        (const __attribute__((address_space(1))) unsigned int*)g,
        (__attribute__((address_space(3))) unsigned int*)l, 16, 0, 0);
}

// ---------------- block reductions (256 threads, wave64) ----------------
__device__ inline float blockSum256(float v) {
    __shared__ float tmp[4];
#pragma unroll
    for (int o = 32; o > 0; o >>= 1) v += __shfl_xor(v, o, 64);
    int w = threadIdx.x >> 6;
    __syncthreads();
    if ((threadIdx.x & 63) == 0) tmp[w] = v;
    __syncthreads();
    return tmp[0] + tmp[1] + tmp[2] + tmp[3];
}
__device__ inline float blockMax256(float v) {
    __shared__ float tmp[4];
#pragma unroll
    for (int o = 32; o > 0; o >>= 1) v = fmaxf(v, __shfl_xor(v, o, 64));
    int w = threadIdx.x >> 6;
    __syncthreads();
    if ((threadIdx.x & 63) == 0) tmp[w] = v;
    __syncthreads();
    return fmaxf(fmaxf(tmp[0], tmp[1]), fmaxf(tmp[2], tmp[3]));
}

// ---------------- mask flag: (sum(xm[0,:]) == 0) ----------------
__global__ __launch_bounds__(256) void mask_k(const float* __restrict__ xm, float* __restrict__ flag) {
    float s = xm[threadIdx.x] + xm[threadIdx.x + 256];
    s = blockSum256(s);
    if (threadIdx.x == 0) flag[0] = (s == 0.f) ? 1.f : 0.f;
}

// ---------------- weight transpose + bf16 cvt: Wt[n][k] = bf16(W[k][n]*s) ----------------
__global__ __launch_bounds__(256) void transp_k(const float* __restrict__ W, ushort* __restrict__ Wt,
                                                int K, int N, float wscale) {
    __shared__ float Ls[64][65];
    const int t = threadIdx.x;
    const int n0 = blockIdx.x * 64, k0 = blockIdx.y * 64;
    const int kr = t >> 4, n4 = (t & 15) * 4;
#pragma unroll
    for (int p = 0; p < 4; ++p) {
        float4 v = *(const float4*)&W[(size_t)(k0 + kr + p * 16) * N + n0 + n4];
        Ls[kr + p * 16][n4 + 0] = v.x; Ls[kr + p * 16][n4 + 1] = v.y;
        Ls[kr + p * 16][n4 + 2] = v.z; Ls[kr + p * 16][n4 + 3] = v.w;
    }
    __syncthreads();
    const int nr = t >> 4, k4 = (t & 15) * 4;
#pragma unroll
    for (int p = 0; p < 4; ++p) {
        ushort4 o;
        o.x = f2b(Ls[k4 + 0][nr + p * 16] * wscale); o.y = f2b(Ls[k4 + 1][nr + p * 16] * wscale);
        o.z = f2b(Ls[k4 + 2][nr + p * 16] * wscale); o.w = f2b(Ls[k4 + 3][nr + p * 16] * wscale);
        *(ushort4*)&Wt[(size_t)(n0 + nr + p * 16) * K + k0 + k4] = o;
    }
}

// ---------------- batched layer-weight transpose ----------------
// z = (l-l0)*6 + m; m: 0..3 -> qw/kw/vw/ow (DxD, q pre-scaled), 4 -> w1, 5 -> w2.
// Layer slot layout (ushorts): qkvo @0 (4M), w1 @4M (2M), w2 @6M (2M). Grid (32,32,6*nl).
__global__ __launch_bounds__(256) void transpall_k(
    const float* __restrict__ qw, const float* __restrict__ kw, const float* __restrict__ vw,
    const float* __restrict__ ow, const float* __restrict__ w1, const float* __restrict__ w2,
    ushort* __restrict__ Wt, int l0, size_t lstride)
{
    const int z = blockIdx.z;
    const int l = l0 + z / 6, m = z % 6;
    ushort* slot = Wt + (size_t)(z / 6) * lstride;
    const float* W; ushort* dst; int K, N; float wscale = 1.f;
    switch (m) {
        case 0: W = qw + (size_t)l * Dc * Dc; K = Dc; N = Dc; dst = slot; wscale = SCALEc; break;
        case 1: W = kw + (size_t)l * Dc * Dc; K = Dc; N = Dc; dst = slot + 1048576; break;
        case 2: W = vw + (size_t)l * Dc * Dc; K = Dc; N = Dc; dst = slot + 2097152; break;
        case 3: W = ow + (size_t)l * Dc * Dc; K = Dc; N = Dc; dst = slot + 3145728; break;
        case 4: W = w1 + (size_t)l * Dc * DFFc; K = Dc; N = DFFc; dst = slot + 4194304; break;
        default: W = w2 + (size_t)l * DFFc * Dc; K = DFFc; N = Dc; dst = slot + 6291456; break;
    }
    if (blockIdx.x >= N / 64 || blockIdx.y >= K / 64) return;
    __shared__ float Ls[64][65];
    const int t = threadIdx.x;
    const int n0 = blockIdx.x * 64, k0 = blockIdx.y * 64;
    const int kr = t >> 4, n4 = (t & 15) * 4;
#pragma unroll
    for (int p = 0; p < 4; ++p) {
        float4 v = *(const float4*)&W[(size_t)(k0 + kr + p * 16) * N + n0 + n4];
        Ls[kr + p * 16][n4 + 0] = v.x; Ls[kr + p * 16][n4 + 1] = v.y;
        Ls[kr + p * 16][n4 + 2] = v.z; Ls[kr + p * 16][n4 + 3] = v.w;
    }
    __syncthreads();
    const int nr = t >> 4, k4 = (t & 15) * 4;
#pragma unroll
    for (int p = 0; p < 4; ++p) {
        ushort4 o;
        o.x = f2b(Ls[k4 + 0][nr + p * 16] * wscale); o.y = f2b(Ls[k4 + 1][nr + p * 16] * wscale);
        o.z = f2b(Ls[k4 + 2][nr + p * 16] * wscale); o.w = f2b(Ls[k4 + 3][nr + p * 16] * wscale);
        *(ushort4*)&dst[(size_t)(n0 + nr + p * 16) * K + k0 + k4] = o;
    }
}

// ---------------- 16-elt loader for fp32 A staging ----------------
__device__ inline void ld16(const float* s, ushort* d) {
#pragma unroll
    for (int i = 0; i < 4; ++i) {
        float4 v = *(const float4*)(s + i * 4);
        d[i * 4 + 0] = f2b(v.x); d[i * 4 + 1] = f2b(v.y);
        d[i * 4 + 2] = f2b(v.z); d[i * 4 + 3] = f2b(v.w);
    }
}

// ---------------- MFMA GEMM (128x128 tile, BK=64, 4 waves, XOR-swizzled LDS) ----------
// Staging: global_load_lds width=16; linear LDS dest + inverse-swizzled global source
// chunk (rule #21) matching the swizzled ds_read. OMODE: 0=fp32, 1=bf16, 2=both.
template <typename TA, int ACT, bool ADDPOS, int OMODE>
__global__ __launch_bounds__(256) void mgemm_k(
    const TA* __restrict__ A, const ushort* __restrict__ Bt,
    const float* __restrict__ bias, const float* __restrict__ pos,
    float* __restrict__ Cf, ushort* __restrict__ Cb,
    int M, int N, int K, float scale)
{
    __shared__ __align__(16) ushort As[128 * 64];
    __shared__ __align__(16) ushort Bs[128 * 64];
    const int tid = threadIdx.x;
    const int nx = gridDim.x;
    const int nwg = nx * gridDim.y;
    int d = blockIdx.x + blockIdx.y * nx;
    if ((nwg & 7) == 0) d = (d & 7) * (nwg >> 3) + (d >> 3); // XCD swizzle, bijective
    const int m0 = (d / nx) * 128, n0 = (d % nx) * 128;
    const int lane = tid & 63, wv = tid >> 6;
    const int wm = (wv >> 1) * 64, wn = (wv & 1) * 64;
    floatx4 acc[4][4] = {};

    const int rA8 = lane >> 3, cch = lane & 7; // gll coords within 8-row issue
    const int srow = tid >> 2, scg = tid & 3;  // reg-stage coords (fp32 A)

    for (int k0 = 0; k0 < K; k0 += 64) {
#pragma unroll
        for (int p = 0; p < 4; ++p) {
            const int r = wv * 32 + p * 8 + rA8;
            const int cs = (cch ^ (r & 7)) * 8;
            gll16(&Bt[(size_t)(n0 + r) * K + k0 + cs], &Bs[(wv * 32 + p * 8) * 64]);
        }
        if constexpr (sizeof(TA) == 2) {
#pragma unroll
            for (int p = 0; p < 4; ++p) {
                const int r = wv * 32 + p * 8 + rA8;
                const int cs = (cch ^ (r & 7)) * 8;
                gll16((const ushort*)&A[(size_t)(m0 + r) * K + k0 + cs], &As[(wv * 32 + p * 8) * 64]);
            }
        } else {
#pragma unroll
            for (int p = 0; p < 2; ++p) {
                const int r = srow + p * 64;
                __align__(16) ushort ta[16];
                ld16(&A[(size_t)(m0 + r) * K + k0 + scg * 16], ta);
                const int base = r * 64, sw = (r & 7) * 8;
                *(short8v*)&As[base + ((scg * 16 + 0) ^ sw)] = *(short8v*)&ta[0];
                *(short8v*)&As[base + ((scg * 16 + 8) ^ sw)] = *(short8v*)&ta[8];
            }
        }
        __syncthreads();
#pragma unroll
        for (int s = 0; s < 2; ++s) {
            short8v af[4], bf_[4];
            const int kg = s * 32 + (lane >> 4) * 8;
#pragma unroll
            for (int f = 0; f < 4; ++f) {
                const int ra = wm + f * 16 + (lane & 15);
                af[f] = *(const short8v*)&As[ra * 64 + (kg ^ ((ra & 7) * 8))];
                const int rb = wn + f * 16 + (lane & 15);
                bf_[f] = *(const short8v*)&Bs[rb * 64 + (kg ^ ((rb & 7) * 8))];
            }
#pragma unroll
            for (int i = 0; i < 4; ++i)
#pragma unroll
                for (int j = 0; j < 4; ++j)
                    acc[i][j] = __builtin_amdgcn_mfma_f32_16x16x32_bf16(af[i], bf_[j], acc[i][j], 0, 0, 0);
        }
        __syncthreads();
    }

    const int cc = lane & 15, rr4 = (lane >> 4) * 4;
#pragma unroll
    for (int i = 0; i < 4; ++i) {
#pragma unroll
        for (int j = 0; j < 4; ++j) {
            const int col = n0 + wn + j * 16 + cc;
            const float bsv = bias[col];
#pragma unroll
            for (int q = 0; q < 4; ++q) {
                const int row = m0 + wm + i * 16 + rr4 + q;
                float v = acc[i][j][q] + bsv;
                if (ADDPOS) v += pos[(size_t)(row & (Sc - 1)) * N + col];
                v *= scale;
                if (ACT == 1) v = fmaxf(v, 0.f);
                if (OMODE == 0) Cf[(size_t)row * N + col] = v;
                else if (OMODE == 1) Cb[(size_t)row * N + col] = f2b(v);
                else { Cf[(size_t)row * N + col] = v; Cb[(size_t)row * N + col] = f2b(v); }
            }
        }
    }
}

// ---------------- fused attention (batch 0, bf16 qkv): softmax(clip(QK^T))·V -> ao ----
// Grid (Sc/32, Hc), 256 thr = 4 waves. QK^T on MFMA (swizzled bf16 LDS); clip bounds the
// max at 10, so exp(v-10) needs no online max; row-sums in-register; PV on VALU from LDS.
__global__ __launch_bounds__(256) void fattn_k(
    const ushort* __restrict__ qkv, ushort* __restrict__ ao, const float* __restrict__ flag)
{
    const int hh = blockIdx.y;
    const int t0 = blockIdx.x * 32;
    __shared__ __align__(16) ushort Qs[32 * 64];
    __shared__ __align__(16) ushort Ks[64 * 64];
    __shared__ float Vs[64][68];
    __shared__ float Ps[32][68];
    __shared__ float rs[4][32];
    const int tid = threadIdx.x;
    const int lane = tid & 63, wv = tid >> 6;
    const bool msk = flag[0] > 0.5f;

    { // stage Q tile (32x64, swizzled copy)
        const int r = tid >> 3, c = tid & 7;
        short8v q = *(const short8v*)&qkv[(size_t)(t0 + r) * QKVS + hh * 64 + c * 8];
        *(short8v*)&Qs[r * 64 + ((c * 8) ^ ((r & 7) * 8))] = q;
    }
    if (tid < 128) ((float*)rs)[tid] = 0.f;

    float o[8] = {};
    const int pq = tid >> 3, pd = (tid & 7) * 8; // PV ownership: row pq, cols pd..pd+7

    for (int s0 = 0; s0 < Sc; s0 += 64) {
        __syncthreads(); // previous PV readers done before restage
        { // stage V (bf16 -> f32 LDS) and K (swizzled copy)
            const int vr = tid >> 2, vc = (tid & 3) * 16;
            const ushort* vsrc = &qkv[(size_t)(s0 + vr) * QKVS + 2048 + hh * 64 + vc];
            short8v v0 = *(const short8v*)vsrc, v1 = *(const short8v*)(vsrc + 8);
#pragma unroll
            for (int u = 0; u < 8; ++u) {
                Vs[vr][vc + u] = b2f((ushort)v0[u]);
                Vs[vr][vc + 8 + u] = b2f((ushort)v1[u]);
            }
#pragma unroll
            for (int u = 0; u < 2; ++u) {
                const int task = tid + u * 256;
                const int kr = task >> 3, kc = task & 7;
                short8v kvv = *(const short8v*)&qkv[(size_t)(s0 + kr) * QKVS + 1024 + hh * 64 + kc * 8];
                *(short8v*)&Ks[kr * 64 + ((kc * 8) ^ ((kr & 7) * 8))] = kvv;
            }
        }
        __syncthreads();
        // QK^T: wave wv owns s-cols [wv*16, wv*16+16), both 16-row q-strips
        floatx4 pacc[2] = {};
#pragma unroll
        for (int i = 0; i < 2; ++i)
#pragma unroll
            for (int s = 0; s < 2; ++s) {
                const int kg = s * 32 + (lane >> 4) * 8;
                const int ra = 16 * i + (lane & 15);
                short8v aq = *(const short8v*)&Qs[ra * 64 + (kg ^ ((ra & 7) * 8))];
                const int rb = 16 * wv + (lane & 15);
                short8v bk = *(const short8v*)&Ks[rb * 64 + (kg ^ ((rb & 7) * 8))];
                pacc[i] = __builtin_amdgcn_mfma_f32_16x16x32_bf16(aq, bk, pacc[i], 0, 0, 0);
            }
        // clip + exp(v-10) + rowsum + write P
        const int cc = lane & 15, rr4 = (lane >> 4) * 4;
#pragma unroll
        for (int i = 0; i < 2; ++i)
#pragma unroll
            for (int q = 0; q < 4; ++q) {
                float v = fminf(fmaxf(pacc[i][q], -10.f), 10.f);
                if (msk) v = -10.f;
                float e = __expf(v - 10.f);
                Ps[16 * i + rr4 + q][wv * 16 + cc] = e;
                float rsum = e;
                rsum += __shfl_xor(rsum, 1, 64);
                rsum += __shfl_xor(rsum, 2, 64);
                rsum += __shfl_xor(rsum, 4, 64);
                rsum += __shfl_xor(rsum, 8, 64);
                if (cc == 0) rs[wv][16 * i + rr4 + q] += rsum;
            }
        __syncthreads();
        // PV (VALU): o[pq][pd..pd+7] += P[pq][ss] * V[ss][pd..pd+7]
#pragma unroll 8
        for (int ss = 0; ss < 64; ++ss) {
            float p = Ps[pq][ss];
#pragma unroll
            for (int u = 0; u < 8; ++u) o[u] += p * Vs[ss][pd + u];
        }
    }
    __syncthreads();
    float inv = 1.f / (rs[0][pq] + rs[1][pq] + rs[2][pq] + rs[3][pq]);
#pragma unroll
    for (int u = 0; u < 8; ++u)
        ao[(size_t)(t0 + pq) * Dc + hh * 64 + pd + u] = f2b(o[u] * inv);
}

// ---------------- fp32 VALU GEMM (head composition): C = A@W ----------------
template <typename TA, int ACT, bool ADDPOS, bool OUT_BF16, bool HASB>
__global__ __launch_bounds__(256) void gemm_k(
    const TA* __restrict__ A, const float* __restrict__ W,
    const float* __restrict__ bias, const float* __restrict__ pos,
    float* __restrict__ Cf, bf16* __restrict__ Cb,
    int M, int N, int K, float scale)
{
    __shared__ float As[16][68];
    __shared__ float Ws[16][68];
    const int tid = threadIdx.x;
    const int m0 = blockIdx.y * 64, n0 = blockIdx.x * 64;
    const int ty = tid >> 4, tx = tid & 15;
    float c[4][4] = {};

    const int ka = tid & 15, mb = tid >> 4;
    const int nw = tid & 63, kb = tid >> 6;

    for (int k0 = 0; k0 < K; k0 += 16) {
#pragma unroll
        for (int j = 0; j < 4; ++j) {
            int m = mb + 16 * j;
            As[ka][m] = ldf(&A[(size_t)(m0 + m) * K + k0 + ka]);
        }
#pragma unroll
        for (int j = 0; j < 4; ++j) {
            int k = kb + 4 * j;
            Ws[k][nw] = W[(size_t)(k0 + k) * N + n0 + nw];
        }
        __syncthreads();
#pragma unroll
        for (int k = 0; k < 16; ++k) {
            float4 av = *(const float4*)&As[k][ty * 4];
            float4 wv = *(const float4*)&Ws[k][tx * 4];
            float a[4] = {av.x, av.y, av.z, av.w};
            float w[4] = {wv.x, wv.y, wv.z, wv.w};
#pragma unroll
            for (int i = 0; i < 4; ++i)
#pragma unroll
                for (int j = 0; j < 4; ++j) c[i][j] += a[i] * w[j];
        }
        __syncthreads();
    }

#pragma unroll
    for (int i = 0; i < 4; ++i) {
        int m = m0 + ty * 4 + i;
#pragma unroll
        for (int j = 0; j < 4; ++j) {
            int n = n0 + tx * 4 + j;
            float v = c[i][j] + (HASB ? bias[n] : 0.f);
            if (ADDPOS) v += pos[(size_t)(m & (Sc - 1)) * N + n];
            v *= scale;
            if (ACT == 1) v = fmaxf(v, 0.f);
            if (OUT_BF16) Cb[(size_t)m * N + n] = __float2bfloat16(v);
            else          Cf[(size_t)m * N + n] = v;
        }
    }
}

// ---------------- fused head bias chain ----------------
__global__ __launch_bounds__(256) void biaschain_k(
    const float* __restrict__ fc1b, const float* __restrict__ fc2w, const float* __restrict__ fc2b,
    const float* __restrict__ fc3w, const float* __restrict__ fc3b, float* __restrict__ bc)
{
    __shared__ float vs[256];
    const int t = threadIdx.x;
    float v = fc1b[t];
    for (int r = 0; r < 5; ++r) {
        vs[t] = v; __syncthreads();
        float s = fc2b[t];
#pragma unroll 8
        for (int k = 0; k < 256; ++k) s += vs[k] * fc2w[k * 256 + t];
        v = s; __syncthreads();
    }
    vs[t] = v; __syncthreads();
    float s = fc3b[t];
#pragma unroll 8
    for (int k = 0; k < 256; ++k) s += vs[k] * fc3w[k * 256 + t];
    bc[t] = s;
}

// ---------------- qkv bias concat for ALL layers (q-part pre-scaled) ----------------
__global__ __launch_bounds__(256) void qkvbiasall_k(
    const float* __restrict__ qb, const float* __restrict__ kb, const float* __restrict__ vb,
    float* __restrict__ o)
{
    int i = blockIdx.x * 256 + threadIdx.x; // grid 72 -> 6*3072
    int l = i / QKVS, j = i - l * QKVS;
    float v = (j < 1024) ? qb[l * Dc + j] * SCALEc
            : (j < 2048) ? kb[l * Dc + j - 1024] : vb[l * Dc + j - 2048];
    o[i] = v;
}

// ---------------- fused: hb = LN(hb + softmax(clip(obv_row))) (bcast over batch) ------
__global__ __launch_bounds__(256) void smaddln_k(
    ushort* __restrict__ hb, const float* __restrict__ obv,
    const float* __restrict__ g, const float* __restrict__ b)
{
    const int row = blockIdx.x;
    const float* op = obv + (size_t)(row & (Sc - 1)) * Dc;
    ushort* hp = hb + (size_t)row * Dc;
    const int c0 = threadIdx.x * 4;
    // clip + softmax over the 1024-col row (recomputed per batch row; trivial VALU)
    float4 ov = *(const float4*)&op[c0];
    float r[4] = {ov.x, ov.y, ov.z, ov.w};
    float mx = -1e30f;
#pragma unroll
    for (int j = 0; j < 4; ++j) { r[j] = fminf(fmaxf(r[j], -10.f), 10.f); mx = fmaxf(mx, r[j]); }
    mx = blockMax256(mx);
    float s = 0.f;
#pragma unroll
    for (int j = 0; j < 4; ++j) { r[j] = __expf(r[j] - mx); s += r[j]; }
    s = blockSum256(s);
    float sinv = 1.f / s;
    // LN(hb + sm)
    ushort4 hv = *(const ushort4*)&hp[c0];
    float x[4] = {b2f(hv.x), b2f(hv.y), b2f(hv.z), b2f(hv.w)};
    float ssum = 0.f;
#pragma unroll
    for (int j = 0; j < 4; ++j) { x[j] += r[j] * sinv; ssum += x[j]; }
    float mean = blockSum256(ssum) * (1.f / (float)Dc);
    float vsum = 0.f;
#pragma unroll
    for (int j = 0; j < 4; ++j) { float d_ = x[j] - mean; vsum += d_ * d_; }
    float var = blockSum256(vsum) * (1.f / (float)Dc);
    float inv = rsqrtf(var + 1e-5f);
    float4 gv = *(const float4*)&g[c0];
    float4 bv = *(const float4*)&b[c0];
    ushort4 o4;
    o4.x = f2b((x[0] - mean) * inv * gv.x + bv.x);
    o4.y = f2b((x[1] - mean) * inv * gv.y + bv.y);
    o4.z = f2b((x[2] - mean) * inv * gv.z + bv.z);
    o4.w = f2b((x[3] - mean) * inv * gv.w + bv.w);
    *(ushort4*)&hp[c0] = o4;
}

// ---------------- hb = bf16(LN(hb + add)) ----------------
template <bool BCAST, typename TADD>
__global__ __launch_bounds__(256) void add_ln_k(
    ushort* __restrict__ hb, const TADD* __restrict__ add,
    const float* __restrict__ g, const float* __restrict__ b)
{
    const int row = blockIdx.x;
    const TADD* ap = BCAST ? add + (size_t)(row & (Sc - 1)) * Dc : add + (size_t)row * Dc;
    ushort* hp = hb + (size_t)row * Dc;
    const int c0 = threadIdx.x * 4;
    ushort4 hv = *(const ushort4*)&hp[c0];
    float x[4] = {b2f(hv.x), b2f(hv.y), b2f(hv.z), b2f(hv.w)};
#pragma unroll
    for (int j = 0; j < 4; ++j) x[j] += ldf(&ap[c0 + j]);
    float s = x[0] + x[1] + x[2] + x[3];
    float mean = blockSum256(s) * (1.f / (float)Dc);
    float vsum = 0.f;
#pragma unroll
    for (int j = 0; j < 4; ++j) { float d = x[j] - mean; vsum += d * d; }
    float var = blockSum256(vsum) * (1.f / (float)Dc);
    float inv = rsqrtf(var + 1e-5f);
    float4 gv = *(const float4*)&g[c0];
    float4 bv = *(const float4*)&b[c0];
    ushort4 ov;
    ov.x = f2b((x[0] - mean) * inv * gv.x + bv.x);
    ov.y = f2b((x[1] - mean) * inv * gv.y + bv.y);
    ov.z = f2b((x[2] - mean) * inv * gv.z + bv.z);
    ov.w = f2b((x[3] - mean) * inv * gv.w + bv.w);
    *(ushort4*)&hp[c0] = ov;
}

// ---------------- launch ----------------
extern "C" void kernel_launch(void* const* d_in, const int* in_sizes, int n_in,
                              void* d_out, int out_size, void* d_ws, size_t ws_size,
                              hipStream_t stream)
{
    const float* x      = (const float*)d_in[0];
    const float* xm     = (const float*)d_in[1];
    // d_in[2] vecSelector: assert-only, unused
    const float* proj_w = (const float*)d_in[3];
    const float* proj_b = (const float*)d_in[4];
    const float* pos    = (const float*)d_in[5];
    const float* qw     = (const float*)d_in[6];
    const float* qb     = (const float*)d_in[7];
    const float* kw     = (const float*)d_in[8];
    const float* kb     = (const float*)d_in[9];
    const float* vw     = (const float*)d_in[10];
    const float* vb     = (const float*)d_in[11];
    const float* ow     = (const float*)d_in[12];
    const float* obias  = (const float*)d_in[13];
    const float* ln1g   = (const float*)d_in[14];
    const float* ln1b   = (const float*)d_in[15];
    const float* ln2g   = (const float*)d_in[16];
    const float* ln2b   = (const float*)d_in[17];
    const float* w1     = (const float*)d_in[18];
    const float* b1     = (const float*)d_in[19];
    const float* w2     = (const float*)d_in[20];
    const float* b2     = (const float*)d_in[21];
    const float* fc1w   = (const float*)d_in[22];
    const float* fc1b   = (const float*)d_in[23];
    const float* fc2w   = (const float*)d_in[24];
    const float* fc2b   = (const float*)d_in[25];
    const float* fc3w   = (const float*)d_in[26];
    const float* fc3b   = (const float*)d_in[27];

    float* ws = (float*)d_ws;
    const size_t HSZ = (size_t)Bc * Sc * Dc; // 8,388,608 floats
    // layout (MiB): [0,16) hb | [16,32) ffu | [32,64) rgA | [64,65) meta | [65,..) Wt
    ushort* hb  = (ushort*)ws;
    ushort* ffu = (ushort*)(ws + HSZ / 2);
    float*  rgA = ws + HSZ;
    float*  meta = ws + 2 * HSZ;            // 64 MiB offset
    float*  flag = meta;
    float*  qkvball = meta + 256;           // 6*3072 floats
    ushort* Wt = (ushort*)(ws + 2 * HSZ + 262144); // 65 MiB offset

    // big path: all 6 layer slots resident (96 MiB) + proj slot -> need ~163 MiB
    const bool big = ws_size >= (size_t)163 * 1024 * 1024;
    const size_t lstride = big ? LSLOT : 0;
    ushort* projWt = big ? Wt + (size_t)6 * LSLOT : Wt;

    // rgA aliasing: attention phase temps | FFN midu | head comp temps
    ushort* qkvfu = (ushort*)rgA;                       // 512*3072 bf16
    ushort* aovu  = (ushort*)(rgA + 786432);            // 512*1024 bf16
    float*  obv   = rgA + 1048576;                      // 512*1024 fp32
    ushort* midu  = (ushort*)rgA;                       // 8192*2048 bf16 (FFN phase)
    float* W2  = rgA;                                   // head temps
    float* W4  = rgA + 65536;
    float* W5  = rgA + 131072;
    float* C1  = rgA + 196608;
    float* Wc  = rgA + 458752;
    float* bcv = rgA + 720896;

    const int MR = Bc * Sc; // 8192

    mask_k<<<1, 256, 0, stream>>>(xm, flag);
    qkvbiasall_k<<<72, 256, 0, stream>>>(qb, kb, vb, qkvball);
    if (big)
        transpall_k<<<dim3(32, 32, 36), 256, 0, stream>>>(qw, kw, vw, ow, w1, w2, Wt, 0, lstride);

    // hb = bf16(x @ proj_w + proj_b + pos)
    transp_k<<<dim3(Dc / 64, INc / 64), 256, 0, stream>>>(proj_w, projWt, INc, Dc, 1.f);
    mgemm_k<float, 0, true, 1><<<dim3(Dc / 128, MR / 128), 256, 0, stream>>>(
        x, projWt, proj_b, pos, nullptr, hb, MR, Dc, INc, 1.f);

    for (int l = 0; l < Lc; ++l) {
        ushort* slot = Wt + (size_t)(big ? l : 0) * LSLOT;
        const float* ob_l = obias + l * Dc;
        const float* b1_l = b1 + l * DFFc;
        const float* b2_l = b2 + l * Dc;

        if (!big)
            transpall_k<<<dim3(32, 32, 6), 256, 0, stream>>>(qw, kw, vw, ow, w1, w2, Wt, l, 0);

        // attention: batch 0 only (sa = ao[0] is all that survives)
        mgemm_k<ushort, 0, false, 1><<<dim3(QKVS / 128, Sc / 128), 256, 0, stream>>>(
            hb, slot, qkvball + l * QKVS, nullptr, nullptr, qkvfu, Sc, QKVS, Dc, 1.f);
        fattn_k<<<dim3(Sc / 32, Hc), 256, 0, stream>>>(qkvfu, aovu, flag);
        mgemm_k<ushort, 0, false, 0><<<dim3(Dc / 128, Sc / 128), 256, 0, stream>>>(
            aovu, slot + 3145728, ob_l, nullptr, obv, nullptr, Sc, Dc, Dc, 1.f);
        smaddln_k<<<MR, 256, 0, stream>>>(hb, obv, ln1g + l * Dc, ln1b + l * Dc);

        // FFN (all batches)
        mgemm_k<ushort, 1, false, 1><<<dim3(DFFc / 128, MR / 128), 256, 0, stream>>>(
            hb, slot + 4194304, b1_l, nullptr, nullptr, midu, MR, DFFc, Dc, 1.f);
        mgemm_k<ushort, 0, false, 1><<<dim3(Dc / 128, MR / 128), 256, 0, stream>>>(
            midu, slot + 6291456, b2_l, nullptr, nullptr, ffu, MR, Dc, DFFc, 1.f);
        add_ln_k<false, ushort><<<MR, 256, 0, stream>>>(hb, ffu, ln2g + l * Dc, ln2b + l * Dc);
    }

    // ---- head: out = h @ Wc + bc, Wc = fc1_w·fc2_w^5·fc3_w (fc2 affine, applied 5x) ----
    gemm_k<float, 0, false, false, false><<<dim3(4, 4), 256, 0, stream>>>(
        fc2w, fc2w, nullptr, nullptr, W2, nullptr, HIDc, HIDc, HIDc, 1.f);
    gemm_k<float, 0, false, false, false><<<dim3(4, 4), 256, 0, stream>>>(
        W2, W2, nullptr, nullptr, W4, nullptr, HIDc, HIDc, HIDc, 1.f);
    gemm_k<float, 0, false, false, false><<<dim3(4, 4), 256, 0, stream>>>(
        W4, fc2w, nullptr, nullptr, W5, nullptr, HIDc, HIDc, HIDc, 1.f);
    gemm_k<float, 0, false, false, false><<<dim3(4, 16), 256, 0, stream>>>(
        fc1w, W5, nullptr, nullptr, C1, nullptr, Dc, HIDc, HIDc, 1.f);
    gemm_k<float, 0, false, false, false><<<dim3(4, 16), 256, 0, stream>>>(
        C1, fc3w, nullptr, nullptr, Wc, nullptr, Dc, HIDc, HIDc, 1.f);
    biaschain_k<<<1, 256, 0, stream>>>(fc1b, fc2w, fc2b, fc3w, fc3b, bcv);
    transp_k<<<dim3(HIDc / 64, Dc / 64), 256, 0, stream>>>(Wc, Wt, Dc, HIDc, 1.f);
    mgemm_k<ushort, 0, false, 0><<<dim3(HIDc / 128, MR / 128), 256, 0, stream>>>(
        hb, Wt, bcv, nullptr, (float*)d_out, nullptr, MR, HIDc, Dc, 1.f);
}

// Round 10
// 1348.260 us; speedup vs baseline: 5.8711x; 1.0373x over previous
//
#include <hip/hip_runtime.h>
#include <hip/hip_bf16.h>

using bf16 = __hip_bfloat16;
typedef __attribute__((ext_vector_type(8))) short short8v;
typedef __attribute__((ext_vector_type(4))) float floatx4;

// Problem dims
constexpr int Bc = 16, Sc = 512, INc = 512, OUTc = 256;
constexpr int Dc = 1024, Hc = 16, Lc = 6, DFFc = 2048, HIDc = 256;
constexpr float SCALEc = 0.125f; // HD^-0.5
constexpr int QKVS = 3072;       // fused qkv row stride
constexpr size_t LSLOT = 8388608; // ushorts per layer weight slot (16 MiB): qkvo|w1|w2

__device__ inline ushort f2b(float f) { // fp32 -> bf16 RNE
    union { float f; unsigned u; } v; v.f = f;
    unsigned r = (v.u + 0x7FFF + ((v.u >> 16) & 1)) >> 16;
    return (ushort)r;
}
__device__ inline float b2f(ushort b) {
    union { unsigned u; float f; } v; v.u = ((unsigned)b) << 16;
    return v.f;
}
__device__ inline float ldf(const float* p) { return *p; }
__device__ inline float ldf(const ushort* p) { return b2f(*p); }

// async global->LDS, 16 B per lane. LDS dest is wave-uniform base + lane*16 (m104).
__device__ inline void gll16(const ushort* g, ushort* l) {
    __builtin_amdgcn_global_load_lds(
        (const __attribute__((address_space(1))) unsigned int*)g,
        (__attribute__((address_space(3))) unsigned int*)l, 16, 0, 0);
}

// ---------------- block reductions (256 threads, wave64) ----------------
__device__ inline float blockSum256(float v) {
    __shared__ float tmp[4];
#pragma unroll
    for (int o = 32; o > 0; o >>= 1) v += __shfl_xor(v, o, 64);
    int w = threadIdx.x >> 6;
    __syncthreads();
    if ((threadIdx.x & 63) == 0) tmp[w] = v;
    __syncthreads();
    return tmp[0] + tmp[1] + tmp[2] + tmp[3];
}
__device__ inline float blockMax256(float v) {
    __shared__ float tmp[4];
#pragma unroll
    for (int o = 32; o > 0; o >>= 1) v = fmaxf(v, __shfl_xor(v, o, 64));
    int w = threadIdx.x >> 6;
    __syncthreads();
    if ((threadIdx.x & 63) == 0) tmp[w] = v;
    __syncthreads();
    return fmaxf(fmaxf(tmp[0], tmp[1]), fmaxf(tmp[2], tmp[3]));
}

// ---------------- mask flag: (sum(xm[0,:]) == 0) ----------------
__global__ __launch_bounds__(256) void mask_k(const float* __restrict__ xm, float* __restrict__ flag) {
    float s = xm[threadIdx.x] + xm[threadIdx.x + 256];
    s = blockSum256(s);
    if (threadIdx.x == 0) flag[0] = (s == 0.f) ? 1.f : 0.f;
}

// ---------------- weight transpose + bf16 cvt: Wt[n][k] = bf16(W[k][n]*s) ----------------
__global__ __launch_bounds__(256) void transp_k(const float* __restrict__ W, ushort* __restrict__ Wt,
                                                int K, int N, float wscale) {
    __shared__ float Ls[64][65];
    const int t = threadIdx.x;
    const int n0 = blockIdx.x * 64, k0 = blockIdx.y * 64;
    const int kr = t >> 4, n4 = (t & 15) * 4;
#pragma unroll
    for (int p = 0; p < 4; ++p) {
        float4 v = *(const float4*)&W[(size_t)(k0 + kr + p * 16) * N + n0 + n4];
        Ls[kr + p * 16][n4 + 0] = v.x; Ls[kr + p * 16][n4 + 1] = v.y;
        Ls[kr + p * 16][n4 + 2] = v.z; Ls[kr + p * 16][n4 + 3] = v.w;
    }
    __syncthreads();
    const int nr = t >> 4, k4 = (t & 15) * 4;
#pragma unroll
    for (int p = 0; p < 4; ++p) {
        ushort4 o;
        o.x = f2b(Ls[k4 + 0][nr + p * 16] * wscale); o.y = f2b(Ls[k4 + 1][nr + p * 16] * wscale);
        o.z = f2b(Ls[k4 + 2][nr + p * 16] * wscale); o.w = f2b(Ls[k4 + 3][nr + p * 16] * wscale);
        *(ushort4*)&Wt[(size_t)(n0 + nr + p * 16) * K + k0 + k4] = o;
    }
}

// ---------------- batched layer-weight transpose (compact grid, ushort8 writes) ------
// Grid (2048, nlayers). blockIdx.x decodes matrix m + tile (no dead blocks):
//   [0,1024): m=id>>8 (q/k/v/ow, 16x16 tiles), [1024,1536): w1 (32x16), [1536,2048): w2 (16x32).
// Layer slot (ushorts): qkvo @0, w1 @4M, w2 @6M.
__global__ __launch_bounds__(256) void transpall_k(
    const float* __restrict__ qw, const float* __restrict__ kw, const float* __restrict__ vw,
    const float* __restrict__ ow, const float* __restrict__ w1, const float* __restrict__ w2,
    ushort* __restrict__ Wt, int l0, size_t lstride)
{
    const int l = l0 + blockIdx.y;
    ushort* slot = Wt + (size_t)blockIdx.y * lstride;
    const int id = blockIdx.x;
    int m, tx, ty;
    if (id < 1024)      { m = id >> 8; int r = id & 255;  tx = r & 15; ty = r >> 4; }
    else if (id < 1536) { m = 4;       int r = id - 1024; tx = r & 31; ty = r >> 5; }
    else                { m = 5;       int r = id - 1536; tx = r & 15; ty = r >> 4; }
    const float* W; ushort* dst; int K, N; float wscale = 1.f;
    switch (m) {
        case 0: W = qw + (size_t)l * Dc * Dc; K = Dc; N = Dc; dst = slot; wscale = SCALEc; break;
        case 1: W = kw + (size_t)l * Dc * Dc; K = Dc; N = Dc; dst = slot + 1048576; break;
        case 2: W = vw + (size_t)l * Dc * Dc; K = Dc; N = Dc; dst = slot + 2097152; break;
        case 3: W = ow + (size_t)l * Dc * Dc; K = Dc; N = Dc; dst = slot + 3145728; break;
        case 4: W = w1 + (size_t)l * Dc * DFFc; K = Dc; N = DFFc; dst = slot + 4194304; break;
        default: W = w2 + (size_t)l * DFFc * Dc; K = DFFc; N = Dc; dst = slot + 6291456; break;
    }
    __shared__ float Ls[64][65];
    const int t = threadIdx.x;
    const int n0 = tx * 64, k0 = ty * 64;
    const int kr = t >> 4, n4 = (t & 15) * 4;
#pragma unroll
    for (int p = 0; p < 4; ++p) {
        float4 v = *(const float4*)&W[(size_t)(k0 + kr + p * 16) * N + n0 + n4];
        Ls[kr + p * 16][n4 + 0] = v.x; Ls[kr + p * 16][n4 + 1] = v.y;
        Ls[kr + p * 16][n4 + 2] = v.z; Ls[kr + p * 16][n4 + 3] = v.w;
    }
    __syncthreads();
    // write: 64 n-rows x 8 k-chunks(8) = 512 tasks, 2 passes, 16 B/lane
#pragma unroll
    for (int p = 0; p < 2; ++p) {
        const int idx = t + 256 * p;
        const int n = idx >> 3, kc = (idx & 7) * 8;
        __align__(16) ushort tmp[8];
#pragma unroll
        for (int u = 0; u < 8; ++u) tmp[u] = f2b(Ls[kc + u][n] * wscale);
        *(short8v*)&dst[(size_t)(n0 + n) * K + k0 + kc] = *(short8v*)tmp;
    }
}

// ---------------- 16-elt loader for fp32 A staging ----------------
__device__ inline void ld16(const float* s, ushort* d) {
#pragma unroll
    for (int i = 0; i < 4; ++i) {
        float4 v = *(const float4*)(s + i * 4);
        d[i * 4 + 0] = f2b(v.x); d[i * 4 + 1] = f2b(v.y);
        d[i * 4 + 2] = f2b(v.z); d[i * 4 + 3] = f2b(v.w);
    }
}

// ---------------- MFMA GEMM (128x128 tile, BK=64, 4 waves, XOR-swizzled LDS) ----------
// Staging: global_load_lds width=16; linear LDS dest + inverse-swizzled global source
// chunk (rule #21) matching the swizzled ds_read. OMODE: 0=fp32, 1=bf16, 2=both.
template <typename TA, int ACT, bool ADDPOS, int OMODE>
__global__ __launch_bounds__(256) void mgemm_k(
    const TA* __restrict__ A, const ushort* __restrict__ Bt,
    const float* __restrict__ bias, const float* __restrict__ pos,
    float* __restrict__ Cf, ushort* __restrict__ Cb,
    int M, int N, int K, float scale)
{
    __shared__ __align__(16) ushort As[128 * 64];
    __shared__ __align__(16) ushort Bs[128 * 64];
    const int tid = threadIdx.x;
    const int nx = gridDim.x;
    const int nwg = nx * gridDim.y;
    int d = blockIdx.x + blockIdx.y * nx;
    if ((nwg & 7) == 0) d = (d & 7) * (nwg >> 3) + (d >> 3); // XCD swizzle, bijective
    const int m0 = (d / nx) * 128, n0 = (d % nx) * 128;
    const int lane = tid & 63, wv = tid >> 6;
    const int wm = (wv >> 1) * 64, wn = (wv & 1) * 64;
    floatx4 acc[4][4] = {};

    const int rA8 = lane >> 3, cch = lane & 7; // gll coords within 8-row issue
    const int srow = tid >> 2, scg = tid & 3;  // reg-stage coords (fp32 A)

    for (int k0 = 0; k0 < K; k0 += 64) {
#pragma unroll
        for (int p = 0; p < 4; ++p) {
            const int r = wv * 32 + p * 8 + rA8;
            const int cs = (cch ^ (r & 7)) * 8;
            gll16(&Bt[(size_t)(n0 + r) * K + k0 + cs], &Bs[(wv * 32 + p * 8) * 64]);
        }
        if constexpr (sizeof(TA) == 2) {
#pragma unroll
            for (int p = 0; p < 4; ++p) {
                const int r = wv * 32 + p * 8 + rA8;
                const int cs = (cch ^ (r & 7)) * 8;
                gll16((const ushort*)&A[(size_t)(m0 + r) * K + k0 + cs], &As[(wv * 32 + p * 8) * 64]);
            }
        } else {
#pragma unroll
            for (int p = 0; p < 2; ++p) {
                const int r = srow + p * 64;
                __align__(16) ushort ta[16];
                ld16(&A[(size_t)(m0 + r) * K + k0 + scg * 16], ta);
                const int base = r * 64, sw = (r & 7) * 8;
                *(short8v*)&As[base + ((scg * 16 + 0) ^ sw)] = *(short8v*)&ta[0];
                *(short8v*)&As[base + ((scg * 16 + 8) ^ sw)] = *(short8v*)&ta[8];
            }
        }
        __syncthreads();
#pragma unroll
        for (int s = 0; s < 2; ++s) {
            short8v af[4], bf_[4];
            const int kg = s * 32 + (lane >> 4) * 8;
#pragma unroll
            for (int f = 0; f < 4; ++f) {
                const int ra = wm + f * 16 + (lane & 15);
                af[f] = *(const short8v*)&As[ra * 64 + (kg ^ ((ra & 7) * 8))];
                const int rb = wn + f * 16 + (lane & 15);
                bf_[f] = *(const short8v*)&Bs[rb * 64 + (kg ^ ((rb & 7) * 8))];
            }
#pragma unroll
            for (int i = 0; i < 4; ++i)
#pragma unroll
                for (int j = 0; j < 4; ++j)
                    acc[i][j] = __builtin_amdgcn_mfma_f32_16x16x32_bf16(af[i], bf_[j], acc[i][j], 0, 0, 0);
        }
        __syncthreads();
    }

    const int cc = lane & 15, rr4 = (lane >> 4) * 4;
#pragma unroll
    for (int i = 0; i < 4; ++i) {
#pragma unroll
        for (int j = 0; j < 4; ++j) {
            const int col = n0 + wn + j * 16 + cc;
            const float bsv = bias[col];
#pragma unroll
            for (int q = 0; q < 4; ++q) {
                const int row = m0 + wm + i * 16 + rr4 + q;
                float v = acc[i][j][q] + bsv;
                if (ADDPOS) v += pos[(size_t)(row & (Sc - 1)) * N + col];
                v *= scale;
                if (ACT == 1) v = fmaxf(v, 0.f);
                if (OMODE == 0) Cf[(size_t)row * N + col] = v;
                else if (OMODE == 1) Cb[(size_t)row * N + col] = f2b(v);
                else { Cf[(size_t)row * N + col] = v; Cb[(size_t)row * N + col] = f2b(v); }
            }
        }
    }
}

// ---------------- fused attention (batch 0, bf16 qkv): softmax(clip(QK^T))·V -> ao ----
// Grid (Sc/16, Hc) = 512 blocks (2/CU), 256 thr = 4 waves. QK^T on MFMA (swizzled bf16
// LDS); clip bounds max at 10 -> exp(v-10), no online max; row-sums in-register; PV on
// VALU: thread owns (row pq, 4 cols at pd).
__global__ __launch_bounds__(256) void fattn_k(
    const ushort* __restrict__ qkv, ushort* __restrict__ ao, const float* __restrict__ flag)
{
    const int hh = blockIdx.y;
    const int t0 = blockIdx.x * 16;
    __shared__ __align__(16) ushort Qs[16 * 64];
    __shared__ __align__(16) ushort Ks[64 * 64];
    __shared__ float Vs[64][68];
    __shared__ float Ps[16][68];
    __shared__ float rs[4][16];
    const int tid = threadIdx.x;
    const int lane = tid & 63, wv = tid >> 6;
    const bool msk = flag[0] > 0.5f;

    if (tid < 128) { // stage Q tile (16x64, swizzled copy)
        const int r = tid >> 3, c = tid & 7;
        short8v q = *(const short8v*)&qkv[(size_t)(t0 + r) * QKVS + hh * 64 + c * 8];
        *(short8v*)&Qs[r * 64 + ((c * 8) ^ ((r & 7) * 8))] = q;
    }
    if (tid < 64) ((float*)rs)[tid] = 0.f;

    float o[4] = {};
    const int pq = tid >> 4, pd = (tid & 15) * 4; // PV ownership

    for (int s0 = 0; s0 < Sc; s0 += 64) {
        __syncthreads(); // previous PV readers done before restage
        { // stage V (bf16 -> f32 LDS) and K (swizzled copy)
            const int vr = tid >> 2, vc = (tid & 3) * 16;
            const ushort* vsrc = &qkv[(size_t)(s0 + vr) * QKVS + 2048 + hh * 64 + vc];
            short8v v0 = *(const short8v*)vsrc, v1 = *(const short8v*)(vsrc + 8);
#pragma unroll
            for (int u = 0; u < 8; ++u) {
                Vs[vr][vc + u] = b2f((ushort)v0[u]);
                Vs[vr][vc + 8 + u] = b2f((ushort)v1[u]);
            }
#pragma unroll
            for (int u = 0; u < 2; ++u) {
                const int task = tid + u * 256;
                const int kr = task >> 3, kc = task & 7;
                short8v kvv = *(const short8v*)&qkv[(size_t)(s0 + kr) * QKVS + 1024 + hh * 64 + kc * 8];
                *(short8v*)&Ks[kr * 64 + ((kc * 8) ^ ((kr & 7) * 8))] = kvv;
            }
        }
        __syncthreads();
        // QK^T: wave wv owns s-cols [wv*16, wv*16+16)
        floatx4 pacc = {};
#pragma unroll
        for (int s = 0; s < 2; ++s) {
            const int kg = s * 32 + (lane >> 4) * 8;
            const int ra = lane & 15;
            short8v aq = *(const short8v*)&Qs[ra * 64 + (kg ^ ((ra & 7) * 8))];
            const int rb = 16 * wv + (lane & 15);
            short8v bk = *(const short8v*)&Ks[rb * 64 + (kg ^ ((rb & 7) * 8))];
            pacc = __builtin_amdgcn_mfma_f32_16x16x32_bf16(aq, bk, pacc, 0, 0, 0);
        }
        // clip + exp(v-10) + rowsum + write P
        const int cc = lane & 15, rr4 = (lane >> 4) * 4;
#pragma unroll
        for (int q = 0; q < 4; ++q) {
            float v = fminf(fmaxf(pacc[q], -10.f), 10.f);
            if (msk) v = -10.f;
            float e = __expf(v - 10.f);
            Ps[rr4 + q][wv * 16 + cc] = e;
            float rsum = e;
            rsum += __shfl_xor(rsum, 1, 64);
            rsum += __shfl_xor(rsum, 2, 64);
            rsum += __shfl_xor(rsum, 4, 64);
            rsum += __shfl_xor(rsum, 8, 64);
            if (cc == 0) rs[wv][rr4 + q] += rsum;
        }
        __syncthreads();
        // PV (VALU): o[pq][pd..pd+3] += P[pq][ss] * V[ss][pd..pd+3]
#pragma unroll 8
        for (int ss = 0; ss < 64; ++ss) {
            float p = Ps[pq][ss];
#pragma unroll
            for (int u = 0; u < 4; ++u) o[u] += p * Vs[ss][pd + u];
        }
    }
    __syncthreads();
    float inv = 1.f / (rs[0][pq] + rs[1][pq] + rs[2][pq] + rs[3][pq]);
#pragma unroll
    for (int u = 0; u < 4; ++u)
        ao[(size_t)(t0 + pq) * Dc + hh * 64 + pd + u] = f2b(o[u] * inv);
}

// ---------------- fp32 VALU GEMM (head composition): C = A@W ----------------
template <typename TA, int ACT, bool ADDPOS, bool OUT_BF16, bool HASB>
__global__ __launch_bounds__(256) void gemm_k(
    const TA* __restrict__ A, const float* __restrict__ W,
    const float* __restrict__ bias, const float* __restrict__ pos,
    float* __restrict__ Cf, bf16* __restrict__ Cb,
    int M, int N, int K, float scale)
{
    __shared__ float As[16][68];
    __shared__ float Ws[16][68];
    const int tid = threadIdx.x;
    const int m0 = blockIdx.y * 64, n0 = blockIdx.x * 64;
    const int ty = tid >> 4, tx = tid & 15;
    float c[4][4] = {};

    const int ka = tid & 15, mb = tid >> 4;
    const int nw = tid & 63, kb = tid >> 6;

    for (int k0 = 0; k0 < K; k0 += 16) {
#pragma unroll
        for (int j = 0; j < 4; ++j) {
            int m = mb + 16 * j;
            As[ka][m] = ldf(&A[(size_t)(m0 + m) * K + k0 + ka]);
        }
#pragma unroll
        for (int j = 0; j < 4; ++j) {
            int k = kb + 4 * j;
            Ws[k][nw] = W[(size_t)(k0 + k) * N + n0 + nw];
        }
        __syncthreads();
#pragma unroll
        for (int k = 0; k < 16; ++k) {
            float4 av = *(const float4*)&As[k][ty * 4];
            float4 wv = *(const float4*)&Ws[k][tx * 4];
            float a[4] = {av.x, av.y, av.z, av.w};
            float w[4] = {wv.x, wv.y, wv.z, wv.w};
#pragma unroll
            for (int i = 0; i < 4; ++i)
#pragma unroll
                for (int j = 0; j < 4; ++j) c[i][j] += a[i] * w[j];
        }
        __syncthreads();
    }

#pragma unroll
    for (int i = 0; i < 4; ++i) {
        int m = m0 + ty * 4 + i;
#pragma unroll
        for (int j = 0; j < 4; ++j) {
            int n = n0 + tx * 4 + j;
            float v = c[i][j] + (HASB ? bias[n] : 0.f);
            if (ADDPOS) v += pos[(size_t)(m & (Sc - 1)) * N + n];
            v *= scale;
            if (ACT == 1) v = fmaxf(v, 0.f);
            if (OUT_BF16) Cb[(size_t)m * N + n] = __float2bfloat16(v);
            else          Cf[(size_t)m * N + n] = v;
        }
    }
}

// ---------------- fused head bias chain ----------------
__global__ __launch_bounds__(256) void biaschain_k(
    const float* __restrict__ fc1b, const float* __restrict__ fc2w, const float* __restrict__ fc2b,
    const float* __restrict__ fc3w, const float* __restrict__ fc3b, float* __restrict__ bc)
{
    __shared__ float vs[256];
    const int t = threadIdx.x;
    float v = fc1b[t];
    for (int r = 0; r < 5; ++r) {
        vs[t] = v; __syncthreads();
        float s = fc2b[t];
#pragma unroll 8
        for (int k = 0; k < 256; ++k) s += vs[k] * fc2w[k * 256 + t];
        v = s; __syncthreads();
    }
    vs[t] = v; __syncthreads();
    float s = fc3b[t];
#pragma unroll 8
    for (int k = 0; k < 256; ++k) s += vs[k] * fc3w[k * 256 + t];
    bc[t] = s;
}

// ---------------- qkv bias concat for ALL layers (q-part pre-scaled) ----------------
__global__ __launch_bounds__(256) void qkvbiasall_k(
    const float* __restrict__ qb, const float* __restrict__ kb, const float* __restrict__ vb,
    float* __restrict__ o)
{
    int i = blockIdx.x * 256 + threadIdx.x; // grid 72 -> 6*3072
    int l = i / QKVS, j = i - l * QKVS;
    float v = (j < 1024) ? qb[l * Dc + j] * SCALEc
            : (j < 2048) ? kb[l * Dc + j - 1024] : vb[l * Dc + j - 2048];
    o[i] = v;
}

// ---------------- fused: hb = LN(hb + softmax(clip(obv_row))) (bcast over batch) ------
__global__ __launch_bounds__(256) void smaddln_k(
    ushort* __restrict__ hb, const float* __restrict__ obv,
    const float* __restrict__ g, const float* __restrict__ b)
{
    const int row = blockIdx.x;
    const float* op = obv + (size_t)(row & (Sc - 1)) * Dc;
    ushort* hp = hb + (size_t)row * Dc;
    const int c0 = threadIdx.x * 4;
    float4 ov = *(const float4*)&op[c0];
    float r[4] = {ov.x, ov.y, ov.z, ov.w};
    float mx = -1e30f;
#pragma unroll
    for (int j = 0; j < 4; ++j) { r[j] = fminf(fmaxf(r[j], -10.f), 10.f); mx = fmaxf(mx, r[j]); }
    mx = blockMax256(mx);
    float s = 0.f;
#pragma unroll
    for (int j = 0; j < 4; ++j) { r[j] = __expf(r[j] - mx); s += r[j]; }
    s = blockSum256(s);
    float sinv = 1.f / s;
    ushort4 hv = *(const ushort4*)&hp[c0];
    float x[4] = {b2f(hv.x), b2f(hv.y), b2f(hv.z), b2f(hv.w)};
    float ssum = 0.f;
#pragma unroll
    for (int j = 0; j < 4; ++j) { x[j] += r[j] * sinv; ssum += x[j]; }
    float mean = blockSum256(ssum) * (1.f / (float)Dc);
    float vsum = 0.f;
#pragma unroll
    for (int j = 0; j < 4; ++j) { float d_ = x[j] - mean; vsum += d_ * d_; }
    float var = blockSum256(vsum) * (1.f / (float)Dc);
    float inv = rsqrtf(var + 1e-5f);
    float4 gv = *(const float4*)&g[c0];
    float4 bv = *(const float4*)&b[c0];
    ushort4 o4;
    o4.x = f2b((x[0] - mean) * inv * gv.x + bv.x);
    o4.y = f2b((x[1] - mean) * inv * gv.y + bv.y);
    o4.z = f2b((x[2] - mean) * inv * gv.z + bv.z);
    o4.w = f2b((x[3] - mean) * inv * gv.w + bv.w);
    *(ushort4*)&hp[c0] = o4;
}

// ---------------- hb = bf16(LN(hb + add)) ----------------
template <bool BCAST, typename TADD>
__global__ __launch_bounds__(256) void add_ln_k(
    ushort* __restrict__ hb, const TADD* __restrict__ add,
    const float* __restrict__ g, const float* __restrict__ b)
{
    const int row = blockIdx.x;
    const TADD* ap = BCAST ? add + (size_t)(row & (Sc - 1)) * Dc : add + (size_t)row * Dc;
    ushort* hp = hb + (size_t)row * Dc;
    const int c0 = threadIdx.x * 4;
    ushort4 hv = *(const ushort4*)&hp[c0];
    float x[4] = {b2f(hv.x), b2f(hv.y), b2f(hv.z), b2f(hv.w)};
#pragma unroll
    for (int j = 0; j < 4; ++j) x[j] += ldf(&ap[c0 + j]);
    float s = x[0] + x[1] + x[2] + x[3];
    float mean = blockSum256(s) * (1.f / (float)Dc);
    float vsum = 0.f;
#pragma unroll
    for (int j = 0; j < 4; ++j) { float d = x[j] - mean; vsum += d * d; }
    float var = blockSum256(vsum) * (1.f / (float)Dc);
    float inv = rsqrtf(var + 1e-5f);
    float4 gv = *(const float4*)&g[c0];
    float4 bv = *(const float4*)&b[c0];
    ushort4 ov;
    ov.x = f2b((x[0] - mean) * inv * gv.x + bv.x);
    ov.y = f2b((x[1] - mean) * inv * gv.y + bv.y);
    ov.z = f2b((x[2] - mean) * inv * gv.z + bv.z);
    ov.w = f2b((x[3] - mean) * inv * gv.w + bv.w);
    *(ushort4*)&hp[c0] = ov;
}

// ---------------- launch ----------------
extern "C" void kernel_launch(void* const* d_in, const int* in_sizes, int n_in,
                              void* d_out, int out_size, void* d_ws, size_t ws_size,
                              hipStream_t stream)
{
    const float* x      = (const float*)d_in[0];
    const float* xm     = (const float*)d_in[1];
    // d_in[2] vecSelector: assert-only, unused
    const float* proj_w = (const float*)d_in[3];
    const float* proj_b = (const float*)d_in[4];
    const float* pos    = (const float*)d_in[5];
    const float* qw     = (const float*)d_in[6];
    const float* qb     = (const float*)d_in[7];
    const float* kw     = (const float*)d_in[8];
    const float* kb     = (const float*)d_in[9];
    const float* vw     = (const float*)d_in[10];
    const float* vb     = (const float*)d_in[11];
    const float* ow     = (const float*)d_in[12];
    const float* obias  = (const float*)d_in[13];
    const float* ln1g   = (const float*)d_in[14];
    const float* ln1b   = (const float*)d_in[15];
    const float* ln2g   = (const float*)d_in[16];
    const float* ln2b   = (const float*)d_in[17];
    const float* w1     = (const float*)d_in[18];
    const float* b1     = (const float*)d_in[19];
    const float* w2     = (const float*)d_in[20];
    const float* b2     = (const float*)d_in[21];
    const float* fc1w   = (const float*)d_in[22];
    const float* fc1b   = (const float*)d_in[23];
    const float* fc2w   = (const float*)d_in[24];
    const float* fc2b   = (const float*)d_in[25];
    const float* fc3w   = (const float*)d_in[26];
    const float* fc3b   = (const float*)d_in[27];

    float* ws = (float*)d_ws;
    const size_t HSZ = (size_t)Bc * Sc * Dc; // 8,388,608 floats
    // layout (MiB): [0,16) hb | [16,32) ffu | [32,64) rgA | [64,65) meta | [65,..) Wt
    ushort* hb  = (ushort*)ws;
    ushort* ffu = (ushort*)(ws + HSZ / 2);
    float*  rgA = ws + HSZ;
    float*  meta = ws + 2 * HSZ;            // 64 MiB offset
    float*  flag = meta;
    float*  qkvball = meta + 256;           // 6*3072 floats
    ushort* Wt = (ushort*)(ws + 2 * HSZ + 262144); // 65 MiB offset

    // big path: all 6 layer slots resident (96 MiB) + proj slot -> need ~163 MiB
    const bool big = ws_size >= (size_t)163 * 1024 * 1024;
    const size_t lstride = big ? LSLOT : 0;
    ushort* projWt = big ? Wt + (size_t)6 * LSLOT : Wt;

    // rgA aliasing: attention phase temps | FFN midu | head comp temps
    ushort* qkvfu = (ushort*)rgA;                       // 512*3072 bf16
    ushort* aovu  = (ushort*)(rgA + 786432);            // 512*1024 bf16
    float*  obv   = rgA + 1048576;                      // 512*1024 fp32
    ushort* midu  = (ushort*)rgA;                       // 8192*2048 bf16 (FFN phase)
    float* W2  = rgA;                                   // head temps
    float* W4  = rgA + 65536;
    float* W5  = rgA + 131072;
    float* C1  = rgA + 196608;
    float* Wc  = rgA + 458752;
    float* bcv = rgA + 720896;

    const int MR = Bc * Sc; // 8192

    mask_k<<<1, 256, 0, stream>>>(xm, flag);
    qkvbiasall_k<<<72, 256, 0, stream>>>(qb, kb, vb, qkvball);
    if (big)
        transpall_k<<<dim3(2048, 6), 256, 0, stream>>>(qw, kw, vw, ow, w1, w2, Wt, 0, lstride);

    // hb = bf16(x @ proj_w + proj_b + pos)
    transp_k<<<dim3(Dc / 64, INc / 64), 256, 0, stream>>>(proj_w, projWt, INc, Dc, 1.f);
    mgemm_k<float, 0, true, 1><<<dim3(Dc / 128, MR / 128), 256, 0, stream>>>(
        x, projWt, proj_b, pos, nullptr, hb, MR, Dc, INc, 1.f);

    for (int l = 0; l < Lc; ++l) {
        ushort* slot = Wt + (size_t)(big ? l : 0) * LSLOT;
        const float* ob_l = obias + l * Dc;
        const float* b1_l = b1 + l * DFFc;
        const float* b2_l = b2 + l * Dc;

        if (!big)
            transpall_k<<<dim3(2048, 1), 256, 0, stream>>>(qw, kw, vw, ow, w1, w2, Wt, l, 0);

        // attention: batch 0 only (sa = ao[0] is all that survives)
        mgemm_k<ushort, 0, false, 1><<<dim3(QKVS / 128, Sc / 128), 256, 0, stream>>>(
            hb, slot, qkvball + l * QKVS, nullptr, nullptr, qkvfu, Sc, QKVS, Dc, 1.f);
        fattn_k<<<dim3(Sc / 16, Hc), 256, 0, stream>>>(qkvfu, aovu, flag);
        mgemm_k<ushort, 0, false, 0><<<dim3(Dc / 128, Sc / 128), 256, 0, stream>>>(
            aovu, slot + 3145728, ob_l, nullptr, obv, nullptr, Sc, Dc, Dc, 1.f);
        smaddln_k<<<MR, 256, 0, stream>>>(hb, obv, ln1g + l * Dc, ln1b + l * Dc);

        // FFN (all batches)
        mgemm_k<ushort, 1, false, 1><<<dim3(DFFc / 128, MR / 128), 256, 0, stream>>>(
            hb, slot + 4194304, b1_l, nullptr, nullptr, midu, MR, DFFc, Dc, 1.f);
        mgemm_k<ushort, 0, false, 1><<<dim3(Dc / 128, MR / 128), 256, 0, stream>>>(
            midu, slot + 6291456, b2_l, nullptr, nullptr, ffu, MR, Dc, DFFc, 1.f);
        add_ln_k<false, ushort><<<MR, 256, 0, stream>>>(hb, ffu, ln2g + l * Dc, ln2b + l * Dc);
    }

    // ---- head: out = h @ Wc + bc, Wc = fc1_w·fc2_w^5·fc3_w (fc2 affine, applied 5x) ----
    gemm_k<float, 0, false, false, false><<<dim3(4, 4), 256, 0, stream>>>(
        fc2w, fc2w, nullptr, nullptr, W2, nullptr, HIDc, HIDc, HIDc, 1.f);
    gemm_k<float, 0, false, false, false><<<dim3(4, 4), 256, 0, stream>>>(
        W2, W2, nullptr, nullptr, W4, nullptr, HIDc, HIDc, HIDc, 1.f);
    gemm_k<float, 0, false, false, false><<<dim3(4, 4), 256, 0, stream>>>(
        W4, fc2w, nullptr, nullptr, W5, nullptr, HIDc, HIDc, HIDc, 1.f);
    gemm_k<float, 0, false, false, false><<<dim3(4, 16), 256, 0, stream>>>(
        fc1w, W5, nullptr, nullptr, C1, nullptr, Dc, HIDc, HIDc, 1.f);
    gemm_k<float, 0, false, false, false><<<dim3(4, 16), 256, 0, stream>>>(
        C1, fc3w, nullptr, nullptr, Wc, nullptr, Dc, HIDc, HIDc, 1.f);
    biaschain_k<<<1, 256, 0, stream>>>(fc1b, fc2w, fc2b, fc3w, fc3b, bcv);
    transp_k<<<dim3(HIDc / 64, Dc / 64), 256, 0, stream>>>(Wc, Wt, Dc, HIDc, 1.f);
    mgemm_k<ushort, 0, false, 0><<<dim3(HIDc / 128, MR / 128), 256, 0, stream>>>(
        hb, Wt, bcv, nullptr, (float*)d_out, nullptr, MR, HIDc, Dc, 1.f);
}